// Round 5
// baseline (3171.667 us; speedup 1.0000x reference)
//
#include <hip/hip_runtime.h>
#include <hip/hip_bf16.h>

#define BB 2
#define LL 4096
#define DD 1024
#define HH 4
#define DH 256
#define CH 32
#define NC (LL/CH)     // 128
#define BL (BB*LL)     // 8192
#define BLD ((size_t)BB*LL*DD) // 8388608

typedef __attribute__((ext_vector_type(8))) short short8;
typedef __attribute__((ext_vector_type(4))) float floatx4;

__device__ __forceinline__ float bf2f(unsigned short u) {
    union { float f; unsigned int i; } x; x.i = ((unsigned int)u) << 16; return x.f;
}
__device__ __forceinline__ unsigned short f2bf(float f) {
    union { float f; unsigned int i; } x; x.f = f;
    unsigned int r = x.i + 0x7FFFu + ((x.i >> 16) & 1u);
    return (unsigned short)(r >> 16);
}
// pack two f32 -> (bf16(b)<<16)|bf16(a), round-half-up (1 add each + 1 perm)
__device__ __forceinline__ unsigned int pkbf(float a, float b) {
    unsigned int ua = __float_as_uint(a) + 0x8000u;
    unsigned int ub = __float_as_uint(b) + 0x8000u;
    return __builtin_amdgcn_perm(ub, ua, 0x07060302);
}

// ---------------------------------------------------------------- f32 -> bf16 bulk convert
__global__ __launch_bounds__(256) void cvt_bf_k(
    const float* __restrict__ x, unsigned short* __restrict__ y)
{
    size_t i = ((size_t)blockIdx.x * 256 + threadIdx.x) * 4;
    float4 v = *(const float4*)(x + i);
    ushort4 o;
    o.x = f2bf(v.x); o.y = f2bf(v.y); o.z = f2bf(v.z); o.w = f2bf(v.w);
    *(ushort4*)(y + i) = o;
}

// ---------------------------------------------------------------- bf16 MFMA GEMM (NT), f32 A
__global__ __launch_bounds__(256) void gemm_mfma(
    const float* __restrict__ A, int lda,
    const float* __restrict__ W, int ldw,
    const float* __restrict__ bias,
    float* __restrict__ C, int ldc, int K)
{
    __shared__ unsigned short Abuf[128][56];
    __shared__ unsigned short Bbuf[128][56];
    const int t = threadIdx.x;
    const int wave = t >> 6, lane = t & 63;
    const int wm = wave >> 1, wn = wave & 1;
    const int row0 = blockIdx.y * 128, col0 = blockIdx.x * 128;

    floatx4 acc[4][4];
#pragma unroll
    for (int i = 0; i < 4; ++i)
#pragma unroll
        for (int j = 0; j < 4; ++j) acc[i][j] = (floatx4){0.f, 0.f, 0.f, 0.f};

    const int fr = lane & 15, fk = (lane >> 4) * 8;

    for (int kt = 0; kt < K; kt += 32) {
        __syncthreads();
#pragma unroll
        for (int it = 0; it < 2; ++it) {
            int idx = t + it * 256;
            int r = idx >> 2, s = (idx & 3) * 8;
            const float* ap = A + (size_t)(row0 + r) * lda + kt + s;
            float4 a0 = *(const float4*)(ap);
            float4 a1 = *(const float4*)(ap + 4);
            ushort4 p0, p1;
            p0.x = f2bf(a0.x); p0.y = f2bf(a0.y); p0.z = f2bf(a0.z); p0.w = f2bf(a0.w);
            p1.x = f2bf(a1.x); p1.y = f2bf(a1.y); p1.z = f2bf(a1.z); p1.w = f2bf(a1.w);
            *(ushort4*)&Abuf[r][s]     = p0;
            *(ushort4*)&Abuf[r][s + 4] = p1;
            const float* wp = W + (size_t)(col0 + r) * ldw + kt + s;
            float4 b0 = *(const float4*)(wp);
            float4 b1 = *(const float4*)(wp + 4);
            ushort4 q0, q1;
            q0.x = f2bf(b0.x); q0.y = f2bf(b0.y); q0.z = f2bf(b0.z); q0.w = f2bf(b0.w);
            q1.x = f2bf(b1.x); q1.y = f2bf(b1.y); q1.z = f2bf(b1.z); q1.w = f2bf(b1.w);
            *(ushort4*)&Bbuf[r][s]     = q0;
            *(ushort4*)&Bbuf[r][s + 4] = q1;
        }
        __syncthreads();

        short8 afrag[4], bfrag[4];
#pragma unroll
        for (int i = 0; i < 4; ++i) {
            afrag[i] = *(const short8*)&Abuf[wm * 64 + i * 16 + fr][fk];
            bfrag[i] = *(const short8*)&Bbuf[wn * 64 + i * 16 + fr][fk];
        }
#pragma unroll
        for (int i = 0; i < 4; ++i)
#pragma unroll
            for (int j = 0; j < 4; ++j)
                acc[i][j] = __builtin_amdgcn_mfma_f32_16x16x32_bf16(
                    afrag[i], bfrag[j], acc[i][j], 0, 0, 0);
    }

    const int fc = lane & 15, frow = (lane >> 4) * 4;
#pragma unroll
    for (int j = 0; j < 4; ++j) {
        int col = col0 + wn * 64 + j * 16 + fc;
        float bv = bias ? bias[col] : 0.0f;
#pragma unroll
        for (int i = 0; i < 4; ++i) {
#pragma unroll
            for (int r = 0; r < 4; ++r) {
                int row = row0 + wm * 64 + i * 16 + frow + r;
                C[(size_t)row * ldc + col] = acc[i][j][r] + bv;
            }
        }
    }
}

// ---------------------------------------------------------------- bf16 MFMA GEMM (NT), bf16 A
__global__ __launch_bounds__(256) void gemm_mfma_bfA(
    const unsigned short* __restrict__ A, int lda,
    const float* __restrict__ W, int ldw,
    float* __restrict__ C, int ldc, int K)
{
    __shared__ unsigned short Abuf[128][56];
    __shared__ unsigned short Bbuf[128][56];
    const int t = threadIdx.x;
    const int wave = t >> 6, lane = t & 63;
    const int wm = wave >> 1, wn = wave & 1;
    const int row0 = blockIdx.y * 128, col0 = blockIdx.x * 128;

    floatx4 acc[4][4];
#pragma unroll
    for (int i = 0; i < 4; ++i)
#pragma unroll
        for (int j = 0; j < 4; ++j) acc[i][j] = (floatx4){0.f, 0.f, 0.f, 0.f};

    const int fr = lane & 15, fk = (lane >> 4) * 8;

    for (int kt = 0; kt < K; kt += 32) {
        __syncthreads();
#pragma unroll
        for (int it = 0; it < 2; ++it) {
            int idx = t + it * 256;
            int r = idx >> 2, s = (idx & 3) * 8;
            uint4 av = *(const uint4*)(A + (size_t)(row0 + r) * lda + kt + s);
            *(uint4*)&Abuf[r][s] = av;
            const float* wp = W + (size_t)(col0 + r) * ldw + kt + s;
            float4 b0 = *(const float4*)(wp);
            float4 b1 = *(const float4*)(wp + 4);
            ushort4 q0, q1;
            q0.x = f2bf(b0.x); q0.y = f2bf(b0.y); q0.z = f2bf(b0.z); q0.w = f2bf(b0.w);
            q1.x = f2bf(b1.x); q1.y = f2bf(b1.y); q1.z = f2bf(b1.z); q1.w = f2bf(b1.w);
            *(ushort4*)&Bbuf[r][s]     = q0;
            *(ushort4*)&Bbuf[r][s + 4] = q1;
        }
        __syncthreads();

        short8 afrag[4], bfrag[4];
#pragma unroll
        for (int i = 0; i < 4; ++i) {
            afrag[i] = *(const short8*)&Abuf[wm * 64 + i * 16 + fr][fk];
            bfrag[i] = *(const short8*)&Bbuf[wn * 64 + i * 16 + fr][fk];
        }
#pragma unroll
        for (int i = 0; i < 4; ++i)
#pragma unroll
            for (int j = 0; j < 4; ++j)
                acc[i][j] = __builtin_amdgcn_mfma_f32_16x16x32_bf16(
                    afrag[i], bfrag[j], acc[i][j], 0, 0, 0);
    }

    const int fc = lane & 15, frow = (lane >> 4) * 4;
#pragma unroll
    for (int j = 0; j < 4; ++j) {
        int col = col0 + wn * 64 + j * 16 + fc;
#pragma unroll
        for (int i = 0; i < 4; ++i) {
#pragma unroll
            for (int r = 0; r < 4; ++r) {
                int row = row0 + wm * 64 + i * 16 + frow + r;
                C[(size_t)row * ldc + col] = acc[i][j][r];
            }
        }
    }
}

// --------------------------------------- causal dwconv K=4 + silu + head-l2norm -> bf16
__global__ __launch_bounds__(256) void convnorm_qk_k(
    const float* __restrict__ x, const float* __restrict__ w,
    unsigned short* __restrict__ y)
{
    int bl = blockIdx.x >> 2;
    int h  = blockIdx.x & 3;
    int l  = bl & (LL - 1);
    int d  = threadIdx.x;
    int c  = h * DH + d;
    const float* wp = w + (size_t)c * 4;
    const float* xp = x + (size_t)bl * DD + c;
    float acc = wp[3] * xp[0];
    if (l >= 1) acc += wp[2] * xp[-(int)DD];
    if (l >= 2) acc += wp[1] * xp[-2*(int)DD];
    if (l >= 3) acc += wp[0] * xp[-3*(int)DD];
    acc = acc / (1.0f + expf(-acc));
    float s = acc * acc;
#pragma unroll
    for (int off = 32; off > 0; off >>= 1) s += __shfl_down(s, off);
    __shared__ float red[4];
    int wv = threadIdx.x >> 6, ln = threadIdx.x & 63;
    if (ln == 0) red[wv] = s;
    __syncthreads();
    float tot = red[0] + red[1] + red[2] + red[3];
    y[(size_t)bl * DD + c] = f2bf(acc * rsqrtf(tot));
}

// ------------------------------------------------- causal depthwise conv K=4 + silu (f32)
__global__ __launch_bounds__(256) void conv_silu_k(
    const float* __restrict__ x, const float* __restrict__ w, float* __restrict__ y)
{
    size_t idx = (size_t)blockIdx.x * 256 + threadIdx.x;
    int c = (int)(idx & (DD - 1));
    int bl = (int)(idx >> 10);
    int l = bl & (LL - 1);
    const float* wp = w + (size_t)c * 4;
    const float* xp = x + (size_t)bl * DD + c;
    float acc = wp[3] * xp[0];
    if (l >= 1) acc += wp[2] * xp[-(int)DD];
    if (l >= 2) acc += wp[1] * xp[-2*(int)DD];
    if (l >= 3) acc += wp[0] * xp[-3*(int)DD];
    y[idx] = acc / (1.0f + expf(-acc));
}

// ------------------------------------------------- FIR causal depthwise conv, LDS-tiled
template<int K>
__global__ __launch_bounds__(256) void fir2_k(
    const float* __restrict__ x, const float* __restrict__ filt, float* __restrict__ y)
{
    const int ctile = blockIdx.x & 15;
    const int ltile = (blockIdx.x >> 4) & 63;
    const int b = blockIdx.x >> 10;
    const int RT = 64 + K - 1;
    __shared__ float xs[RT][64];
    __shared__ float fs[64][K + 1];
    const int t = threadIdx.x;
    const int l0 = ltile * 64;

    for (int i = t; i < RT * 16; i += 256) {
        int li = i >> 4, c4 = (i & 15) * 4;
        int l = l0 - (K - 1) + li;
        float4 v = make_float4(0.f, 0.f, 0.f, 0.f);
        if (l >= 0)
            v = *(const float4*)(x + ((size_t)b * LL + l) * DD + ctile * 64 + c4);
        *(float4*)&xs[li][c4] = v;
    }
    for (int i = t; i < 64 * K; i += 256) {
        fs[i / K][i % K] = filt[(size_t)ctile * 64 * K + i];
    }
    __syncthreads();

    const int c = t & 63, lg = t >> 6;
    float acc[16];
#pragma unroll
    for (int o = 0; o < 16; ++o) acc[o] = 0.f;
#pragma unroll
    for (int j = 0; j < 16 + K - 1; ++j) {
        float xv = xs[lg * 16 + j][c];
#pragma unroll
        for (int o = 0; o < 16; ++o) {
            int tap = j - o;
            if (tap >= 0 && tap < K) acc[o] += fs[c][tap] * xv;
        }
    }
    size_t base = ((size_t)b * LL + l0 + lg * 16) * DD + ctile * 64 + c;
#pragma unroll
    for (int o = 0; o < 16; ++o)
        y[base + (size_t)o * DD] = acc[o];
}

// ------------------------------------------------- beta = sigmoid(hs @ b_proj^T)
__global__ __launch_bounds__(256) void beta_k(
    const float* __restrict__ hs, const float* __restrict__ bw, float* __restrict__ beta)
{
    int bl = blockIdx.x;
    const float* xr = hs + (size_t)bl * DD;
    float a0=0.f,a1=0.f,a2=0.f,a3=0.f;
    for (int k = threadIdx.x; k < DD; k += 256) {
        float xv = xr[k];
        a0 += xv * bw[k];
        a1 += xv * bw[DD + k];
        a2 += xv * bw[2*DD + k];
        a3 += xv * bw[3*DD + k];
    }
#pragma unroll
    for (int off = 32; off > 0; off >>= 1) {
        a0 += __shfl_down(a0, off); a1 += __shfl_down(a1, off);
        a2 += __shfl_down(a2, off); a3 += __shfl_down(a3, off);
    }
    __shared__ float red[4][4];
    int wv = threadIdx.x >> 6, ln = threadIdx.x & 63;
    if (ln == 0) { red[wv][0]=a0; red[wv][1]=a1; red[wv][2]=a2; red[wv][3]=a3; }
    __syncthreads();
    if (threadIdx.x < 4) {
        int h = threadIdx.x;
        float s = red[0][h] + red[1][h] + red[2][h] + red[3][h];
        beta[(size_t)bl * HH + h] = 1.0f / (1.0f + expf(-s));
    }
}

// ------------------------------------------------- k transpose: k[b,l,h*DH+e] -> kT[bh,e,l]
__global__ __launch_bounds__(256) void tr_k(
    const unsigned short* __restrict__ k, unsigned short* __restrict__ kT)
{
    int et = blockIdx.x & 3;
    int lt = (blockIdx.x >> 2) & 63;
    int bh = blockIdx.x >> 8;
    int h = bh & 3, b = bh >> 2;
    __shared__ unsigned short tile[64][72];
    int t = threadIdx.x;
    int tr = t >> 4;
    int tc = (t & 15) * 4;
#pragma unroll
    for (int i = 0; i < 4; ++i) {
        int l = tr + i * 16;
        ushort4 v = *(const ushort4*)(k + ((size_t)b * LL + lt*64 + l) * DD + h * DH + et*64 + tc);
        *(ushort4*)&tile[l][tc] = v;
    }
    __syncthreads();
#pragma unroll
    for (int i = 0; i < 4; ++i) {
        int e = tr + i * 16;
        ushort4 v;
        v.x = tile[tc+0][e]; v.y = tile[tc+1][e];
        v.z = tile[tc+2][e]; v.w = tile[tc+3][e];
        *(ushort4*)(kT + ((size_t)bh * DH + et*64 + e) * LL + (size_t)lt*64 + tc) = v;
    }
}

// ------------------------------------------------- u transpose: u[bh,l,d] -> uT[bh,d,l]
__global__ __launch_bounds__(256) void tru_k(
    const unsigned short* __restrict__ u, unsigned short* __restrict__ uT)
{
    int et = blockIdx.x & 3;
    int lt = (blockIdx.x >> 2) & 63;
    int bh = blockIdx.x >> 8;
    __shared__ unsigned short tile[64][72];
    int t = threadIdx.x;
    int tr = t >> 4;
    int tc = (t & 15) * 4;
#pragma unroll
    for (int i = 0; i < 4; ++i) {
        int l = tr + i * 16;
        ushort4 v = *(const ushort4*)(u + ((size_t)bh * LL + lt*64 + l) * DH + et*64 + tc);
        *(ushort4*)&tile[l][tc] = v;
    }
    __syncthreads();
#pragma unroll
    for (int i = 0; i < 4; ++i) {
        int e = tr + i * 16;
        ushort4 v;
        v.x = tile[tc+0][e]; v.y = tile[tc+1][e];
        v.z = tile[tc+2][e]; v.w = tile[tc+3][e];
        *(ushort4*)(uT + ((size_t)bh * DH + et*64 + e) * LL + (size_t)lt*64 + tc) = v;
    }
}

// ------------------------------------------------- per-chunk prep (attn out now bf16)
__global__ __launch_bounds__(256) void chunk_prep_k(
    const unsigned short* __restrict__ q, const unsigned short* __restrict__ k,
    const float* __restrict__ v, const float* __restrict__ beta,
    unsigned short* __restrict__ u_out, unsigned short* __restrict__ w_out,
    unsigned short* __restrict__ attn_out)
{
    int ci = blockIdx.x & (NC - 1);
    int bh = blockIdx.x >> 7;
    int h = bh & (HH - 1), b = bh >> 2;
    __shared__ float kt[CH][DH + 4];
    __shared__ float Am[CH][CH + 1];
    __shared__ float Ab[CH][CH + 1];
    __shared__ float bet[CH];
    int t = threadIdx.x;
    size_t qgbase = (size_t)b * LL + (size_t)ci * CH;

    for (int i = t; i < CH * (DH / 4); i += 256) {
        int r = i >> 6;
        int c4 = (i & 63) * 4;
        ushort4 kv = *(const ushort4*)(k + (qgbase + r) * DD + h * DH + c4);
        kt[r][c4+0] = bf2f(kv.x); kt[r][c4+1] = bf2f(kv.y);
        kt[r][c4+2] = bf2f(kv.z); kt[r][c4+3] = bf2f(kv.w);
    }
    if (t < CH) bet[t] = beta[(qgbase + t) * HH + h];
    __syncthreads();

    int c = t >> 3, e0 = (t & 7) * 4;
    {
        float accA[4] = {0,0,0,0}, accT[4] = {0,0,0,0};
        const unsigned short* qrow = q + (qgbase + c) * DD + h * DH;
        for (int d0 = 0; d0 < DH; d0 += 4) {
            float4 kc = *(const float4*)&kt[c][d0];
            ushort4 qv = *(const ushort4*)(qrow + d0);
            float qx = bf2f(qv.x), qy = bf2f(qv.y), qz = bf2f(qv.z), qw = bf2f(qv.w);
#pragma unroll
            for (int e = 0; e < 4; ++e) {
                float4 ke = *(const float4*)&kt[e0 + e][d0];
                accA[e] += kc.x*ke.x + kc.y*ke.y + kc.z*ke.z + kc.w*ke.w;
                accT[e] += qx*ke.x + qy*ke.y + qz*ke.z + qw*ke.w;
            }
        }
        float bc = bet[c];
        size_t abase = (size_t)blockIdx.x * (CH * CH) + (size_t)c * CH;
#pragma unroll
        for (int e = 0; e < 4; ++e) {
            int ee = e0 + e;
            Am[c][ee] = (ee < c) ? (-bc * accA[e]) : 0.0f;
            attn_out[abase + ee] = (ee <= c) ? f2bf(accT[e]) : (unsigned short)0;
        }
    }
    __syncthreads();

    for (int i = 1; i < CH; ++i) {
        float upd = 0.0f;
        if (t < i) {
#pragma unroll
            for (int kk = 0; kk < CH; ++kk) upd += Am[i][kk] * Am[kk][t];
        }
        __syncthreads();
        if (t < i) Am[i][t] += upd;
        __syncthreads();
    }

    for (int i = t; i < CH * CH; i += 256) {
        int cc = i >> 5, ee = i & 31;
        float val = Am[cc][ee] + (cc == ee ? 1.0f : 0.0f);
        Ab[cc][ee] = val * bet[ee];
    }
    __syncthreads();

    int c2 = t >> 3, dd0 = (t & 7) * 32;
    float accu[32];
#pragma unroll
    for (int j = 0; j < 32; ++j) accu[j] = 0.0f;
    for (int e = 0; e < CH; ++e) {
        float ab = Ab[c2][e];
        const float* vrow = v + (qgbase + e) * DD + h * DH + dd0;
#pragma unroll
        for (int j4 = 0; j4 < 8; ++j4) {
            float4 v4 = *(const float4*)(vrow + j4 * 4);
            accu[j4*4+0] += ab * v4.x; accu[j4*4+1] += ab * v4.y;
            accu[j4*4+2] += ab * v4.z; accu[j4*4+3] += ab * v4.w;
        }
    }
    size_t obase = ((size_t)bh * LL + (size_t)ci * CH + c2) * DH + dd0;
#pragma unroll
    for (int j4 = 0; j4 < 8; ++j4) {
        ushort4 o;
        o.x = f2bf(accu[j4*4+0]); o.y = f2bf(accu[j4*4+1]);
        o.z = f2bf(accu[j4*4+2]); o.w = f2bf(accu[j4*4+3]);
        *(ushort4*)(u_out + obase + j4*4) = o;
    }

#pragma unroll
    for (int j = 0; j < 32; ++j) accu[j] = 0.0f;
    for (int e = 0; e < CH; ++e) {
        float ab = Ab[c2][e];
#pragma unroll
        for (int j4 = 0; j4 < 8; ++j4) {
            float4 v4 = *(const float4*)&kt[e][dd0 + j4*4];
            accu[j4*4+0] += ab * v4.x; accu[j4*4+1] += ab * v4.y;
            accu[j4*4+2] += ab * v4.z; accu[j4*4+3] += ab * v4.w;
        }
    }
#pragma unroll
    for (int j4 = 0; j4 < 8; ++j4) {
        ushort4 o;
        o.x = f2bf(accu[j4*4+0]); o.y = f2bf(accu[j4*4+1]);
        o.z = f2bf(accu[j4*4+2]); o.w = f2bf(accu[j4*4+3]);
        *(ushort4*)(w_out + obase + j4*4) = o;
    }
}

// ------------------------------------------------- chunk scan v3: MFMA, barrier-free.
// 16 blocks = (b,h) x 2 col-halves; 4 waves/block, each wave owns a 32-col slice.
// S (256 x 32) f32 lives in accumulators across all 128 chunks.
__global__ __launch_bounds__(256) void scan3_k(
    const unsigned short* __restrict__ q, const unsigned short* __restrict__ kT,
    const unsigned short* __restrict__ uT, const unsigned short* __restrict__ w,
    const unsigned short* __restrict__ attn, float* __restrict__ dout)
{
    const int bj = blockIdx.x & 1;
    const int bh = blockIdx.x >> 1;
    const int h = bh & (HH - 1), b = bh >> 2;
    const int wave = threadIdx.x >> 6, lane = threadIdx.x & 63;
    const int lr = lane & 15, lg = lane >> 4;
    const int colW = bj * 128 + wave * 32;   // global col of wave's slice
    const int colL = wave * 32;              // col within block LDS

    __shared__ unsigned short Sb[128][264];    // [col][e] bf16, 528B pitch (16B aligned)
    __shared__ unsigned short uadjT[128][40];  // [col][cc] bf16, 80B pitch

    floatx4 Sacc[16][2];
#pragma unroll
    for (int mt = 0; mt < 16; ++mt) {
        Sacc[mt][0] = (floatx4){0.f,0.f,0.f,0.f};
        Sacc[mt][1] = (floatx4){0.f,0.f,0.f,0.f};
    }

    const unsigned short* qbase = q + (size_t)b * LL * DD + h * DH;
    const unsigned short* wbase = w + (size_t)bh * LL * DH;
    const unsigned short* uTb = uT + (size_t)bh * DH * LL;
    const unsigned short* kTb = kT + (size_t)bh * DH * LL;
    float* db = dout + (size_t)bh * LL * DH;

    for (int ci = 0; ci < NC; ++ci) {
        const int l0 = ci * CH;

        // 1) Sb = bf16(Sacc)   (C-layout -> [col][e], wave-private cols)
#pragma unroll
        for (int nt = 0; nt < 2; ++nt) {
            int col = colL + nt * 16 + lr;
#pragma unroll
            for (int mt = 0; mt < 16; ++mt) {
                int e0 = mt * 16 + lg * 4;
                *(unsigned int*)&Sb[col][e0]     = pkbf(Sacc[mt][nt][0], Sacc[mt][nt][1]);
                *(unsigned int*)&Sb[col][e0 + 2] = pkbf(Sacc[mt][nt][2], Sacc[mt][nt][3]);
            }
        }

        // 2) stage A: Tacc = [w(2 tiles); q(2 tiles)] @ S  (K = 256)
        floatx4 Tacc[4][2];
#pragma unroll
        for (int mt = 0; mt < 4; ++mt) {
            Tacc[mt][0] = (floatx4){0.f,0.f,0.f,0.f};
            Tacc[mt][1] = (floatx4){0.f,0.f,0.f,0.f};
        }
#pragma unroll
        for (int kt = 0; kt < 8; ++kt) {
            const int k0 = kt * 32 + lg * 8;
            short8 aw0 = *(const short8*)(wbase + (size_t)(l0 + lr) * DH + k0);
            short8 aw1 = *(const short8*)(wbase + (size_t)(l0 + 16 + lr) * DH + k0);
            short8 aq0 = *(const short8*)(qbase + (size_t)(l0 + lr) * DD + k0);
            short8 aq1 = *(const short8*)(qbase + (size_t)(l0 + 16 + lr) * DD + k0);
            short8 sb0 = *(const short8*)&Sb[colL + lr][k0];
            short8 sb1 = *(const short8*)&Sb[colL + 16 + lr][k0];
            Tacc[0][0] = __builtin_amdgcn_mfma_f32_16x16x32_bf16(aw0, sb0, Tacc[0][0], 0,0,0);
            Tacc[0][1] = __builtin_amdgcn_mfma_f32_16x16x32_bf16(aw0, sb1, Tacc[0][1], 0,0,0);
            Tacc[1][0] = __builtin_amdgcn_mfma_f32_16x16x32_bf16(aw1, sb0, Tacc[1][0], 0,0,0);
            Tacc[1][1] = __builtin_amdgcn_mfma_f32_16x16x32_bf16(aw1, sb1, Tacc[1][1], 0,0,0);
            Tacc[2][0] = __builtin_amdgcn_mfma_f32_16x16x32_bf16(aq0, sb0, Tacc[2][0], 0,0,0);
            Tacc[2][1] = __builtin_amdgcn_mfma_f32_16x16x32_bf16(aq0, sb1, Tacc[2][1], 0,0,0);
            Tacc[3][0] = __builtin_amdgcn_mfma_f32_16x16x32_bf16(aq1, sb0, Tacc[3][0], 0,0,0);
            Tacc[3][1] = __builtin_amdgcn_mfma_f32_16x16x32_bf16(aq1, sb1, Tacc[3][1], 0,0,0);
        }

        // 3) u_adj = u - w@S  (C-layout), pack into uadjT[col][cc]
        float ua[2][2][4];
#pragma unroll
        for (int nt = 0; nt < 2; ++nt) {
            int colG = colW + nt * 16 + lr;
#pragma unroll
            for (int mt = 0; mt < 2; ++mt) {
                ushort4 u4 = *(const ushort4*)(uTb + (size_t)colG * LL + l0 + mt * 16 + lg * 4);
                ua[mt][nt][0] = bf2f(u4.x) - Tacc[mt][nt][0];
                ua[mt][nt][1] = bf2f(u4.y) - Tacc[mt][nt][1];
                ua[mt][nt][2] = bf2f(u4.z) - Tacc[mt][nt][2];
                ua[mt][nt][3] = bf2f(u4.w) - Tacc[mt][nt][3];
            }
        }
#pragma unroll
        for (int nt = 0; nt < 2; ++nt) {
            int col = colL + nt * 16 + lr;
#pragma unroll
            for (int mt = 0; mt < 2; ++mt) {
                int cc0 = mt * 16 + lg * 4;
                *(unsigned int*)&uadjT[col][cc0]     = pkbf(ua[mt][nt][0], ua[mt][nt][1]);
                *(unsigned int*)&uadjT[col][cc0 + 2] = pkbf(ua[mt][nt][2], ua[mt][nt][3]);
            }
        }

        // 4) uadj B-frags (K = 32, single k-tile)
        short8 ub0 = *(const short8*)&uadjT[colL + lr][lg * 8];
        short8 ub1 = *(const short8*)&uadjT[colL + 16 + lr][lg * 8];

        // 5) O = q@S + attn@u_adj ; store f32
        const unsigned short* ab = attn + ((size_t)bh * NC + ci) * (CH * CH);
        short8 at0 = *(const short8*)(ab + (size_t)lr * CH + lg * 8);
        short8 at1 = *(const short8*)(ab + (size_t)(16 + lr) * CH + lg * 8);
        floatx4 O00 = __builtin_amdgcn_mfma_f32_16x16x32_bf16(at0, ub0, Tacc[2][0], 0,0,0);
        floatx4 O01 = __builtin_amdgcn_mfma_f32_16x16x32_bf16(at0, ub1, Tacc[2][1], 0,0,0);
        floatx4 O10 = __builtin_amdgcn_mfma_f32_16x16x32_bf16(at1, ub0, Tacc[3][0], 0,0,0);
        floatx4 O11 = __builtin_amdgcn_mfma_f32_16x16x32_bf16(at1, ub1, Tacc[3][1], 0,0,0);
#pragma unroll
        for (int r = 0; r < 4; ++r) {
            db[(size_t)(l0 + lg * 4 + r) * DH + colW + lr]           = O00[r];
            db[(size_t)(l0 + lg * 4 + r) * DH + colW + 16 + lr]      = O01[r];
            db[(size_t)(l0 + 16 + lg * 4 + r) * DH + colW + lr]      = O10[r];
            db[(size_t)(l0 + 16 + lg * 4 + r) * DH + colW + 16 + lr] = O11[r];
        }

        // 6) S += k^T @ u_adj   (A from kT, K = 32)
#pragma unroll 4
        for (int mt = 0; mt < 16; ++mt) {
            short8 kf = *(const short8*)(kTb + (size_t)(mt * 16 + lr) * LL + l0 + lg * 8);
            Sacc[mt][0] = __builtin_amdgcn_mfma_f32_16x16x32_bf16(kf, ub0, Sacc[mt][0], 0,0,0);
            Sacc[mt][1] = __builtin_amdgcn_mfma_f32_16x16x32_bf16(kf, ub1, Sacc[mt][1], 0,0,0);
        }
    }
}

// ------------------------------------------------- per-head stats
__global__ __launch_bounds__(256) void stats_k(
    const float* __restrict__ ls, const float* __restrict__ llb,
    const float* __restrict__ dox, const float* __restrict__ v,
    float* __restrict__ stats)
{
    int bl = blockIdx.x;
    int b = bl >> 12, l = bl & (LL - 1);
    int wv = threadIdx.x >> 6, ln = threadIdx.x & 63;
    size_t ibase = (size_t)bl * DD + wv * DH;
    size_t dbase = (((size_t)(b * HH + wv)) * LL + l) * DH;
#pragma unroll
    for (int tn = 0; tn < 4; ++tn) {
        const float* p; size_t base;
        if (tn == 0)      { p = ls;  base = ibase; }
        else if (tn == 1) { p = llb; base = ibase; }
        else if (tn == 2) { p = dox; base = dbase; }
        else              { p = v;   base = ibase; }
        float4 x = *(const float4*)(p + base + ln * 4);
        float sm = x.x + x.y + x.z + x.w;
        float sq = x.x*x.x + x.y*x.y + x.z*x.z + x.w*x.w;
        float sa = fabsf(x.x) + fabsf(x.y) + fabsf(x.z) + fabsf(x.w);
#pragma unroll
        for (int off = 32; off > 0; off >>= 1) {
            sm += __shfl_down(sm, off);
            sq += __shfl_down(sq, off);
            sa += __shfl_down(sa, off);
        }
        if (ln == 0) {
            float mean = sm * (1.0f / DH);
            float var = sq * (1.0f / DH) - mean * mean;
            float am = sa * (1.0f / DH);
            float l2 = sqrtf(sq);
            *(float4*)(stats + (size_t)bl * 64 + wv * 16 + tn * 4) =
                make_float4(mean, var, am, l2);
        }
    }
}

// ------------------------------------------------- gate finish
__global__ __launch_bounds__(256) void gate_fin_k(
    const float* __restrict__ hpart, const float* __restrict__ stats,
    const float* __restrict__ w1, const float* __restrict__ w2,
    const float* __restrict__ b2, const float* __restrict__ ltemp,
    float* __restrict__ fw)
{
    int bl = blockIdx.x;
    int t = threadIdx.x;
    float temp = log1pf(expf(ltemp[0])) + 1e-4f;
    __shared__ float st[HH][16];
    __shared__ float red[4][4];
    if (t < 64) st[t >> 4][t & 15] = stats[(size_t)bl * 64 + t];
    const float* hp = hpart + (size_t)bl * DD;
    __syncthreads();
    for (int h = 0; h < HH; ++h) {
        float lg0=0.f, lg1=0.f, lg2=0.f, lg3=0.f;
#pragma unroll
        for (int ii = 0; ii < 4; ++ii) {
            int e = t * 4 + ii;
            float x = hp[e];
            const float* wr = w1 + (size_t)e * 1040 + 1024;
#pragma unroll
            for (int s = 0; s < 16; ++s) x += st[h][s] * wr[s];
            float g = 0.5f * x * (1.0f + erff(x * 0.70710678118654752f));
            lg0 += g * w2[e];
            lg1 += g * w2[1024 + e];
            lg2 += g * w2[2048 + e];
            lg3 += g * w2[3072 + e];
        }
#pragma unroll
        for (int off = 32; off > 0; off >>= 1) {
            lg0 += __shfl_down(lg0, off); lg1 += __shfl_down(lg1, off);
            lg2 += __shfl_down(lg2, off); lg3 += __shfl_down(lg3, off);
        }
        int wv = t >> 6, ln = t & 63;
        if (ln == 0) { red[wv][0]=lg0; red[wv][1]=lg1; red[wv][2]=lg2; red[wv][3]=lg3; }
        __syncthreads();
        if (t == 0) {
            float l0 = (red[0][0]+red[1][0]+red[2][0]+red[3][0] + b2[0]) / temp;
            float l1 = (red[0][1]+red[1][1]+red[2][1]+red[3][1] + b2[1]) / temp;
            float l2 = (red[0][2]+red[1][2]+red[2][2]+red[3][2] + b2[2]) / temp;
            float l3 = (red[0][3]+red[1][3]+red[2][3]+red[3][3] + b2[3]) / temp;
            float m = fmaxf(fmaxf(l0,l1), fmaxf(l2,l3));
            float e0 = expf(l0-m), e1 = expf(l1-m), e2 = expf(l2-m), e3 = expf(l3-m);
            float inv = 1.0f / (e0+e1+e2+e3);
            *(float4*)(fw + (size_t)bl * 16 + h * 4) =
                make_float4(e0*inv, e1*inv, e2*inv, e3*inv);
        }
        __syncthreads();
    }
}

// ------------------------------------------------- combine + rms norm
__global__ __launch_bounds__(256) void combine_k(
    const float* __restrict__ ls, const float* __restrict__ llb,
    const float* __restrict__ dox, const float* __restrict__ v,
    const float* __restrict__ fw, const float* __restrict__ rss,
    const float* __restrict__ rsl, const float* __restrict__ onw,
    float* __restrict__ opre)
{
    int h = blockIdx.x & (HH - 1);
    int bl = blockIdx.x >> 2;
    int b = bl >> 12, l = bl & (LL - 1);
    int d = threadIdx.x;
    size_t i1 = (size_t)blockIdx.x * DH + d;
    size_t i2 = (((size_t)(b * HH + h)) * LL + l) * DH + d;
    const float* fwp = fw + (size_t)blockIdx.x * 4;
    float f0 = fwp[0], f1 = fwp[1], f2 = fwp[2], f3 = fwp[3];
    float aS = rss[0], aL = rsl[0];
    float vls = ls[i1], vll = llb[i1], vd = dox[i2], vv = v[i1];
    float o = f0*vls + f1*vll + f2*vd + f3*vv + aS*vls + aL*vll;
    float s = o * o;
#pragma unroll
    for (int off = 32; off > 0; off >>= 1) s += __shfl_down(s, off);
    __shared__ float red[4];
    int wv = threadIdx.x >> 6, ln = threadIdx.x & 63;
    if (ln == 0) red[wv] = s;
    __syncthreads();
    float ms = (red[0] + red[1] + red[2] + red[3]) * (1.0f / DH);
    opre[(size_t)bl * DD + h * DH + d] = o * rsqrtf(ms + 1e-5f) * onw[d];
}

// ================================================================ launch
extern "C" void kernel_launch(void* const* d_in, const int* in_sizes, int n_in,
                              void* d_out, int out_size, void* d_ws, size_t ws_size,
                              hipStream_t stream)
{
    const float* hs  = (const float*)d_in[0];
    const float* qw  = (const float*)d_in[1];
    const float* kw  = (const float*)d_in[2];
    const float* vw  = (const float*)d_in[3];
    const float* bw  = (const float*)d_in[4];
    const float* qcw = (const float*)d_in[5];
    const float* kcw = (const float*)d_in[6];
    const float* vcw = (const float*)d_in[7];
    const float* fsw = (const float*)d_in[8];
    const float* flw = (const float*)d_in[9];
    const float* w1  = (const float*)d_in[10];
    const float* b1  = (const float*)d_in[11];
    const float* w2  = (const float*)d_in[12];
    const float* b2  = (const float*)d_in[13];
    const float* lt  = (const float*)d_in[14];
    const float* rss = (const float*)d_in[15];
    const float* rsl = (const float*)d_in[16];
    const float* onw = (const float*)d_in[17];
    const float* opw = (const float*)d_in[18];
    float* out = (float*)d_out;

    // workspace (~173 MB):
    // [0,BLD): tmp f32 | phase2-3: ktbuf(shorts)+uTbuf(shorts) | phase4: lsbuf
    // [BLD,2BLD): vbuf
    // [2BLD,3BLD): phase1: hsb(shorts, first half) | phase3+: dbuf
    // [3BLD,4BLD): qbuf+kbuf shorts | later hpart/opre f32
    // [4BLD,5BLD): ubuf+wbuf shorts | later llbuf f32
    // [5BLD,...): attnb(shorts 1M) | statsb | fwbuf | betab
    float* wsf = (float*)d_ws;
    float* tmp   = wsf;
    unsigned short* ktbuf = (unsigned short*)tmp;
    unsigned short* uTbuf = (unsigned short*)(wsf + BLD/2);
    float* vbuf  = wsf + BLD;
    float* dbuf  = wsf + 2*BLD;
    unsigned short* hsb = (unsigned short*)(wsf + 2*BLD);
    unsigned short* qbuf = (unsigned short*)(wsf + 3*BLD);
    unsigned short* kbuf = qbuf + BLD;
    float* hpart = wsf + 3*BLD;
    float* opre  = wsf + 3*BLD;
    unsigned short* ubuf = (unsigned short*)(wsf + 4*BLD);
    unsigned short* wbuf = ubuf + BLD;
    float* llbuf = wsf + 4*BLD;
    float* lsbuf = tmp;
    unsigned short* attnb = (unsigned short*)(wsf + 5*BLD);
    float* statsb = wsf + 5*BLD + 524288;
    float* fwbuf  = statsb + (size_t)BL*HH*16;
    float* betab  = fwbuf + (size_t)BL*HH*4;

    dim3 gg(8, 64);   // N/128, M/128

    cvt_bf_k<<<(int)(BLD/1024), 256, 0, stream>>>(hs, hsb);

    gemm_mfma_bfA<<<gg, 256, 0, stream>>>(hsb, DD, qw, DD, tmp, DD, DD);
    convnorm_qk_k<<<BL*HH, 256, 0, stream>>>(tmp, qcw, qbuf);
    gemm_mfma_bfA<<<gg, 256, 0, stream>>>(hsb, DD, kw, DD, tmp, DD, DD);
    convnorm_qk_k<<<BL*HH, 256, 0, stream>>>(tmp, kcw, kbuf);
    gemm_mfma_bfA<<<gg, 256, 0, stream>>>(hsb, DD, vw, DD, tmp, DD, DD);
    conv_silu_k<<<(int)(BLD/256), 256, 0, stream>>>(tmp, vcw, vbuf);

    beta_k<<<BL, 256, 0, stream>>>(hs, bw, betab);

    tr_k<<<8*64*4, 256, 0, stream>>>(kbuf, ktbuf);
    chunk_prep_k<<<BB*HH*NC, 256, 0, stream>>>(qbuf, kbuf, vbuf, betab, ubuf, wbuf, attnb);
    tru_k<<<8*64*4, 256, 0, stream>>>(ubuf, uTbuf);

    scan3_k<<<BB*HH*2, 256, 0, stream>>>(qbuf, ktbuf, uTbuf, wbuf, attnb, dbuf);

    fir2_k<5><<<BB*64*16, 256, 0, stream>>>(vbuf, fsw, lsbuf);
    fir2_k<64><<<BB*64*16, 256, 0, stream>>>(vbuf, flw, llbuf);

    stats_k<<<BL, 256, 0, stream>>>(lsbuf, llbuf, dbuf, vbuf, statsb);

    gemm_mfma<<<gg, 256, 0, stream>>>(hs, DD, w1, 1040, b1, hpart, DD, DD);
    gate_fin_k<<<BL, 256, 0, stream>>>(hpart, statsb, w1, w2, b2, lt, fwbuf);

    combine_k<<<BL*HH, 256, 0, stream>>>(lsbuf, llbuf, dbuf, vbuf, fwbuf, rss, rsl, onw, opre);

    gemm_mfma<<<gg, 256, 0, stream>>>(opre, DD, opw, DD, nullptr, out, DD, DD);
}

// Round 6
// 1464.535 us; speedup vs baseline: 2.1656x; 2.1656x over previous
//
#include <hip/hip_runtime.h>
#include <hip/hip_bf16.h>

#define BB 2
#define LL 4096
#define DD 1024
#define HH 4
#define DH 256
#define CH 32
#define NC (LL/CH)     // 128
#define BL (BB*LL)     // 8192
#define BLD ((size_t)BB*LL*DD) // 8388608

typedef __attribute__((ext_vector_type(8))) short short8;
typedef __attribute__((ext_vector_type(4))) float floatx4;

__device__ __forceinline__ float bf2f(unsigned short u) {
    union { float f; unsigned int i; } x; x.i = ((unsigned int)u) << 16; return x.f;
}
__device__ __forceinline__ unsigned short f2bf(float f) {
    union { float f; unsigned int i; } x; x.f = f;
    unsigned int r = x.i + 0x7FFFu + ((x.i >> 16) & 1u);
    return (unsigned short)(r >> 16);
}
// pack two f32 -> (bf16(b)<<16)|bf16(a), round-half-up
__device__ __forceinline__ unsigned int pkbf(float a, float b) {
    unsigned int ua = __float_as_uint(a) + 0x8000u;
    unsigned int ub = __float_as_uint(b) + 0x8000u;
    return __builtin_amdgcn_perm(ub, ua, 0x07060302);
}

// ---------------------------------------------------------------- f32 -> bf16 bulk convert
__global__ __launch_bounds__(256) void cvt_bf_k(
    const float* __restrict__ x, unsigned short* __restrict__ y)
{
    size_t i = ((size_t)blockIdx.x * 256 + threadIdx.x) * 4;
    float4 v = *(const float4*)(x + i);
    ushort4 o;
    o.x = f2bf(v.x); o.y = f2bf(v.y); o.z = f2bf(v.z); o.w = f2bf(v.w);
    *(ushort4*)(y + i) = o;
}

// ---------------------------------------------------------------- bf16 MFMA GEMM (NT), f32 A
__global__ __launch_bounds__(256) void gemm_mfma(
    const float* __restrict__ A, int lda,
    const float* __restrict__ W, int ldw,
    const float* __restrict__ bias,
    float* __restrict__ C, int ldc, int K)
{
    __shared__ unsigned short Abuf[128][56];
    __shared__ unsigned short Bbuf[128][56];
    const int t = threadIdx.x;
    const int wave = t >> 6, lane = t & 63;
    const int wm = wave >> 1, wn = wave & 1;
    const int row0 = blockIdx.y * 128, col0 = blockIdx.x * 128;

    floatx4 acc[4][4];
#pragma unroll
    for (int i = 0; i < 4; ++i)
#pragma unroll
        for (int j = 0; j < 4; ++j) acc[i][j] = (floatx4){0.f, 0.f, 0.f, 0.f};

    const int fr = lane & 15, fk = (lane >> 4) * 8;

    for (int kt = 0; kt < K; kt += 32) {
        __syncthreads();
#pragma unroll
        for (int it = 0; it < 2; ++it) {
            int idx = t + it * 256;
            int r = idx >> 2, s = (idx & 3) * 8;
            const float* ap = A + (size_t)(row0 + r) * lda + kt + s;
            float4 a0 = *(const float4*)(ap);
            float4 a1 = *(const float4*)(ap + 4);
            ushort4 p0, p1;
            p0.x = f2bf(a0.x); p0.y = f2bf(a0.y); p0.z = f2bf(a0.z); p0.w = f2bf(a0.w);
            p1.x = f2bf(a1.x); p1.y = f2bf(a1.y); p1.z = f2bf(a1.z); p1.w = f2bf(a1.w);
            *(ushort4*)&Abuf[r][s]     = p0;
            *(ushort4*)&Abuf[r][s + 4] = p1;
            const float* wp = W + (size_t)(col0 + r) * ldw + kt + s;
            float4 b0 = *(const float4*)(wp);
            float4 b1 = *(const float4*)(wp + 4);
            ushort4 q0, q1;
            q0.x = f2bf(b0.x); q0.y = f2bf(b0.y); q0.z = f2bf(b0.z); q0.w = f2bf(b0.w);
            q1.x = f2bf(b1.x); q1.y = f2bf(b1.y); q1.z = f2bf(b1.z); q1.w = f2bf(b1.w);
            *(ushort4*)&Bbuf[r][s]     = q0;
            *(ushort4*)&Bbuf[r][s + 4] = q1;
        }
        __syncthreads();

        short8 afrag[4], bfrag[4];
#pragma unroll
        for (int i = 0; i < 4; ++i) {
            afrag[i] = *(const short8*)&Abuf[wm * 64 + i * 16 + fr][fk];
            bfrag[i] = *(const short8*)&Bbuf[wn * 64 + i * 16 + fr][fk];
        }
#pragma unroll
        for (int i = 0; i < 4; ++i)
#pragma unroll
            for (int j = 0; j < 4; ++j)
                acc[i][j] = __builtin_amdgcn_mfma_f32_16x16x32_bf16(
                    afrag[i], bfrag[j], acc[i][j], 0, 0, 0);
    }

    const int fc = lane & 15, frow = (lane >> 4) * 4;
#pragma unroll
    for (int j = 0; j < 4; ++j) {
        int col = col0 + wn * 64 + j * 16 + fc;
        float bv = bias ? bias[col] : 0.0f;
#pragma unroll
        for (int i = 0; i < 4; ++i) {
#pragma unroll
            for (int r = 0; r < 4; ++r) {
                int row = row0 + wm * 64 + i * 16 + frow + r;
                C[(size_t)row * ldc + col] = acc[i][j][r] + bv;
            }
        }
    }
}

// ---------------------------------------------------------------- bf16 MFMA GEMM (NT), bf16 A
__global__ __launch_bounds__(256) void gemm_mfma_bfA(
    const unsigned short* __restrict__ A, int lda,
    const float* __restrict__ W, int ldw,
    float* __restrict__ C, int ldc, int K)
{
    __shared__ unsigned short Abuf[128][56];
    __shared__ unsigned short Bbuf[128][56];
    const int t = threadIdx.x;
    const int wave = t >> 6, lane = t & 63;
    const int wm = wave >> 1, wn = wave & 1;
    const int row0 = blockIdx.y * 128, col0 = blockIdx.x * 128;

    floatx4 acc[4][4];
#pragma unroll
    for (int i = 0; i < 4; ++i)
#pragma unroll
        for (int j = 0; j < 4; ++j) acc[i][j] = (floatx4){0.f, 0.f, 0.f, 0.f};

    const int fr = lane & 15, fk = (lane >> 4) * 8;

    for (int kt = 0; kt < K; kt += 32) {
        __syncthreads();
#pragma unroll
        for (int it = 0; it < 2; ++it) {
            int idx = t + it * 256;
            int r = idx >> 2, s = (idx & 3) * 8;
            uint4 av = *(const uint4*)(A + (size_t)(row0 + r) * lda + kt + s);
            *(uint4*)&Abuf[r][s] = av;
            const float* wp = W + (size_t)(col0 + r) * ldw + kt + s;
            float4 b0 = *(const float4*)(wp);
            float4 b1 = *(const float4*)(wp + 4);
            ushort4 q0, q1;
            q0.x = f2bf(b0.x); q0.y = f2bf(b0.y); q0.z = f2bf(b0.z); q0.w = f2bf(b0.w);
            q1.x = f2bf(b1.x); q1.y = f2bf(b1.y); q1.z = f2bf(b1.z); q1.w = f2bf(b1.w);
            *(ushort4*)&Bbuf[r][s]     = q0;
            *(ushort4*)&Bbuf[r][s + 4] = q1;
        }
        __syncthreads();

        short8 afrag[4], bfrag[4];
#pragma unroll
        for (int i = 0; i < 4; ++i) {
            afrag[i] = *(const short8*)&Abuf[wm * 64 + i * 16 + fr][fk];
            bfrag[i] = *(const short8*)&Bbuf[wn * 64 + i * 16 + fr][fk];
        }
#pragma unroll
        for (int i = 0; i < 4; ++i)
#pragma unroll
            for (int j = 0; j < 4; ++j)
                acc[i][j] = __builtin_amdgcn_mfma_f32_16x16x32_bf16(
                    afrag[i], bfrag[j], acc[i][j], 0, 0, 0);
    }

    const int fc = lane & 15, frow = (lane >> 4) * 4;
#pragma unroll
    for (int j = 0; j < 4; ++j) {
        int col = col0 + wn * 64 + j * 16 + fc;
#pragma unroll
        for (int i = 0; i < 4; ++i) {
#pragma unroll
            for (int r = 0; r < 4; ++r) {
                int row = row0 + wm * 64 + i * 16 + frow + r;
                C[(size_t)row * ldc + col] = acc[i][j][r];
            }
        }
    }
}

// --------------------------------------- causal dwconv K=4 + silu + head-l2norm -> bf16
__global__ __launch_bounds__(256) void convnorm_qk_k(
    const float* __restrict__ x, const float* __restrict__ w,
    unsigned short* __restrict__ y)
{
    int bl = blockIdx.x >> 2;
    int h  = blockIdx.x & 3;
    int l  = bl & (LL - 1);
    int d  = threadIdx.x;
    int c  = h * DH + d;
    const float* wp = w + (size_t)c * 4;
    const float* xp = x + (size_t)bl * DD + c;
    float acc = wp[3] * xp[0];
    if (l >= 1) acc += wp[2] * xp[-(int)DD];
    if (l >= 2) acc += wp[1] * xp[-2*(int)DD];
    if (l >= 3) acc += wp[0] * xp[-3*(int)DD];
    acc = acc / (1.0f + expf(-acc));
    float s = acc * acc;
#pragma unroll
    for (int off = 32; off > 0; off >>= 1) s += __shfl_down(s, off);
    __shared__ float red[4];
    int wv = threadIdx.x >> 6, ln = threadIdx.x & 63;
    if (ln == 0) red[wv] = s;
    __syncthreads();
    float tot = red[0] + red[1] + red[2] + red[3];
    y[(size_t)bl * DD + c] = f2bf(acc * rsqrtf(tot));
}

// ------------------------------------------------- causal depthwise conv K=4 + silu (f32)
__global__ __launch_bounds__(256) void conv_silu_k(
    const float* __restrict__ x, const float* __restrict__ w, float* __restrict__ y)
{
    size_t idx = (size_t)blockIdx.x * 256 + threadIdx.x;
    int c = (int)(idx & (DD - 1));
    int bl = (int)(idx >> 10);
    int l = bl & (LL - 1);
    const float* wp = w + (size_t)c * 4;
    const float* xp = x + (size_t)bl * DD + c;
    float acc = wp[3] * xp[0];
    if (l >= 1) acc += wp[2] * xp[-(int)DD];
    if (l >= 2) acc += wp[1] * xp[-2*(int)DD];
    if (l >= 3) acc += wp[0] * xp[-3*(int)DD];
    y[idx] = acc / (1.0f + expf(-acc));
}

// ------------------------------------------------- FIR causal depthwise conv, LDS-tiled
template<int K>
__global__ __launch_bounds__(256) void fir2_k(
    const float* __restrict__ x, const float* __restrict__ filt, float* __restrict__ y)
{
    const int ctile = blockIdx.x & 15;
    const int ltile = (blockIdx.x >> 4) & 63;
    const int b = blockIdx.x >> 10;
    const int RT = 64 + K - 1;
    __shared__ float xs[RT][64];
    __shared__ float fs[64][K + 1];
    const int t = threadIdx.x;
    const int l0 = ltile * 64;

    for (int i = t; i < RT * 16; i += 256) {
        int li = i >> 4, c4 = (i & 15) * 4;
        int l = l0 - (K - 1) + li;
        float4 v = make_float4(0.f, 0.f, 0.f, 0.f);
        if (l >= 0)
            v = *(const float4*)(x + ((size_t)b * LL + l) * DD + ctile * 64 + c4);
        *(float4*)&xs[li][c4] = v;
    }
    for (int i = t; i < 64 * K; i += 256) {
        fs[i / K][i % K] = filt[(size_t)ctile * 64 * K + i];
    }
    __syncthreads();

    const int c = t & 63, lg = t >> 6;
    float acc[16];
#pragma unroll
    for (int o = 0; o < 16; ++o) acc[o] = 0.f;
#pragma unroll
    for (int j = 0; j < 16 + K - 1; ++j) {
        float xv = xs[lg * 16 + j][c];
#pragma unroll
        for (int o = 0; o < 16; ++o) {
            int tap = j - o;
            if (tap >= 0 && tap < K) acc[o] += fs[c][tap] * xv;
        }
    }
    size_t base = ((size_t)b * LL + l0 + lg * 16) * DD + ctile * 64 + c;
#pragma unroll
    for (int o = 0; o < 16; ++o)
        y[base + (size_t)o * DD] = acc[o];
}

// ------------------------------------------------- beta = sigmoid(hs @ b_proj^T)
__global__ __launch_bounds__(256) void beta_k(
    const float* __restrict__ hs, const float* __restrict__ bw, float* __restrict__ beta)
{
    int bl = blockIdx.x;
    const float* xr = hs + (size_t)bl * DD;
    float a0=0.f,a1=0.f,a2=0.f,a3=0.f;
    for (int k = threadIdx.x; k < DD; k += 256) {
        float xv = xr[k];
        a0 += xv * bw[k];
        a1 += xv * bw[DD + k];
        a2 += xv * bw[2*DD + k];
        a3 += xv * bw[3*DD + k];
    }
#pragma unroll
    for (int off = 32; off > 0; off >>= 1) {
        a0 += __shfl_down(a0, off); a1 += __shfl_down(a1, off);
        a2 += __shfl_down(a2, off); a3 += __shfl_down(a3, off);
    }
    __shared__ float red[4][4];
    int wv = threadIdx.x >> 6, ln = threadIdx.x & 63;
    if (ln == 0) { red[wv][0]=a0; red[wv][1]=a1; red[wv][2]=a2; red[wv][3]=a3; }
    __syncthreads();
    if (threadIdx.x < 4) {
        int h = threadIdx.x;
        float s = red[0][h] + red[1][h] + red[2][h] + red[3][h];
        beta[(size_t)bl * HH + h] = 1.0f / (1.0f + expf(-s));
    }
}

// ------------------------------------------------- k transpose: k[b,l,h*DH+e] -> kT[bh,e,l]
__global__ __launch_bounds__(256) void tr_k(
    const unsigned short* __restrict__ k, unsigned short* __restrict__ kT)
{
    int et = blockIdx.x & 3;
    int lt = (blockIdx.x >> 2) & 63;
    int bh = blockIdx.x >> 8;
    int h = bh & 3, b = bh >> 2;
    __shared__ unsigned short tile[64][72];
    int t = threadIdx.x;
    int tr = t >> 4;
    int tc = (t & 15) * 4;
#pragma unroll
    for (int i = 0; i < 4; ++i) {
        int l = tr + i * 16;
        ushort4 v = *(const ushort4*)(k + ((size_t)b * LL + lt*64 + l) * DD + h * DH + et*64 + tc);
        *(ushort4*)&tile[l][tc] = v;
    }
    __syncthreads();
#pragma unroll
    for (int i = 0; i < 4; ++i) {
        int e = tr + i * 16;
        ushort4 v;
        v.x = tile[tc+0][e]; v.y = tile[tc+1][e];
        v.z = tile[tc+2][e]; v.w = tile[tc+3][e];
        *(ushort4*)(kT + ((size_t)bh * DH + et*64 + e) * LL + (size_t)lt*64 + tc) = v;
    }
}

// ------------------------------------------------- u transpose: u[bh,l,d] -> uT[bh,d,l]
__global__ __launch_bounds__(256) void tru_k(
    const unsigned short* __restrict__ u, unsigned short* __restrict__ uT)
{
    int et = blockIdx.x & 3;
    int lt = (blockIdx.x >> 2) & 63;
    int bh = blockIdx.x >> 8;
    __shared__ unsigned short tile[64][72];
    int t = threadIdx.x;
    int tr = t >> 4;
    int tc = (t & 15) * 4;
#pragma unroll
    for (int i = 0; i < 4; ++i) {
        int l = tr + i * 16;
        ushort4 v = *(const ushort4*)(u + ((size_t)bh * LL + lt*64 + l) * DH + et*64 + tc);
        *(ushort4*)&tile[l][tc] = v;
    }
    __syncthreads();
#pragma unroll
    for (int i = 0; i < 4; ++i) {
        int e = tr + i * 16;
        ushort4 v;
        v.x = tile[tc+0][e]; v.y = tile[tc+1][e];
        v.z = tile[tc+2][e]; v.w = tile[tc+3][e];
        *(ushort4*)(uT + ((size_t)bh * DH + et*64 + e) * LL + (size_t)lt*64 + tc) = v;
    }
}

// ------------------------------------------------- per-chunk prep (attn out bf16)
__global__ __launch_bounds__(256) void chunk_prep_k(
    const unsigned short* __restrict__ q, const unsigned short* __restrict__ k,
    const float* __restrict__ v, const float* __restrict__ beta,
    unsigned short* __restrict__ u_out, unsigned short* __restrict__ w_out,
    unsigned short* __restrict__ attn_out)
{
    int ci = blockIdx.x & (NC - 1);
    int bh = blockIdx.x >> 7;
    int h = bh & (HH - 1), b = bh >> 2;
    __shared__ float kt[CH][DH + 4];
    __shared__ float Am[CH][CH + 1];
    __shared__ float Ab[CH][CH + 1];
    __shared__ float bet[CH];
    int t = threadIdx.x;
    size_t qgbase = (size_t)b * LL + (size_t)ci * CH;

    for (int i = t; i < CH * (DH / 4); i += 256) {
        int r = i >> 6;
        int c4 = (i & 63) * 4;
        ushort4 kv = *(const ushort4*)(k + (qgbase + r) * DD + h * DH + c4);
        kt[r][c4+0] = bf2f(kv.x); kt[r][c4+1] = bf2f(kv.y);
        kt[r][c4+2] = bf2f(kv.z); kt[r][c4+3] = bf2f(kv.w);
    }
    if (t < CH) bet[t] = beta[(qgbase + t) * HH + h];
    __syncthreads();

    int c = t >> 3, e0 = (t & 7) * 4;
    {
        float accA[4] = {0,0,0,0}, accT[4] = {0,0,0,0};
        const unsigned short* qrow = q + (qgbase + c) * DD + h * DH;
        for (int d0 = 0; d0 < DH; d0 += 4) {
            float4 kc = *(const float4*)&kt[c][d0];
            ushort4 qv = *(const ushort4*)(qrow + d0);
            float qx = bf2f(qv.x), qy = bf2f(qv.y), qz = bf2f(qv.z), qw = bf2f(qv.w);
#pragma unroll
            for (int e = 0; e < 4; ++e) {
                float4 ke = *(const float4*)&kt[e0 + e][d0];
                accA[e] += kc.x*ke.x + kc.y*ke.y + kc.z*ke.z + kc.w*ke.w;
                accT[e] += qx*ke.x + qy*ke.y + qz*ke.z + qw*ke.w;
            }
        }
        float bc = bet[c];
        size_t abase = (size_t)blockIdx.x * (CH * CH) + (size_t)c * CH;
#pragma unroll
        for (int e = 0; e < 4; ++e) {
            int ee = e0 + e;
            Am[c][ee] = (ee < c) ? (-bc * accA[e]) : 0.0f;
            attn_out[abase + ee] = (ee <= c) ? f2bf(accT[e]) : (unsigned short)0;
        }
    }
    __syncthreads();

    for (int i = 1; i < CH; ++i) {
        float upd = 0.0f;
        if (t < i) {
#pragma unroll
            for (int kk = 0; kk < CH; ++kk) upd += Am[i][kk] * Am[kk][t];
        }
        __syncthreads();
        if (t < i) Am[i][t] += upd;
        __syncthreads();
    }

    for (int i = t; i < CH * CH; i += 256) {
        int cc = i >> 5, ee = i & 31;
        float val = Am[cc][ee] + (cc == ee ? 1.0f : 0.0f);
        Ab[cc][ee] = val * bet[ee];
    }
    __syncthreads();

    int c2 = t >> 3, dd0 = (t & 7) * 32;
    float accu[32];
#pragma unroll
    for (int j = 0; j < 32; ++j) accu[j] = 0.0f;
    for (int e = 0; e < CH; ++e) {
        float ab = Ab[c2][e];
        const float* vrow = v + (qgbase + e) * DD + h * DH + dd0;
#pragma unroll
        for (int j4 = 0; j4 < 8; ++j4) {
            float4 v4 = *(const float4*)(vrow + j4 * 4);
            accu[j4*4+0] += ab * v4.x; accu[j4*4+1] += ab * v4.y;
            accu[j4*4+2] += ab * v4.z; accu[j4*4+3] += ab * v4.w;
        }
    }
    size_t obase = ((size_t)bh * LL + (size_t)ci * CH + c2) * DH + dd0;
#pragma unroll
    for (int j4 = 0; j4 < 8; ++j4) {
        ushort4 o;
        o.x = f2bf(accu[j4*4+0]); o.y = f2bf(accu[j4*4+1]);
        o.z = f2bf(accu[j4*4+2]); o.w = f2bf(accu[j4*4+3]);
        *(ushort4*)(u_out + obase + j4*4) = o;
    }

#pragma unroll
    for (int j = 0; j < 32; ++j) accu[j] = 0.0f;
    for (int e = 0; e < CH; ++e) {
        float ab = Ab[c2][e];
#pragma unroll
        for (int j4 = 0; j4 < 8; ++j4) {
            float4 v4 = *(const float4*)&kt[e][dd0 + j4*4];
            accu[j4*4+0] += ab * v4.x; accu[j4*4+1] += ab * v4.y;
            accu[j4*4+2] += ab * v4.z; accu[j4*4+3] += ab * v4.w;
        }
    }
#pragma unroll
    for (int j4 = 0; j4 < 8; ++j4) {
        ushort4 o;
        o.x = f2bf(accu[j4*4+0]); o.y = f2bf(accu[j4*4+1]);
        o.z = f2bf(accu[j4*4+2]); o.w = f2bf(accu[j4*4+3]);
        *(ushort4*)(w_out + obase + j4*4) = o;
    }
}

// ------------------------------------------------- chunk scan v4: MFMA + 128 blocks.
// grid = bh(8) x 16 dv-slices of 16 cols. 4 waves; wave w owns S rows e in [64w,64w+64).
// S slice kept in f32 accumulators (4 C-layout tiles/wave) across all 128 chunks.
__global__ __launch_bounds__(256) void scan4_k(
    const unsigned short* __restrict__ q, const unsigned short* __restrict__ kT,
    const unsigned short* __restrict__ uT, const unsigned short* __restrict__ w,
    const unsigned short* __restrict__ attn, float* __restrict__ dout)
{
    const int jb = blockIdx.x & 15;
    const int bh = blockIdx.x >> 4;
    const int h = bh & (HH - 1), b = bh >> 2;
    const int jcol = jb * 16;
    const int wave = threadIdx.x >> 6, lane = threadIdx.x & 63;
    const int lr = lane & 15, lg = lane >> 4;

    __shared__ unsigned short SbT[16][264];   // [col][e] bf16
    __shared__ unsigned short uadjT[16][40];  // [col][cc] bf16
    __shared__ float Pred[4][64][17];         // [src wave][m-row: w0,w1,q0,q1][col]

    floatx4 Sacc[4];                          // e-tile mt: e = 64*wave + 16*mt + lg*4 + r
#pragma unroll
    for (int mt = 0; mt < 4; ++mt) Sacc[mt] = (floatx4){0.f,0.f,0.f,0.f};

    const unsigned short* qb  = q + (size_t)b * LL * DD + h * DH;
    const unsigned short* wb  = w + (size_t)bh * LL * DH;
    const unsigned short* uTb = uT + (size_t)bh * DH * LL;
    const unsigned short* kTb = kT + (size_t)bh * DH * LL;
    float* db = dout + (size_t)bh * LL * DH;

    for (int ci = 0; ci < NC; ++ci) {
        const int l0 = ci * CH;

        // 1) pack wave's S slice -> SbT[col][e]
#pragma unroll
        for (int mt = 0; mt < 4; ++mt) {
            int e0 = 64 * wave + 16 * mt + lg * 4;
            *(unsigned int*)&SbT[lr][e0]     = pkbf(Sacc[mt][0], Sacc[mt][1]);
            *(unsigned int*)&SbT[lr][e0 + 2] = pkbf(Sacc[mt][2], Sacc[mt][3]);
        }
        __syncthreads();   // (a)

        // 2) partial [w0,w1,q0,q1] @ S over wave's e-slice (K = 64)
        floatx4 P0 = (floatx4){0.f,0.f,0.f,0.f}, P1 = P0, P2 = P0, P3 = P0;
#pragma unroll
        for (int kt = 0; kt < 2; ++kt) {
            const int e0 = 64 * wave + 32 * kt + lg * 8;
            short8 aw0 = *(const short8*)(wb + (size_t)(l0 + lr) * DH + e0);
            short8 aw1 = *(const short8*)(wb + (size_t)(l0 + 16 + lr) * DH + e0);
            short8 aq0 = *(const short8*)(qb + (size_t)(l0 + lr) * DD + e0);
            short8 aq1 = *(const short8*)(qb + (size_t)(l0 + 16 + lr) * DD + e0);
            short8 sb  = *(const short8*)&SbT[lr][e0];
            P0 = __builtin_amdgcn_mfma_f32_16x16x32_bf16(aw0, sb, P0, 0,0,0);
            P1 = __builtin_amdgcn_mfma_f32_16x16x32_bf16(aw1, sb, P1, 0,0,0);
            P2 = __builtin_amdgcn_mfma_f32_16x16x32_bf16(aq0, sb, P2, 0,0,0);
            P3 = __builtin_amdgcn_mfma_f32_16x16x32_bf16(aq1, sb, P3, 0,0,0);
        }
#pragma unroll
        for (int r = 0; r < 4; ++r) {
            Pred[wave][ 0 + lg * 4 + r][lr] = P0[r];
            Pred[wave][16 + lg * 4 + r][lr] = P1[r];
            Pred[wave][32 + lg * 4 + r][lr] = P2[r];
            Pred[wave][48 + lg * 4 + r][lr] = P3[r];
        }
        __syncthreads();   // (b)

        // 3) reduce: wave owns m-tile = wave (0:w0, 1:w1, 2:q0, 3:q1)
        float red[4];
#pragma unroll
        for (int r = 0; r < 4; ++r) {
            int m = wave * 16 + lg * 4 + r;
            red[r] = Pred[0][m][lr] + Pred[1][m][lr] + Pred[2][m][lr] + Pred[3][m][lr];
        }

        // 4) waves 0,1: uadj = u - w@S -> uadjT[col][cc]
        if (wave < 2) {
            ushort4 u4 = *(const ushort4*)(uTb + (size_t)(jcol + lr) * LL + l0 + wave * 16 + lg * 4);
            float ua0 = bf2f(u4.x) - red[0];
            float ua1 = bf2f(u4.y) - red[1];
            float ua2 = bf2f(u4.z) - red[2];
            float ua3 = bf2f(u4.w) - red[3];
            int cc0 = wave * 16 + lg * 4;
            *(unsigned int*)&uadjT[lr][cc0]     = pkbf(ua0, ua1);
            *(unsigned int*)&uadjT[lr][cc0 + 2] = pkbf(ua2, ua3);
        }
        __syncthreads();   // (c)

        short8 ub = *(const short8*)&uadjT[lr][lg * 8];   // B-frag: n=col, k=cc

        // 5) waves 2,3: O = q@S + attn@uadj -> dout
        if (wave >= 2) {
            const unsigned short* ac = attn + ((size_t)bh * NC + ci) * (CH * CH);
            short8 af = *(const short8*)(ac + (size_t)((wave - 2) * 16 + lr) * CH + lg * 8);
            floatx4 Ot = (floatx4){red[0], red[1], red[2], red[3]};
            Ot = __builtin_amdgcn_mfma_f32_16x16x32_bf16(af, ub, Ot, 0,0,0);
#pragma unroll
            for (int r = 0; r < 4; ++r)
                db[(size_t)(l0 + (wave - 2) * 16 + lg * 4 + r) * DH + jcol + lr] = Ot[r];
        }

        // 6) S slice += kT @ uadj  (K = 32)
#pragma unroll
        for (int mt = 0; mt < 4; ++mt) {
            short8 kf = *(const short8*)(kTb + (size_t)(64 * wave + 16 * mt + lr) * LL + l0 + lg * 8);
            Sacc[mt] = __builtin_amdgcn_mfma_f32_16x16x32_bf16(kf, ub, Sacc[mt], 0,0,0);
        }
        __syncthreads();   // protects SbT/uadjT/Pred reuse next chunk
    }
}

// ------------------------------------------------- per-head stats
__global__ __launch_bounds__(256) void stats_k(
    const float* __restrict__ ls, const float* __restrict__ llb,
    const float* __restrict__ dox, const float* __restrict__ v,
    float* __restrict__ stats)
{
    int bl = blockIdx.x;
    int b = bl >> 12, l = bl & (LL - 1);
    int wv = threadIdx.x >> 6, ln = threadIdx.x & 63;
    size_t ibase = (size_t)bl * DD + wv * DH;
    size_t dbase = (((size_t)(b * HH + wv)) * LL + l) * DH;
#pragma unroll
    for (int tn = 0; tn < 4; ++tn) {
        const float* p; size_t base;
        if (tn == 0)      { p = ls;  base = ibase; }
        else if (tn == 1) { p = llb; base = ibase; }
        else if (tn == 2) { p = dox; base = dbase; }
        else              { p = v;   base = ibase; }
        float4 x = *(const float4*)(p + base + ln * 4);
        float sm = x.x + x.y + x.z + x.w;
        float sq = x.x*x.x + x.y*x.y + x.z*x.z + x.w*x.w;
        float sa = fabsf(x.x) + fabsf(x.y) + fabsf(x.z) + fabsf(x.w);
#pragma unroll
        for (int off = 32; off > 0; off >>= 1) {
            sm += __shfl_down(sm, off);
            sq += __shfl_down(sq, off);
            sa += __shfl_down(sa, off);
        }
        if (ln == 0) {
            float mean = sm * (1.0f / DH);
            float var = sq * (1.0f / DH) - mean * mean;
            float am = sa * (1.0f / DH);
            float l2 = sqrtf(sq);
            *(float4*)(stats + (size_t)bl * 64 + wv * 16 + tn * 4) =
                make_float4(mean, var, am, l2);
        }
    }
}

// ------------------------------------------------- gate finish
__global__ __launch_bounds__(256) void gate_fin_k(
    const float* __restrict__ hpart, const float* __restrict__ stats,
    const float* __restrict__ w1, const float* __restrict__ w2,
    const float* __restrict__ b2, const float* __restrict__ ltemp,
    float* __restrict__ fw)
{
    int bl = blockIdx.x;
    int t = threadIdx.x;
    float temp = log1pf(expf(ltemp[0])) + 1e-4f;
    __shared__ float st[HH][16];
    __shared__ float red[4][4];
    if (t < 64) st[t >> 4][t & 15] = stats[(size_t)bl * 64 + t];
    const float* hp = hpart + (size_t)bl * DD;
    __syncthreads();
    for (int h = 0; h < HH; ++h) {
        float lg0=0.f, lg1=0.f, lg2=0.f, lg3=0.f;
#pragma unroll
        for (int ii = 0; ii < 4; ++ii) {
            int e = t * 4 + ii;
            float x = hp[e];
            const float* wr = w1 + (size_t)e * 1040 + 1024;
#pragma unroll
            for (int s = 0; s < 16; ++s) x += st[h][s] * wr[s];
            float g = 0.5f * x * (1.0f + erff(x * 0.70710678118654752f));
            lg0 += g * w2[e];
            lg1 += g * w2[1024 + e];
            lg2 += g * w2[2048 + e];
            lg3 += g * w2[3072 + e];
        }
#pragma unroll
        for (int off = 32; off > 0; off >>= 1) {
            lg0 += __shfl_down(lg0, off); lg1 += __shfl_down(lg1, off);
            lg2 += __shfl_down(lg2, off); lg3 += __shfl_down(lg3, off);
        }
        int wv = t >> 6, ln = t & 63;
        if (ln == 0) { red[wv][0]=lg0; red[wv][1]=lg1; red[wv][2]=lg2; red[wv][3]=lg3; }
        __syncthreads();
        if (t == 0) {
            float l0 = (red[0][0]+red[1][0]+red[2][0]+red[3][0] + b2[0]) / temp;
            float l1 = (red[0][1]+red[1][1]+red[2][1]+red[3][1] + b2[1]) / temp;
            float l2 = (red[0][2]+red[1][2]+red[2][2]+red[3][2] + b2[2]) / temp;
            float l3 = (red[0][3]+red[1][3]+red[2][3]+red[3][3] + b2[3]) / temp;
            float m = fmaxf(fmaxf(l0,l1), fmaxf(l2,l3));
            float e0 = expf(l0-m), e1 = expf(l1-m), e2 = expf(l2-m), e3 = expf(l3-m);
            float inv = 1.0f / (e0+e1+e2+e3);
            *(float4*)(fw + (size_t)bl * 16 + h * 4) =
                make_float4(e0*inv, e1*inv, e2*inv, e3*inv);
        }
        __syncthreads();
    }
}

// ------------------------------------------------- combine + rms norm
__global__ __launch_bounds__(256) void combine_k(
    const float* __restrict__ ls, const float* __restrict__ llb,
    const float* __restrict__ dox, const float* __restrict__ v,
    const float* __restrict__ fw, const float* __restrict__ rss,
    const float* __restrict__ rsl, const float* __restrict__ onw,
    float* __restrict__ opre)
{
    int h = blockIdx.x & (HH - 1);
    int bl = blockIdx.x >> 2;
    int b = bl >> 12, l = bl & (LL - 1);
    int d = threadIdx.x;
    size_t i1 = (size_t)blockIdx.x * DH + d;
    size_t i2 = (((size_t)(b * HH + h)) * LL + l) * DH + d;
    const float* fwp = fw + (size_t)blockIdx.x * 4;
    float f0 = fwp[0], f1 = fwp[1], f2 = fwp[2], f3 = fwp[3];
    float aS = rss[0], aL = rsl[0];
    float vls = ls[i1], vll = llb[i1], vd = dox[i2], vv = v[i1];
    float o = f0*vls + f1*vll + f2*vd + f3*vv + aS*vls + aL*vll;
    float s = o * o;
#pragma unroll
    for (int off = 32; off > 0; off >>= 1) s += __shfl_down(s, off);
    __shared__ float red[4];
    int wv = threadIdx.x >> 6, ln = threadIdx.x & 63;
    if (ln == 0) red[wv] = s;
    __syncthreads();
    float ms = (red[0] + red[1] + red[2] + red[3]) * (1.0f / DH);
    opre[(size_t)bl * DD + h * DH + d] = o * rsqrtf(ms + 1e-5f) * onw[d];
}

// ================================================================ launch
extern "C" void kernel_launch(void* const* d_in, const int* in_sizes, int n_in,
                              void* d_out, int out_size, void* d_ws, size_t ws_size,
                              hipStream_t stream)
{
    const float* hs  = (const float*)d_in[0];
    const float* qw  = (const float*)d_in[1];
    const float* kw  = (const float*)d_in[2];
    const float* vw  = (const float*)d_in[3];
    const float* bw  = (const float*)d_in[4];
    const float* qcw = (const float*)d_in[5];
    const float* kcw = (const float*)d_in[6];
    const float* vcw = (const float*)d_in[7];
    const float* fsw = (const float*)d_in[8];
    const float* flw = (const float*)d_in[9];
    const float* w1  = (const float*)d_in[10];
    const float* b1  = (const float*)d_in[11];
    const float* w2  = (const float*)d_in[12];
    const float* b2  = (const float*)d_in[13];
    const float* lt  = (const float*)d_in[14];
    const float* rss = (const float*)d_in[15];
    const float* rsl = (const float*)d_in[16];
    const float* onw = (const float*)d_in[17];
    const float* opw = (const float*)d_in[18];
    float* out = (float*)d_out;

    float* wsf = (float*)d_ws;
    float* tmp   = wsf;
    unsigned short* ktbuf = (unsigned short*)tmp;
    unsigned short* uTbuf = (unsigned short*)(wsf + BLD/2);
    float* vbuf  = wsf + BLD;
    float* dbuf  = wsf + 2*BLD;
    unsigned short* hsb = (unsigned short*)(wsf + 2*BLD);
    unsigned short* qbuf = (unsigned short*)(wsf + 3*BLD);
    unsigned short* kbuf = qbuf + BLD;
    float* hpart = wsf + 3*BLD;
    float* opre  = wsf + 3*BLD;
    unsigned short* ubuf = (unsigned short*)(wsf + 4*BLD);
    unsigned short* wbuf = ubuf + BLD;
    float* llbuf = wsf + 4*BLD;
    float* lsbuf = tmp;
    unsigned short* attnb = (unsigned short*)(wsf + 5*BLD);
    float* statsb = wsf + 5*BLD + 524288;
    float* fwbuf  = statsb + (size_t)BL*HH*16;
    float* betab  = fwbuf + (size_t)BL*HH*4;

    dim3 gg(8, 64);   // N/128, M/128

    cvt_bf_k<<<(int)(BLD/1024), 256, 0, stream>>>(hs, hsb);

    gemm_mfma_bfA<<<gg, 256, 0, stream>>>(hsb, DD, qw, DD, tmp, DD, DD);
    convnorm_qk_k<<<BL*HH, 256, 0, stream>>>(tmp, qcw, qbuf);
    gemm_mfma_bfA<<<gg, 256, 0, stream>>>(hsb, DD, kw, DD, tmp, DD, DD);
    convnorm_qk_k<<<BL*HH, 256, 0, stream>>>(tmp, kcw, kbuf);
    gemm_mfma_bfA<<<gg, 256, 0, stream>>>(hsb, DD, vw, DD, tmp, DD, DD);
    conv_silu_k<<<(int)(BLD/256), 256, 0, stream>>>(tmp, vcw, vbuf);

    beta_k<<<BL, 256, 0, stream>>>(hs, bw, betab);

    tr_k<<<8*64*4, 256, 0, stream>>>(kbuf, ktbuf);
    chunk_prep_k<<<BB*HH*NC, 256, 0, stream>>>(qbuf, kbuf, vbuf, betab, ubuf, wbuf, attnb);
    tru_k<<<8*64*4, 256, 0, stream>>>(ubuf, uTbuf);

    scan4_k<<<BB*HH*16, 256, 0, stream>>>(qbuf, ktbuf, uTbuf, wbuf, attnb, dbuf);

    fir2_k<5><<<BB*64*16, 256, 0, stream>>>(vbuf, fsw, lsbuf);
    fir2_k<64><<<BB*64*16, 256, 0, stream>>>(vbuf, flw, llbuf);

    stats_k<<<BL, 256, 0, stream>>>(lsbuf, llbuf, dbuf, vbuf, statsb);

    gemm_mfma<<<gg, 256, 0, stream>>>(hs, DD, w1, 1040, b1, hpart, DD, DD);
    gate_fin_k<<<BL, 256, 0, stream>>>(hpart, statsb, w1, w2, b2, lt, fwbuf);

    combine_k<<<BL*HH, 256, 0, stream>>>(lsbuf, llbuf, dbuf, vbuf, fwbuf, rss, rsl, onw, opre);

    gemm_mfma<<<gg, 256, 0, stream>>>(opre, DD, opw, DD, nullptr, out, DD, DD);
}

// Round 7
// 1171.921 us; speedup vs baseline: 2.7064x; 1.2497x over previous
//
#include <hip/hip_runtime.h>
#include <hip/hip_bf16.h>

#define BB 2
#define LL 4096
#define DD 1024
#define HH 4
#define DH 256
#define CH 32
#define NC (LL/CH)     // 128
#define BL (BB*LL)     // 8192
#define BLD ((size_t)BB*LL*DD) // 8388608

typedef __attribute__((ext_vector_type(8))) short short8;
typedef __attribute__((ext_vector_type(4))) float floatx4;

__device__ __forceinline__ float bf2f(unsigned short u) {
    union { float f; unsigned int i; } x; x.i = ((unsigned int)u) << 16; return x.f;
}
__device__ __forceinline__ float bflo(unsigned int u) {
    union { float f; unsigned int i; } x; x.i = u << 16; return x.f;
}
__device__ __forceinline__ float bfhi(unsigned int u) {
    union { float f; unsigned int i; } x; x.i = u & 0xFFFF0000u; return x.f;
}
__device__ __forceinline__ unsigned short f2bf(float f) {
    union { float f; unsigned int i; } x; x.f = f;
    unsigned int r = x.i + 0x7FFFu + ((x.i >> 16) & 1u);
    return (unsigned short)(r >> 16);
}
// pack two f32 -> (bf16(b)<<16)|bf16(a), round-half-up
__device__ __forceinline__ unsigned int pkbf(float a, float b) {
    unsigned int ua = __float_as_uint(a) + 0x8000u;
    unsigned int ub = __float_as_uint(b) + 0x8000u;
    return __builtin_amdgcn_perm(ub, ua, 0x07060302);
}

// ---------------------------------------------------------------- f32 -> bf16 bulk convert
__global__ __launch_bounds__(256) void cvt_bf_k(
    const float* __restrict__ x, unsigned short* __restrict__ y)
{
    size_t i = ((size_t)blockIdx.x * 256 + threadIdx.x) * 4;
    float4 v = *(const float4*)(x + i);
    ushort4 o;
    o.x = f2bf(v.x); o.y = f2bf(v.y); o.z = f2bf(v.z); o.w = f2bf(v.w);
    *(ushort4*)(y + i) = o;
}

// ---------------------------------------------------------------- pack w1[:,1024:1040] -> bf16 [1024][16]
__global__ __launch_bounds__(256) void w1s_prep_k(
    const float* __restrict__ w1, unsigned short* __restrict__ w1s)
{
    int idx = blockIdx.x * 256 + threadIdx.x;   // 16384
    int e = idx >> 4, s = idx & 15;
    w1s[idx] = f2bf(w1[(size_t)e * 1040 + 1024 + s]);
}

// ---------------------------------------------------------------- bf16 MFMA GEMM (NT), f32 A
__global__ __launch_bounds__(256) void gemm_mfma(
    const float* __restrict__ A, int lda,
    const float* __restrict__ W, int ldw,
    const float* __restrict__ bias,
    float* __restrict__ C, int ldc, int K)
{
    __shared__ unsigned short Abuf[128][56];
    __shared__ unsigned short Bbuf[128][56];
    const int t = threadIdx.x;
    const int wave = t >> 6, lane = t & 63;
    const int wm = wave >> 1, wn = wave & 1;
    const int row0 = blockIdx.y * 128, col0 = blockIdx.x * 128;

    floatx4 acc[4][4];
#pragma unroll
    for (int i = 0; i < 4; ++i)
#pragma unroll
        for (int j = 0; j < 4; ++j) acc[i][j] = (floatx4){0.f, 0.f, 0.f, 0.f};

    const int fr = lane & 15, fk = (lane >> 4) * 8;

    for (int kt = 0; kt < K; kt += 32) {
        __syncthreads();
#pragma unroll
        for (int it = 0; it < 2; ++it) {
            int idx = t + it * 256;
            int r = idx >> 2, s = (idx & 3) * 8;
            const float* ap = A + (size_t)(row0 + r) * lda + kt + s;
            float4 a0 = *(const float4*)(ap);
            float4 a1 = *(const float4*)(ap + 4);
            ushort4 p0, p1;
            p0.x = f2bf(a0.x); p0.y = f2bf(a0.y); p0.z = f2bf(a0.z); p0.w = f2bf(a0.w);
            p1.x = f2bf(a1.x); p1.y = f2bf(a1.y); p1.z = f2bf(a1.z); p1.w = f2bf(a1.w);
            *(ushort4*)&Abuf[r][s]     = p0;
            *(ushort4*)&Abuf[r][s + 4] = p1;
            const float* wp = W + (size_t)(col0 + r) * ldw + kt + s;
            float4 b0 = *(const float4*)(wp);
            float4 b1 = *(const float4*)(wp + 4);
            ushort4 q0, q1;
            q0.x = f2bf(b0.x); q0.y = f2bf(b0.y); q0.z = f2bf(b0.z); q0.w = f2bf(b0.w);
            q1.x = f2bf(b1.x); q1.y = f2bf(b1.y); q1.z = f2bf(b1.z); q1.w = f2bf(b1.w);
            *(ushort4*)&Bbuf[r][s]     = q0;
            *(ushort4*)&Bbuf[r][s + 4] = q1;
        }
        __syncthreads();

        short8 afrag[4], bfrag[4];
#pragma unroll
        for (int i = 0; i < 4; ++i) {
            afrag[i] = *(const short8*)&Abuf[wm * 64 + i * 16 + fr][fk];
            bfrag[i] = *(const short8*)&Bbuf[wn * 64 + i * 16 + fr][fk];
        }
#pragma unroll
        for (int i = 0; i < 4; ++i)
#pragma unroll
            for (int j = 0; j < 4; ++j)
                acc[i][j] = __builtin_amdgcn_mfma_f32_16x16x32_bf16(
                    afrag[i], bfrag[j], acc[i][j], 0, 0, 0);
    }

    const int fc = lane & 15, frow = (lane >> 4) * 4;
#pragma unroll
    for (int j = 0; j < 4; ++j) {
        int col = col0 + wn * 64 + j * 16 + fc;
        float bv = bias ? bias[col] : 0.0f;
#pragma unroll
        for (int i = 0; i < 4; ++i) {
#pragma unroll
            for (int r = 0; r < 4; ++r) {
                int row = row0 + wm * 64 + i * 16 + frow + r;
                C[(size_t)row * ldc + col] = acc[i][j][r] + bv;
            }
        }
    }
}

// ---------------------------------------------------------------- bf16 MFMA GEMM (NT), bf16 A
__global__ __launch_bounds__(256) void gemm_mfma_bfA(
    const unsigned short* __restrict__ A, int lda,
    const float* __restrict__ W, int ldw,
    float* __restrict__ C, int ldc, int K)
{
    __shared__ unsigned short Abuf[128][56];
    __shared__ unsigned short Bbuf[128][56];
    const int t = threadIdx.x;
    const int wave = t >> 6, lane = t & 63;
    const int wm = wave >> 1, wn = wave & 1;
    const int row0 = blockIdx.y * 128, col0 = blockIdx.x * 128;

    floatx4 acc[4][4];
#pragma unroll
    for (int i = 0; i < 4; ++i)
#pragma unroll
        for (int j = 0; j < 4; ++j) acc[i][j] = (floatx4){0.f, 0.f, 0.f, 0.f};

    const int fr = lane & 15, fk = (lane >> 4) * 8;

    for (int kt = 0; kt < K; kt += 32) {
        __syncthreads();
#pragma unroll
        for (int it = 0; it < 2; ++it) {
            int idx = t + it * 256;
            int r = idx >> 2, s = (idx & 3) * 8;
            uint4 av = *(const uint4*)(A + (size_t)(row0 + r) * lda + kt + s);
            *(uint4*)&Abuf[r][s] = av;
            const float* wp = W + (size_t)(col0 + r) * ldw + kt + s;
            float4 b0 = *(const float4*)(wp);
            float4 b1 = *(const float4*)(wp + 4);
            ushort4 q0, q1;
            q0.x = f2bf(b0.x); q0.y = f2bf(b0.y); q0.z = f2bf(b0.z); q0.w = f2bf(b0.w);
            q1.x = f2bf(b1.x); q1.y = f2bf(b1.y); q1.z = f2bf(b1.z); q1.w = f2bf(b1.w);
            *(ushort4*)&Bbuf[r][s]     = q0;
            *(ushort4*)&Bbuf[r][s + 4] = q1;
        }
        __syncthreads();

        short8 afrag[4], bfrag[4];
#pragma unroll
        for (int i = 0; i < 4; ++i) {
            afrag[i] = *(const short8*)&Abuf[wm * 64 + i * 16 + fr][fk];
            bfrag[i] = *(const short8*)&Bbuf[wn * 64 + i * 16 + fr][fk];
        }
#pragma unroll
        for (int i = 0; i < 4; ++i)
#pragma unroll
            for (int j = 0; j < 4; ++j)
                acc[i][j] = __builtin_amdgcn_mfma_f32_16x16x32_bf16(
                    afrag[i], bfrag[j], acc[i][j], 0, 0, 0);
    }

    const int fc = lane & 15, frow = (lane >> 4) * 4;
#pragma unroll
    for (int j = 0; j < 4; ++j) {
        int col = col0 + wn * 64 + j * 16 + fc;
#pragma unroll
        for (int i = 0; i < 4; ++i) {
#pragma unroll
            for (int r = 0; r < 4; ++r) {
                int row = row0 + wm * 64 + i * 16 + frow + r;
                C[(size_t)row * ldc + col] = acc[i][j][r];
            }
        }
    }
}

// --------------------------------------- causal dwconv K=4 + silu + head-l2norm -> bf16
__global__ __launch_bounds__(256) void convnorm_qk_k(
    const float* __restrict__ x, const float* __restrict__ w,
    unsigned short* __restrict__ y)
{
    int bl = blockIdx.x >> 2;
    int h  = blockIdx.x & 3;
    int l  = bl & (LL - 1);
    int d  = threadIdx.x;
    int c  = h * DH + d;
    const float* wp = w + (size_t)c * 4;
    const float* xp = x + (size_t)bl * DD + c;
    float acc = wp[3] * xp[0];
    if (l >= 1) acc += wp[2] * xp[-(int)DD];
    if (l >= 2) acc += wp[1] * xp[-2*(int)DD];
    if (l >= 3) acc += wp[0] * xp[-3*(int)DD];
    acc = acc / (1.0f + expf(-acc));
    float s = acc * acc;
#pragma unroll
    for (int off = 32; off > 0; off >>= 1) s += __shfl_down(s, off);
    __shared__ float red[4];
    int wv = threadIdx.x >> 6, ln = threadIdx.x & 63;
    if (ln == 0) red[wv] = s;
    __syncthreads();
    float tot = red[0] + red[1] + red[2] + red[3];
    y[(size_t)bl * DD + c] = f2bf(acc * rsqrtf(tot));
}

// ------------------------------------------------- causal depthwise conv K=4 + silu (f32)
__global__ __launch_bounds__(256) void conv_silu_k(
    const float* __restrict__ x, const float* __restrict__ w, float* __restrict__ y)
{
    size_t idx = (size_t)blockIdx.x * 256 + threadIdx.x;
    int c = (int)(idx & (DD - 1));
    int bl = (int)(idx >> 10);
    int l = bl & (LL - 1);
    const float* wp = w + (size_t)c * 4;
    const float* xp = x + (size_t)bl * DD + c;
    float acc = wp[3] * xp[0];
    if (l >= 1) acc += wp[2] * xp[-(int)DD];
    if (l >= 2) acc += wp[1] * xp[-2*(int)DD];
    if (l >= 3) acc += wp[0] * xp[-3*(int)DD];
    y[idx] = acc / (1.0f + expf(-acc));
}

// ------------------------------------------------- FIR causal depthwise conv, LDS-tiled
template<int K>
__global__ __launch_bounds__(256) void fir2_k(
    const float* __restrict__ x, const float* __restrict__ filt, float* __restrict__ y)
{
    const int ctile = blockIdx.x & 15;
    const int ltile = (blockIdx.x >> 4) & 63;
    const int b = blockIdx.x >> 10;
    const int RT = 64 + K - 1;
    __shared__ float xs[RT][64];
    __shared__ float fs[64][K + 1];
    const int t = threadIdx.x;
    const int l0 = ltile * 64;

    for (int i = t; i < RT * 16; i += 256) {
        int li = i >> 4, c4 = (i & 15) * 4;
        int l = l0 - (K - 1) + li;
        float4 v = make_float4(0.f, 0.f, 0.f, 0.f);
        if (l >= 0)
            v = *(const float4*)(x + ((size_t)b * LL + l) * DD + ctile * 64 + c4);
        *(float4*)&xs[li][c4] = v;
    }
    for (int i = t; i < 64 * K; i += 256) {
        fs[i / K][i % K] = filt[(size_t)ctile * 64 * K + i];
    }
    __syncthreads();

    const int c = t & 63, lg = t >> 6;
    float acc[16];
#pragma unroll
    for (int o = 0; o < 16; ++o) acc[o] = 0.f;
#pragma unroll
    for (int j = 0; j < 16 + K - 1; ++j) {
        float xv = xs[lg * 16 + j][c];
#pragma unroll
        for (int o = 0; o < 16; ++o) {
            int tap = j - o;
            if (tap >= 0 && tap < K) acc[o] += fs[c][tap] * xv;
        }
    }
    size_t base = ((size_t)b * LL + l0 + lg * 16) * DD + ctile * 64 + c;
#pragma unroll
    for (int o = 0; o < 16; ++o)
        y[base + (size_t)o * DD] = acc[o];
}

// ------------------------------------------------- beta = sigmoid(hs @ b_proj^T)
__global__ __launch_bounds__(256) void beta_k(
    const float* __restrict__ hs, const float* __restrict__ bw, float* __restrict__ beta)
{
    int bl = blockIdx.x;
    const float* xr = hs + (size_t)bl * DD;
    float a0=0.f,a1=0.f,a2=0.f,a3=0.f;
    for (int k = threadIdx.x; k < DD; k += 256) {
        float xv = xr[k];
        a0 += xv * bw[k];
        a1 += xv * bw[DD + k];
        a2 += xv * bw[2*DD + k];
        a3 += xv * bw[3*DD + k];
    }
#pragma unroll
    for (int off = 32; off > 0; off >>= 1) {
        a0 += __shfl_down(a0, off); a1 += __shfl_down(a1, off);
        a2 += __shfl_down(a2, off); a3 += __shfl_down(a3, off);
    }
    __shared__ float red[4][4];
    int wv = threadIdx.x >> 6, ln = threadIdx.x & 63;
    if (ln == 0) { red[wv][0]=a0; red[wv][1]=a1; red[wv][2]=a2; red[wv][3]=a3; }
    __syncthreads();
    if (threadIdx.x < 4) {
        int h = threadIdx.x;
        float s = red[0][h] + red[1][h] + red[2][h] + red[3][h];
        beta[(size_t)bl * HH + h] = 1.0f / (1.0f + expf(-s));
    }
}

// ------------------------------------------------- k transpose: k[b,l,h*DH+e] -> kT[bh,e,l]
__global__ __launch_bounds__(256) void tr_k(
    const unsigned short* __restrict__ k, unsigned short* __restrict__ kT)
{
    int et = blockIdx.x & 3;
    int lt = (blockIdx.x >> 2) & 63;
    int bh = blockIdx.x >> 8;
    int h = bh & 3, b = bh >> 2;
    __shared__ unsigned short tile[64][72];
    int t = threadIdx.x;
    int tr = t >> 4;
    int tc = (t & 15) * 4;
#pragma unroll
    for (int i = 0; i < 4; ++i) {
        int l = tr + i * 16;
        ushort4 v = *(const ushort4*)(k + ((size_t)b * LL + lt*64 + l) * DD + h * DH + et*64 + tc);
        *(ushort4*)&tile[l][tc] = v;
    }
    __syncthreads();
#pragma unroll
    for (int i = 0; i < 4; ++i) {
        int e = tr + i * 16;
        ushort4 v;
        v.x = tile[tc+0][e]; v.y = tile[tc+1][e];
        v.z = tile[tc+2][e]; v.w = tile[tc+3][e];
        *(ushort4*)(kT + ((size_t)bh * DH + et*64 + e) * LL + (size_t)lt*64 + tc) = v;
    }
}

// ------------------------------------------------- u transpose: u[bh,l,d] -> uT[bh,d,l]
__global__ __launch_bounds__(256) void tru_k(
    const unsigned short* __restrict__ u, unsigned short* __restrict__ uT)
{
    int et = blockIdx.x & 3;
    int lt = (blockIdx.x >> 2) & 63;
    int bh = blockIdx.x >> 8;
    __shared__ unsigned short tile[64][72];
    int t = threadIdx.x;
    int tr = t >> 4;
    int tc = (t & 15) * 4;
#pragma unroll
    for (int i = 0; i < 4; ++i) {
        int l = tr + i * 16;
        ushort4 v = *(const ushort4*)(u + ((size_t)bh * LL + lt*64 + l) * DH + et*64 + tc);
        *(ushort4*)&tile[l][tc] = v;
    }
    __syncthreads();
#pragma unroll
    for (int i = 0; i < 4; ++i) {
        int e = tr + i * 16;
        ushort4 v;
        v.x = tile[tc+0][e]; v.y = tile[tc+1][e];
        v.z = tile[tc+2][e]; v.w = tile[tc+3][e];
        *(ushort4*)(uT + ((size_t)bh * DH + et*64 + e) * LL + (size_t)lt*64 + tc) = v;
    }
}

// ------------------------------------------------- per-chunk prep (attn out bf16)
__global__ __launch_bounds__(256) void chunk_prep_k(
    const unsigned short* __restrict__ q, const unsigned short* __restrict__ k,
    const float* __restrict__ v, const float* __restrict__ beta,
    unsigned short* __restrict__ u_out, unsigned short* __restrict__ w_out,
    unsigned short* __restrict__ attn_out)
{
    int ci = blockIdx.x & (NC - 1);
    int bh = blockIdx.x >> 7;
    int h = bh & (HH - 1), b = bh >> 2;
    __shared__ float kt[CH][DH + 4];
    __shared__ float Am[CH][CH + 1];
    __shared__ float Ab[CH][CH + 1];
    __shared__ float bet[CH];
    int t = threadIdx.x;
    size_t qgbase = (size_t)b * LL + (size_t)ci * CH;

    for (int i = t; i < CH * (DH / 4); i += 256) {
        int r = i >> 6;
        int c4 = (i & 63) * 4;
        ushort4 kv = *(const ushort4*)(k + (qgbase + r) * DD + h * DH + c4);
        kt[r][c4+0] = bf2f(kv.x); kt[r][c4+1] = bf2f(kv.y);
        kt[r][c4+2] = bf2f(kv.z); kt[r][c4+3] = bf2f(kv.w);
    }
    if (t < CH) bet[t] = beta[(qgbase + t) * HH + h];
    __syncthreads();

    int c = t >> 3, e0 = (t & 7) * 4;
    {
        float accA[4] = {0,0,0,0}, accT[4] = {0,0,0,0};
        const unsigned short* qrow = q + (qgbase + c) * DD + h * DH;
        for (int d0 = 0; d0 < DH; d0 += 4) {
            float4 kc = *(const float4*)&kt[c][d0];
            ushort4 qv = *(const ushort4*)(qrow + d0);
            float qx = bf2f(qv.x), qy = bf2f(qv.y), qz = bf2f(qv.z), qw = bf2f(qv.w);
#pragma unroll
            for (int e = 0; e < 4; ++e) {
                float4 ke = *(const float4*)&kt[e0 + e][d0];
                accA[e] += kc.x*ke.x + kc.y*ke.y + kc.z*ke.z + kc.w*ke.w;
                accT[e] += qx*ke.x + qy*ke.y + qz*ke.z + qw*ke.w;
            }
        }
        float bc = bet[c];
        size_t abase = (size_t)blockIdx.x * (CH * CH) + (size_t)c * CH;
#pragma unroll
        for (int e = 0; e < 4; ++e) {
            int ee = e0 + e;
            Am[c][ee] = (ee < c) ? (-bc * accA[e]) : 0.0f;
            attn_out[abase + ee] = (ee <= c) ? f2bf(accT[e]) : (unsigned short)0;
        }
    }
    __syncthreads();

    for (int i = 1; i < CH; ++i) {
        float upd = 0.0f;
        if (t < i) {
#pragma unroll
            for (int kk = 0; kk < CH; ++kk) upd += Am[i][kk] * Am[kk][t];
        }
        __syncthreads();
        if (t < i) Am[i][t] += upd;
        __syncthreads();
    }

    for (int i = t; i < CH * CH; i += 256) {
        int cc = i >> 5, ee = i & 31;
        float val = Am[cc][ee] + (cc == ee ? 1.0f : 0.0f);
        Ab[cc][ee] = val * bet[ee];
    }
    __syncthreads();

    int c2 = t >> 3, dd0 = (t & 7) * 32;
    float accu[32];
#pragma unroll
    for (int j = 0; j < 32; ++j) accu[j] = 0.0f;
    for (int e = 0; e < CH; ++e) {
        float ab = Ab[c2][e];
        const float* vrow = v + (qgbase + e) * DD + h * DH + dd0;
#pragma unroll
        for (int j4 = 0; j4 < 8; ++j4) {
            float4 v4 = *(const float4*)(vrow + j4 * 4);
            accu[j4*4+0] += ab * v4.x; accu[j4*4+1] += ab * v4.y;
            accu[j4*4+2] += ab * v4.z; accu[j4*4+3] += ab * v4.w;
        }
    }
    size_t obase = ((size_t)bh * LL + (size_t)ci * CH + c2) * DH + dd0;
#pragma unroll
    for (int j4 = 0; j4 < 8; ++j4) {
        ushort4 o;
        o.x = f2bf(accu[j4*4+0]); o.y = f2bf(accu[j4*4+1]);
        o.z = f2bf(accu[j4*4+2]); o.w = f2bf(accu[j4*4+3]);
        *(ushort4*)(u_out + obase + j4*4) = o;
    }

#pragma unroll
    for (int j = 0; j < 32; ++j) accu[j] = 0.0f;
    for (int e = 0; e < CH; ++e) {
        float ab = Ab[c2][e];
#pragma unroll
        for (int j4 = 0; j4 < 8; ++j4) {
            float4 v4 = *(const float4*)&kt[e][dd0 + j4*4];
            accu[j4*4+0] += ab * v4.x; accu[j4*4+1] += ab * v4.y;
            accu[j4*4+2] += ab * v4.z; accu[j4*4+3] += ab * v4.w;
        }
    }
#pragma unroll
    for (int j4 = 0; j4 < 8; ++j4) {
        ushort4 o;
        o.x = f2bf(accu[j4*4+0]); o.y = f2bf(accu[j4*4+1]);
        o.z = f2bf(accu[j4*4+2]); o.w = f2bf(accu[j4*4+3]);
        *(ushort4*)(w_out + obase + j4*4) = o;
    }
}

// ------------------------------------------------- chunk scan v4: MFMA + 128 blocks (R6, verified)
__global__ __launch_bounds__(256) void scan4_k(
    const unsigned short* __restrict__ q, const unsigned short* __restrict__ kT,
    const unsigned short* __restrict__ uT, const unsigned short* __restrict__ w,
    const unsigned short* __restrict__ attn, float* __restrict__ dout)
{
    const int jb = blockIdx.x & 15;
    const int bh = blockIdx.x >> 4;
    const int h = bh & (HH - 1), b = bh >> 2;
    const int jcol = jb * 16;
    const int wave = threadIdx.x >> 6, lane = threadIdx.x & 63;
    const int lr = lane & 15, lg = lane >> 4;

    __shared__ unsigned short SbT[16][264];
    __shared__ unsigned short uadjT[16][40];
    __shared__ float Pred[4][64][17];

    floatx4 Sacc[4];
#pragma unroll
    for (int mt = 0; mt < 4; ++mt) Sacc[mt] = (floatx4){0.f,0.f,0.f,0.f};

    const unsigned short* qb  = q + (size_t)b * LL * DD + h * DH;
    const unsigned short* wb  = w + (size_t)bh * LL * DH;
    const unsigned short* uTb = uT + (size_t)bh * DH * LL;
    const unsigned short* kTb = kT + (size_t)bh * DH * LL;
    float* db = dout + (size_t)bh * LL * DH;

    for (int ci = 0; ci < NC; ++ci) {
        const int l0 = ci * CH;

#pragma unroll
        for (int mt = 0; mt < 4; ++mt) {
            int e0 = 64 * wave + 16 * mt + lg * 4;
            *(unsigned int*)&SbT[lr][e0]     = pkbf(Sacc[mt][0], Sacc[mt][1]);
            *(unsigned int*)&SbT[lr][e0 + 2] = pkbf(Sacc[mt][2], Sacc[mt][3]);
        }
        __syncthreads();

        floatx4 P0 = (floatx4){0.f,0.f,0.f,0.f}, P1 = P0, P2 = P0, P3 = P0;
#pragma unroll
        for (int kt = 0; kt < 2; ++kt) {
            const int e0 = 64 * wave + 32 * kt + lg * 8;
            short8 aw0 = *(const short8*)(wb + (size_t)(l0 + lr) * DH + e0);
            short8 aw1 = *(const short8*)(wb + (size_t)(l0 + 16 + lr) * DH + e0);
            short8 aq0 = *(const short8*)(qb + (size_t)(l0 + lr) * DD + e0);
            short8 aq1 = *(const short8*)(qb + (size_t)(l0 + 16 + lr) * DD + e0);
            short8 sb  = *(const short8*)&SbT[lr][e0];
            P0 = __builtin_amdgcn_mfma_f32_16x16x32_bf16(aw0, sb, P0, 0,0,0);
            P1 = __builtin_amdgcn_mfma_f32_16x16x32_bf16(aw1, sb, P1, 0,0,0);
            P2 = __builtin_amdgcn_mfma_f32_16x16x32_bf16(aq0, sb, P2, 0,0,0);
            P3 = __builtin_amdgcn_mfma_f32_16x16x32_bf16(aq1, sb, P3, 0,0,0);
        }
#pragma unroll
        for (int r = 0; r < 4; ++r) {
            Pred[wave][ 0 + lg * 4 + r][lr] = P0[r];
            Pred[wave][16 + lg * 4 + r][lr] = P1[r];
            Pred[wave][32 + lg * 4 + r][lr] = P2[r];
            Pred[wave][48 + lg * 4 + r][lr] = P3[r];
        }
        __syncthreads();

        float red[4];
#pragma unroll
        for (int r = 0; r < 4; ++r) {
            int m = wave * 16 + lg * 4 + r;
            red[r] = Pred[0][m][lr] + Pred[1][m][lr] + Pred[2][m][lr] + Pred[3][m][lr];
        }

        if (wave < 2) {
            ushort4 u4 = *(const ushort4*)(uTb + (size_t)(jcol + lr) * LL + l0 + wave * 16 + lg * 4);
            float ua0 = bf2f(u4.x) - red[0];
            float ua1 = bf2f(u4.y) - red[1];
            float ua2 = bf2f(u4.z) - red[2];
            float ua3 = bf2f(u4.w) - red[3];
            int cc0 = wave * 16 + lg * 4;
            *(unsigned int*)&uadjT[lr][cc0]     = pkbf(ua0, ua1);
            *(unsigned int*)&uadjT[lr][cc0 + 2] = pkbf(ua2, ua3);
        }
        __syncthreads();

        short8 ub = *(const short8*)&uadjT[lr][lg * 8];

        if (wave >= 2) {
            const unsigned short* ac = attn + ((size_t)bh * NC + ci) * (CH * CH);
            short8 af = *(const short8*)(ac + (size_t)((wave - 2) * 16 + lr) * CH + lg * 8);
            floatx4 Ot = (floatx4){red[0], red[1], red[2], red[3]};
            Ot = __builtin_amdgcn_mfma_f32_16x16x32_bf16(af, ub, Ot, 0,0,0);
#pragma unroll
            for (int r = 0; r < 4; ++r)
                db[(size_t)(l0 + (wave - 2) * 16 + lg * 4 + r) * DH + jcol + lr] = Ot[r];
        }

#pragma unroll
        for (int mt = 0; mt < 4; ++mt) {
            short8 kf = *(const short8*)(kTb + (size_t)(64 * wave + 16 * mt + lr) * LL + l0 + lg * 8);
            Sacc[mt] = __builtin_amdgcn_mfma_f32_16x16x32_bf16(kf, ub, Sacc[mt], 0,0,0);
        }
        __syncthreads();
    }
}

// ------------------------------------------------- per-head stats
__global__ __launch_bounds__(256) void stats_k(
    const float* __restrict__ ls, const float* __restrict__ llb,
    const float* __restrict__ dox, const float* __restrict__ v,
    float* __restrict__ stats)
{
    int bl = blockIdx.x;
    int b = bl >> 12, l = bl & (LL - 1);
    int wv = threadIdx.x >> 6, ln = threadIdx.x & 63;
    size_t ibase = (size_t)bl * DD + wv * DH;
    size_t dbase = (((size_t)(b * HH + wv)) * LL + l) * DH;
#pragma unroll
    for (int tn = 0; tn < 4; ++tn) {
        const float* p; size_t base;
        if (tn == 0)      { p = ls;  base = ibase; }
        else if (tn == 1) { p = llb; base = ibase; }
        else if (tn == 2) { p = dox; base = dbase; }
        else              { p = v;   base = ibase; }
        float4 x = *(const float4*)(p + base + ln * 4);
        float sm = x.x + x.y + x.z + x.w;
        float sq = x.x*x.x + x.y*x.y + x.z*x.z + x.w*x.w;
        float sa = fabsf(x.x) + fabsf(x.y) + fabsf(x.z) + fabsf(x.w);
#pragma unroll
        for (int off = 32; off > 0; off >>= 1) {
            sm += __shfl_down(sm, off);
            sq += __shfl_down(sq, off);
            sa += __shfl_down(sa, off);
        }
        if (ln == 0) {
            float mean = sm * (1.0f / DH);
            float var = sq * (1.0f / DH) - mean * mean;
            float am = sa * (1.0f / DH);
            float l2 = sqrtf(sq);
            *(float4*)(stats + (size_t)bl * 64 + wv * 16 + tn * 4) =
                make_float4(mean, var, am, l2);
        }
    }
}

// ------------------------------------------------- gate finish v2: coalesced, single reduction
__global__ __launch_bounds__(256) void gate_fin2_k(
    const float* __restrict__ hpart, const float* __restrict__ stats,
    const unsigned short* __restrict__ w1s,   // [1024][16] bf16
    const float* __restrict__ w2, const float* __restrict__ b2,
    const float* __restrict__ ltemp, float* __restrict__ fw)
{
    const int bl = blockIdx.x;
    const int t = threadIdx.x;
    const float temp = log1pf(expf(ltemp[0])) + 1e-4f;
    __shared__ float st[HH][16];
    __shared__ float red[4][16];
    __shared__ float fin[16];
    if (t < 64) st[t >> 4][t & 15] = stats[(size_t)bl * 64 + t];

    const int e0 = t * 4;
    float4 hp4 = *(const float4*)(hpart + (size_t)bl * DD + e0);
    float hp[4] = {hp4.x, hp4.y, hp4.z, hp4.w};
    float w2a[4][4];
#pragma unroll
    for (int j = 0; j < 4; ++j) {
        float4 wv = *(const float4*)(w2 + (size_t)j * 1024 + e0);
        w2a[j][0] = wv.x; w2a[j][1] = wv.y; w2a[j][2] = wv.z; w2a[j][3] = wv.w;
    }
    uint4 wpk[8];
    const uint4* wp = (const uint4*)(w1s + (size_t)e0 * 16);
#pragma unroll
    for (int i = 0; i < 8; ++i) wpk[i] = wp[i];
    __syncthreads();

    float lg[4][4];
#pragma unroll
    for (int h = 0; h < 4; ++h)
#pragma unroll
        for (int j = 0; j < 4; ++j) lg[h][j] = 0.0f;

#pragma unroll
    for (int ii = 0; ii < 4; ++ii) {
        float xh[4] = {hp[ii], hp[ii], hp[ii], hp[ii]};
        unsigned arr[8] = {wpk[ii*2].x, wpk[ii*2].y, wpk[ii*2].z, wpk[ii*2].w,
                           wpk[ii*2+1].x, wpk[ii*2+1].y, wpk[ii*2+1].z, wpk[ii*2+1].w};
#pragma unroll
        for (int p = 0; p < 8; ++p) {
            float wlo = bflo(arr[p]), whi = bfhi(arr[p]);
            int s = p * 2;
#pragma unroll
            for (int h = 0; h < 4; ++h)
                xh[h] += st[h][s] * wlo + st[h][s + 1] * whi;
        }
#pragma unroll
        for (int h = 0; h < 4; ++h) {
            float x = xh[h];
            float g = 0.5f * x * (1.0f + erff(x * 0.70710678118654752f));
            lg[h][0] += g * w2a[0][ii];
            lg[h][1] += g * w2a[1][ii];
            lg[h][2] += g * w2a[2][ii];
            lg[h][3] += g * w2a[3][ii];
        }
    }

#pragma unroll
    for (int h = 0; h < 4; ++h)
#pragma unroll
        for (int j = 0; j < 4; ++j)
#pragma unroll
            for (int off = 32; off > 0; off >>= 1)
                lg[h][j] += __shfl_down(lg[h][j], off);

    const int wv = t >> 6, ln = t & 63;
    if (ln == 0) {
#pragma unroll
        for (int h = 0; h < 4; ++h)
#pragma unroll
            for (int j = 0; j < 4; ++j) red[wv][h * 4 + j] = lg[h][j];
    }
    __syncthreads();
    if (t < 16) {
        float s = red[0][t] + red[1][t] + red[2][t] + red[3][t] + b2[t & 3];
        fin[t] = s / temp;
    }
    __syncthreads();
    if (t < 4) {
        float l0 = fin[t*4], l1 = fin[t*4+1], l2 = fin[t*4+2], l3 = fin[t*4+3];
        float m = fmaxf(fmaxf(l0, l1), fmaxf(l2, l3));
        float e0x = expf(l0-m), e1 = expf(l1-m), e2 = expf(l2-m), e3 = expf(l3-m);
        float inv = 1.0f / (e0x + e1 + e2 + e3);
        *(float4*)(fw + (size_t)bl * 16 + t * 4) = make_float4(e0x*inv, e1*inv, e2*inv, e3*inv);
    }
}

// ------------------------------------------------- combine + rms norm
__global__ __launch_bounds__(256) void combine_k(
    const float* __restrict__ ls, const float* __restrict__ llb,
    const float* __restrict__ dox, const float* __restrict__ v,
    const float* __restrict__ fw, const float* __restrict__ rss,
    const float* __restrict__ rsl, const float* __restrict__ onw,
    float* __restrict__ opre)
{
    int h = blockIdx.x & (HH - 1);
    int bl = blockIdx.x >> 2;
    int b = bl >> 12, l = bl & (LL - 1);
    int d = threadIdx.x;
    size_t i1 = (size_t)blockIdx.x * DH + d;
    size_t i2 = (((size_t)(b * HH + h)) * LL + l) * DH + d;
    const float* fwp = fw + (size_t)blockIdx.x * 4;
    float f0 = fwp[0], f1 = fwp[1], f2 = fwp[2], f3 = fwp[3];
    float aS = rss[0], aL = rsl[0];
    float vls = ls[i1], vll = llb[i1], vd = dox[i2], vv = v[i1];
    float o = f0*vls + f1*vll + f2*vd + f3*vv + aS*vls + aL*vll;
    float s = o * o;
#pragma unroll
    for (int off = 32; off > 0; off >>= 1) s += __shfl_down(s, off);
    __shared__ float red[4];
    int wv = threadIdx.x >> 6, ln = threadIdx.x & 63;
    if (ln == 0) red[wv] = s;
    __syncthreads();
    float ms = (red[0] + red[1] + red[2] + red[3]) * (1.0f / DH);
    opre[(size_t)bl * DD + h * DH + d] = o * rsqrtf(ms + 1e-5f) * onw[d];
}

// ================================================================ launch
extern "C" void kernel_launch(void* const* d_in, const int* in_sizes, int n_in,
                              void* d_out, int out_size, void* d_ws, size_t ws_size,
                              hipStream_t stream)
{
    const float* hs  = (const float*)d_in[0];
    const float* qw  = (const float*)d_in[1];
    const float* kw  = (const float*)d_in[2];
    const float* vw  = (const float*)d_in[3];
    const float* bw  = (const float*)d_in[4];
    const float* qcw = (const float*)d_in[5];
    const float* kcw = (const float*)d_in[6];
    const float* vcw = (const float*)d_in[7];
    const float* fsw = (const float*)d_in[8];
    const float* flw = (const float*)d_in[9];
    const float* w1  = (const float*)d_in[10];
    const float* b1  = (const float*)d_in[11];
    const float* w2  = (const float*)d_in[12];
    const float* b2  = (const float*)d_in[13];
    const float* lt  = (const float*)d_in[14];
    const float* rss = (const float*)d_in[15];
    const float* rsl = (const float*)d_in[16];
    const float* onw = (const float*)d_in[17];
    const float* opw = (const float*)d_in[18];
    float* out = (float*)d_out;

    float* wsf = (float*)d_ws;
    float* tmp   = wsf;
    unsigned short* ktbuf = (unsigned short*)tmp;
    unsigned short* uTbuf = (unsigned short*)(wsf + BLD/2);
    float* vbuf  = wsf + BLD;
    float* dbuf  = wsf + 2*BLD;
    unsigned short* hsb = (unsigned short*)(wsf + 2*BLD);
    unsigned short* qbuf = (unsigned short*)(wsf + 3*BLD);
    unsigned short* kbuf = qbuf + BLD;
    float* hpart = wsf + 3*BLD;
    float* opre  = wsf + 3*BLD;
    unsigned short* ubuf = (unsigned short*)(wsf + 4*BLD);
    unsigned short* wbuf = ubuf + BLD;
    float* llbuf = wsf + 4*BLD;
    float* lsbuf = tmp;
    unsigned short* attnb = (unsigned short*)(wsf + 5*BLD);
    float* statsb = wsf + 5*BLD + 524288;
    float* fwbuf  = statsb + (size_t)BL*HH*16;
    float* betab  = fwbuf + (size_t)BL*HH*4;
    unsigned short* w1sp = (unsigned short*)(betab + (size_t)BL*HH);

    dim3 gg(8, 64);   // N/128, M/128

    cvt_bf_k<<<(int)(BLD/1024), 256, 0, stream>>>(hs, hsb);
    w1s_prep_k<<<64, 256, 0, stream>>>(w1, w1sp);

    gemm_mfma_bfA<<<gg, 256, 0, stream>>>(hsb, DD, qw, DD, tmp, DD, DD);
    convnorm_qk_k<<<BL*HH, 256, 0, stream>>>(tmp, qcw, qbuf);
    gemm_mfma_bfA<<<gg, 256, 0, stream>>>(hsb, DD, kw, DD, tmp, DD, DD);
    convnorm_qk_k<<<BL*HH, 256, 0, stream>>>(tmp, kcw, kbuf);
    gemm_mfma_bfA<<<gg, 256, 0, stream>>>(hsb, DD, vw, DD, tmp, DD, DD);
    conv_silu_k<<<(int)(BLD/256), 256, 0, stream>>>(tmp, vcw, vbuf);

    beta_k<<<BL, 256, 0, stream>>>(hs, bw, betab);

    tr_k<<<8*64*4, 256, 0, stream>>>(kbuf, ktbuf);
    chunk_prep_k<<<BB*HH*NC, 256, 0, stream>>>(qbuf, kbuf, vbuf, betab, ubuf, wbuf, attnb);
    tru_k<<<8*64*4, 256, 0, stream>>>(ubuf, uTbuf);

    scan4_k<<<BB*HH*16, 256, 0, stream>>>(qbuf, ktbuf, uTbuf, wbuf, attnb, dbuf);

    fir2_k<5><<<BB*64*16, 256, 0, stream>>>(vbuf, fsw, lsbuf);
    fir2_k<64><<<BB*64*16, 256, 0, stream>>>(vbuf, flw, llbuf);

    stats_k<<<BL, 256, 0, stream>>>(lsbuf, llbuf, dbuf, vbuf, statsb);

    gemm_mfma<<<gg, 256, 0, stream>>>(hs, DD, w1, 1040, b1, hpart, DD, DD);
    gate_fin2_k<<<BL, 256, 0, stream>>>(hpart, statsb, w1sp, w2, b2, lt, fwbuf);

    combine_k<<<BL*HH, 256, 0, stream>>>(lsbuf, llbuf, dbuf, vbuf, fwbuf, rss, rsl, onw, opre);

    gemm_mfma<<<gg, 256, 0, stream>>>(opre, DD, opw, DD, nullptr, out, DD, DD);
}

// Round 8
// 1040.958 us; speedup vs baseline: 3.0469x; 1.1258x over previous
//
#include <hip/hip_runtime.h>
#include <hip/hip_bf16.h>

#define BB 2
#define LL 4096
#define DD 1024
#define HH 4
#define DH 256
#define CH 32
#define NC (LL/CH)     // 128
#define BL (BB*LL)     // 8192
#define BLD ((size_t)BB*LL*DD) // 8388608

typedef __attribute__((ext_vector_type(8))) short short8;
typedef __attribute__((ext_vector_type(4))) float floatx4;

__device__ __forceinline__ float bf2f(unsigned short u) {
    union { float f; unsigned int i; } x; x.i = ((unsigned int)u) << 16; return x.f;
}
__device__ __forceinline__ float bflo(unsigned int u) {
    union { float f; unsigned int i; } x; x.i = u << 16; return x.f;
}
__device__ __forceinline__ float bfhi(unsigned int u) {
    union { float f; unsigned int i; } x; x.i = u & 0xFFFF0000u; return x.f;
}
__device__ __forceinline__ unsigned short f2bf(float f) {
    union { float f; unsigned int i; } x; x.f = f;
    unsigned int r = x.i + 0x7FFFu + ((x.i >> 16) & 1u);
    return (unsigned short)(r >> 16);
}
// pack two f32 -> (bf16(b)<<16)|bf16(a), round-half-up
__device__ __forceinline__ unsigned int pkbf(float a, float b) {
    unsigned int ua = __float_as_uint(a) + 0x8000u;
    unsigned int ub = __float_as_uint(b) + 0x8000u;
    return __builtin_amdgcn_perm(ub, ua, 0x07060302);
}
// barrier with LDS-only drain: s_waitcnt lgkmcnt(0) (vmcnt=63, expcnt=7) + s_barrier.
// Keeps prefetch global loads in flight across the barrier (no vmcnt(0) drain).
__device__ __forceinline__ void lds_barrier() {
    __builtin_amdgcn_s_waitcnt(0xC07F);
    __builtin_amdgcn_s_barrier();
}

// ---------------------------------------------------------------- f32 -> bf16 bulk convert
__global__ __launch_bounds__(256) void cvt_bf_k(
    const float* __restrict__ x, unsigned short* __restrict__ y)
{
    size_t i = ((size_t)blockIdx.x * 256 + threadIdx.x) * 4;
    float4 v = *(const float4*)(x + i);
    ushort4 o;
    o.x = f2bf(v.x); o.y = f2bf(v.y); o.z = f2bf(v.z); o.w = f2bf(v.w);
    *(ushort4*)(y + i) = o;
}

// ---------------------------------------------------------------- pack w1[:,1024:1040] -> bf16 [1024][16]
__global__ __launch_bounds__(256) void w1s_prep_k(
    const float* __restrict__ w1, unsigned short* __restrict__ w1s)
{
    int idx = blockIdx.x * 256 + threadIdx.x;   // 16384
    int e = idx >> 4, s = idx & 15;
    w1s[idx] = f2bf(w1[(size_t)e * 1040 + 1024 + s]);
}

// ---------------------------------------------------------------- bf16 MFMA GEMM (NT), f32 A
__global__ __launch_bounds__(256) void gemm_mfma(
    const float* __restrict__ A, int lda,
    const float* __restrict__ W, int ldw,
    const float* __restrict__ bias,
    float* __restrict__ C, int ldc, int K)
{
    __shared__ unsigned short Abuf[128][56];
    __shared__ unsigned short Bbuf[128][56];
    const int t = threadIdx.x;
    const int wave = t >> 6, lane = t & 63;
    const int wm = wave >> 1, wn = wave & 1;
    const int row0 = blockIdx.y * 128, col0 = blockIdx.x * 128;

    floatx4 acc[4][4];
#pragma unroll
    for (int i = 0; i < 4; ++i)
#pragma unroll
        for (int j = 0; j < 4; ++j) acc[i][j] = (floatx4){0.f, 0.f, 0.f, 0.f};

    const int fr = lane & 15, fk = (lane >> 4) * 8;

    for (int kt = 0; kt < K; kt += 32) {
        __syncthreads();
#pragma unroll
        for (int it = 0; it < 2; ++it) {
            int idx = t + it * 256;
            int r = idx >> 2, s = (idx & 3) * 8;
            const float* ap = A + (size_t)(row0 + r) * lda + kt + s;
            float4 a0 = *(const float4*)(ap);
            float4 a1 = *(const float4*)(ap + 4);
            ushort4 p0, p1;
            p0.x = f2bf(a0.x); p0.y = f2bf(a0.y); p0.z = f2bf(a0.z); p0.w = f2bf(a0.w);
            p1.x = f2bf(a1.x); p1.y = f2bf(a1.y); p1.z = f2bf(a1.z); p1.w = f2bf(a1.w);
            *(ushort4*)&Abuf[r][s]     = p0;
            *(ushort4*)&Abuf[r][s + 4] = p1;
            const float* wp = W + (size_t)(col0 + r) * ldw + kt + s;
            float4 b0 = *(const float4*)(wp);
            float4 b1 = *(const float4*)(wp + 4);
            ushort4 q0, q1;
            q0.x = f2bf(b0.x); q0.y = f2bf(b0.y); q0.z = f2bf(b0.z); q0.w = f2bf(b0.w);
            q1.x = f2bf(b1.x); q1.y = f2bf(b1.y); q1.z = f2bf(b1.z); q1.w = f2bf(b1.w);
            *(ushort4*)&Bbuf[r][s]     = q0;
            *(ushort4*)&Bbuf[r][s + 4] = q1;
        }
        __syncthreads();

        short8 afrag[4], bfrag[4];
#pragma unroll
        for (int i = 0; i < 4; ++i) {
            afrag[i] = *(const short8*)&Abuf[wm * 64 + i * 16 + fr][fk];
            bfrag[i] = *(const short8*)&Bbuf[wn * 64 + i * 16 + fr][fk];
        }
#pragma unroll
        for (int i = 0; i < 4; ++i)
#pragma unroll
            for (int j = 0; j < 4; ++j)
                acc[i][j] = __builtin_amdgcn_mfma_f32_16x16x32_bf16(
                    afrag[i], bfrag[j], acc[i][j], 0, 0, 0);
    }

    const int fc = lane & 15, frow = (lane >> 4) * 4;
#pragma unroll
    for (int j = 0; j < 4; ++j) {
        int col = col0 + wn * 64 + j * 16 + fc;
        float bv = bias ? bias[col] : 0.0f;
#pragma unroll
        for (int i = 0; i < 4; ++i) {
#pragma unroll
            for (int r = 0; r < 4; ++r) {
                int row = row0 + wm * 64 + i * 16 + frow + r;
                C[(size_t)row * ldc + col] = acc[i][j][r] + bv;
            }
        }
    }
}

// ---------------------------------------------------------------- bf16 MFMA GEMM (NT), bf16 A
__global__ __launch_bounds__(256) void gemm_mfma_bfA(
    const unsigned short* __restrict__ A, int lda,
    const float* __restrict__ W, int ldw,
    float* __restrict__ C, int ldc, int K)
{
    __shared__ unsigned short Abuf[128][56];
    __shared__ unsigned short Bbuf[128][56];
    const int t = threadIdx.x;
    const int wave = t >> 6, lane = t & 63;
    const int wm = wave >> 1, wn = wave & 1;
    const int row0 = blockIdx.y * 128, col0 = blockIdx.x * 128;

    floatx4 acc[4][4];
#pragma unroll
    for (int i = 0; i < 4; ++i)
#pragma unroll
        for (int j = 0; j < 4; ++j) acc[i][j] = (floatx4){0.f, 0.f, 0.f, 0.f};

    const int fr = lane & 15, fk = (lane >> 4) * 8;

    for (int kt = 0; kt < K; kt += 32) {
        __syncthreads();
#pragma unroll
        for (int it = 0; it < 2; ++it) {
            int idx = t + it * 256;
            int r = idx >> 2, s = (idx & 3) * 8;
            uint4 av = *(const uint4*)(A + (size_t)(row0 + r) * lda + kt + s);
            *(uint4*)&Abuf[r][s] = av;
            const float* wp = W + (size_t)(col0 + r) * ldw + kt + s;
            float4 b0 = *(const float4*)(wp);
            float4 b1 = *(const float4*)(wp + 4);
            ushort4 q0, q1;
            q0.x = f2bf(b0.x); q0.y = f2bf(b0.y); q0.z = f2bf(b0.z); q0.w = f2bf(b0.w);
            q1.x = f2bf(b1.x); q1.y = f2bf(b1.y); q1.z = f2bf(b1.z); q1.w = f2bf(b1.w);
            *(ushort4*)&Bbuf[r][s]     = q0;
            *(ushort4*)&Bbuf[r][s + 4] = q1;
        }
        __syncthreads();

        short8 afrag[4], bfrag[4];
#pragma unroll
        for (int i = 0; i < 4; ++i) {
            afrag[i] = *(const short8*)&Abuf[wm * 64 + i * 16 + fr][fk];
            bfrag[i] = *(const short8*)&Bbuf[wn * 64 + i * 16 + fr][fk];
        }
#pragma unroll
        for (int i = 0; i < 4; ++i)
#pragma unroll
            for (int j = 0; j < 4; ++j)
                acc[i][j] = __builtin_amdgcn_mfma_f32_16x16x32_bf16(
                    afrag[i], bfrag[j], acc[i][j], 0, 0, 0);
    }

    const int fc = lane & 15, frow = (lane >> 4) * 4;
#pragma unroll
    for (int j = 0; j < 4; ++j) {
        int col = col0 + wn * 64 + j * 16 + fc;
#pragma unroll
        for (int i = 0; i < 4; ++i) {
#pragma unroll
            for (int r = 0; r < 4; ++r) {
                int row = row0 + wm * 64 + i * 16 + frow + r;
                C[(size_t)row * ldc + col] = acc[i][j][r];
            }
        }
    }
}

// --------------------------------------- causal dwconv K=4 + silu + head-l2norm -> bf16
__global__ __launch_bounds__(256) void convnorm_qk_k(
    const float* __restrict__ x, const float* __restrict__ w,
    unsigned short* __restrict__ y)
{
    int bl = blockIdx.x >> 2;
    int h  = blockIdx.x & 3;
    int l  = bl & (LL - 1);
    int d  = threadIdx.x;
    int c  = h * DH + d;
    const float* wp = w + (size_t)c * 4;
    const float* xp = x + (size_t)bl * DD + c;
    float acc = wp[3] * xp[0];
    if (l >= 1) acc += wp[2] * xp[-(int)DD];
    if (l >= 2) acc += wp[1] * xp[-2*(int)DD];
    if (l >= 3) acc += wp[0] * xp[-3*(int)DD];
    acc = acc / (1.0f + expf(-acc));
    float s = acc * acc;
#pragma unroll
    for (int off = 32; off > 0; off >>= 1) s += __shfl_down(s, off);
    __shared__ float red[4];
    int wv = threadIdx.x >> 6, ln = threadIdx.x & 63;
    if (ln == 0) red[wv] = s;
    __syncthreads();
    float tot = red[0] + red[1] + red[2] + red[3];
    y[(size_t)bl * DD + c] = f2bf(acc * rsqrtf(tot));
}

// ------------------------------------------------- causal depthwise conv K=4 + silu (f32)
__global__ __launch_bounds__(256) void conv_silu_k(
    const float* __restrict__ x, const float* __restrict__ w, float* __restrict__ y)
{
    size_t idx = (size_t)blockIdx.x * 256 + threadIdx.x;
    int c = (int)(idx & (DD - 1));
    int bl = (int)(idx >> 10);
    int l = bl & (LL - 1);
    const float* wp = w + (size_t)c * 4;
    const float* xp = x + (size_t)bl * DD + c;
    float acc = wp[3] * xp[0];
    if (l >= 1) acc += wp[2] * xp[-(int)DD];
    if (l >= 2) acc += wp[1] * xp[-2*(int)DD];
    if (l >= 3) acc += wp[0] * xp[-3*(int)DD];
    y[idx] = acc / (1.0f + expf(-acc));
}

// ------------------------------------------------- FIR causal depthwise conv, LDS-tiled
template<int K>
__global__ __launch_bounds__(256) void fir2_k(
    const float* __restrict__ x, const float* __restrict__ filt, float* __restrict__ y)
{
    const int ctile = blockIdx.x & 15;
    const int ltile = (blockIdx.x >> 4) & 63;
    const int b = blockIdx.x >> 10;
    const int RT = 64 + K - 1;
    __shared__ float xs[RT][64];
    __shared__ float fs[64][K + 1];
    const int t = threadIdx.x;
    const int l0 = ltile * 64;

    for (int i = t; i < RT * 16; i += 256) {
        int li = i >> 4, c4 = (i & 15) * 4;
        int l = l0 - (K - 1) + li;
        float4 v = make_float4(0.f, 0.f, 0.f, 0.f);
        if (l >= 0)
            v = *(const float4*)(x + ((size_t)b * LL + l) * DD + ctile * 64 + c4);
        *(float4*)&xs[li][c4] = v;
    }
    for (int i = t; i < 64 * K; i += 256) {
        fs[i / K][i % K] = filt[(size_t)ctile * 64 * K + i];
    }
    __syncthreads();

    const int c = t & 63, lg = t >> 6;
    float acc[16];
#pragma unroll
    for (int o = 0; o < 16; ++o) acc[o] = 0.f;
#pragma unroll
    for (int j = 0; j < 16 + K - 1; ++j) {
        float xv = xs[lg * 16 + j][c];
#pragma unroll
        for (int o = 0; o < 16; ++o) {
            int tap = j - o;
            if (tap >= 0 && tap < K) acc[o] += fs[c][tap] * xv;
        }
    }
    size_t base = ((size_t)b * LL + l0 + lg * 16) * DD + ctile * 64 + c;
#pragma unroll
    for (int o = 0; o < 16; ++o)
        y[base + (size_t)o * DD] = acc[o];
}

// ------------------------------------------------- beta = sigmoid(hs @ b_proj^T)
__global__ __launch_bounds__(256) void beta_k(
    const float* __restrict__ hs, const float* __restrict__ bw, float* __restrict__ beta)
{
    int bl = blockIdx.x;
    const float* xr = hs + (size_t)bl * DD;
    float a0=0.f,a1=0.f,a2=0.f,a3=0.f;
    for (int k = threadIdx.x; k < DD; k += 256) {
        float xv = xr[k];
        a0 += xv * bw[k];
        a1 += xv * bw[DD + k];
        a2 += xv * bw[2*DD + k];
        a3 += xv * bw[3*DD + k];
    }
#pragma unroll
    for (int off = 32; off > 0; off >>= 1) {
        a0 += __shfl_down(a0, off); a1 += __shfl_down(a1, off);
        a2 += __shfl_down(a2, off); a3 += __shfl_down(a3, off);
    }
    __shared__ float red[4][4];
    int wv = threadIdx.x >> 6, ln = threadIdx.x & 63;
    if (ln == 0) { red[wv][0]=a0; red[wv][1]=a1; red[wv][2]=a2; red[wv][3]=a3; }
    __syncthreads();
    if (threadIdx.x < 4) {
        int h = threadIdx.x;
        float s = red[0][h] + red[1][h] + red[2][h] + red[3][h];
        beta[(size_t)bl * HH + h] = 1.0f / (1.0f + expf(-s));
    }
}

// ------------------------------------------------- k transpose: k[b,l,h*DH+e] -> kT[bh,e,l]
__global__ __launch_bounds__(256) void tr_k(
    const unsigned short* __restrict__ k, unsigned short* __restrict__ kT)
{
    int et = blockIdx.x & 3;
    int lt = (blockIdx.x >> 2) & 63;
    int bh = blockIdx.x >> 8;
    int h = bh & 3, b = bh >> 2;
    __shared__ unsigned short tile[64][72];
    int t = threadIdx.x;
    int tr = t >> 4;
    int tc = (t & 15) * 4;
#pragma unroll
    for (int i = 0; i < 4; ++i) {
        int l = tr + i * 16;
        ushort4 v = *(const ushort4*)(k + ((size_t)b * LL + lt*64 + l) * DD + h * DH + et*64 + tc);
        *(ushort4*)&tile[l][tc] = v;
    }
    __syncthreads();
#pragma unroll
    for (int i = 0; i < 4; ++i) {
        int e = tr + i * 16;
        ushort4 v;
        v.x = tile[tc+0][e]; v.y = tile[tc+1][e];
        v.z = tile[tc+2][e]; v.w = tile[tc+3][e];
        *(ushort4*)(kT + ((size_t)bh * DH + et*64 + e) * LL + (size_t)lt*64 + tc) = v;
    }
}

// ------------------------------------------------- u transpose: u[bh,l,d] -> uT[bh,d,l]
__global__ __launch_bounds__(256) void tru_k(
    const unsigned short* __restrict__ u, unsigned short* __restrict__ uT)
{
    int et = blockIdx.x & 3;
    int lt = (blockIdx.x >> 2) & 63;
    int bh = blockIdx.x >> 8;
    __shared__ unsigned short tile[64][72];
    int t = threadIdx.x;
    int tr = t >> 4;
    int tc = (t & 15) * 4;
#pragma unroll
    for (int i = 0; i < 4; ++i) {
        int l = tr + i * 16;
        ushort4 v = *(const ushort4*)(u + ((size_t)bh * LL + lt*64 + l) * DH + et*64 + tc);
        *(ushort4*)&tile[l][tc] = v;
    }
    __syncthreads();
#pragma unroll
    for (int i = 0; i < 4; ++i) {
        int e = tr + i * 16;
        ushort4 v;
        v.x = tile[tc+0][e]; v.y = tile[tc+1][e];
        v.z = tile[tc+2][e]; v.w = tile[tc+3][e];
        *(ushort4*)(uT + ((size_t)bh * DH + et*64 + e) * LL + (size_t)lt*64 + tc) = v;
    }
}

// ------------------------------------------------- per-chunk prep (attn out bf16)
__global__ __launch_bounds__(256) void chunk_prep_k(
    const unsigned short* __restrict__ q, const unsigned short* __restrict__ k,
    const float* __restrict__ v, const float* __restrict__ beta,
    unsigned short* __restrict__ u_out, unsigned short* __restrict__ w_out,
    unsigned short* __restrict__ attn_out)
{
    int ci = blockIdx.x & (NC - 1);
    int bh = blockIdx.x >> 7;
    int h = bh & (HH - 1), b = bh >> 2;
    __shared__ float kt[CH][DH + 4];
    __shared__ float Am[CH][CH + 1];
    __shared__ float Ab[CH][CH + 1];
    __shared__ float bet[CH];
    int t = threadIdx.x;
    size_t qgbase = (size_t)b * LL + (size_t)ci * CH;

    for (int i = t; i < CH * (DH / 4); i += 256) {
        int r = i >> 6;
        int c4 = (i & 63) * 4;
        ushort4 kv = *(const ushort4*)(k + (qgbase + r) * DD + h * DH + c4);
        kt[r][c4+0] = bf2f(kv.x); kt[r][c4+1] = bf2f(kv.y);
        kt[r][c4+2] = bf2f(kv.z); kt[r][c4+3] = bf2f(kv.w);
    }
    if (t < CH) bet[t] = beta[(qgbase + t) * HH + h];
    __syncthreads();

    int c = t >> 3, e0 = (t & 7) * 4;
    {
        float accA[4] = {0,0,0,0}, accT[4] = {0,0,0,0};
        const unsigned short* qrow = q + (qgbase + c) * DD + h * DH;
        for (int d0 = 0; d0 < DH; d0 += 4) {
            float4 kc = *(const float4*)&kt[c][d0];
            ushort4 qv = *(const ushort4*)(qrow + d0);
            float qx = bf2f(qv.x), qy = bf2f(qv.y), qz = bf2f(qv.z), qw = bf2f(qv.w);
#pragma unroll
            for (int e = 0; e < 4; ++e) {
                float4 ke = *(const float4*)&kt[e0 + e][d0];
                accA[e] += kc.x*ke.x + kc.y*ke.y + kc.z*ke.z + kc.w*ke.w;
                accT[e] += qx*ke.x + qy*ke.y + qz*ke.z + qw*ke.w;
            }
        }
        float bc = bet[c];
        size_t abase = (size_t)blockIdx.x * (CH * CH) + (size_t)c * CH;
#pragma unroll
        for (int e = 0; e < 4; ++e) {
            int ee = e0 + e;
            Am[c][ee] = (ee < c) ? (-bc * accA[e]) : 0.0f;
            attn_out[abase + ee] = (ee <= c) ? f2bf(accT[e]) : (unsigned short)0;
        }
    }
    __syncthreads();

    for (int i = 1; i < CH; ++i) {
        float upd = 0.0f;
        if (t < i) {
#pragma unroll
            for (int kk = 0; kk < CH; ++kk) upd += Am[i][kk] * Am[kk][t];
        }
        __syncthreads();
        if (t < i) Am[i][t] += upd;
        __syncthreads();
    }

    for (int i = t; i < CH * CH; i += 256) {
        int cc = i >> 5, ee = i & 31;
        float val = Am[cc][ee] + (cc == ee ? 1.0f : 0.0f);
        Ab[cc][ee] = val * bet[ee];
    }
    __syncthreads();

    int c2 = t >> 3, dd0 = (t & 7) * 32;
    float accu[32];
#pragma unroll
    for (int j = 0; j < 32; ++j) accu[j] = 0.0f;
    for (int e = 0; e < CH; ++e) {
        float ab = Ab[c2][e];
        const float* vrow = v + (qgbase + e) * DD + h * DH + dd0;
#pragma unroll
        for (int j4 = 0; j4 < 8; ++j4) {
            float4 v4 = *(const float4*)(vrow + j4 * 4);
            accu[j4*4+0] += ab * v4.x; accu[j4*4+1] += ab * v4.y;
            accu[j4*4+2] += ab * v4.z; accu[j4*4+3] += ab * v4.w;
        }
    }
    size_t obase = ((size_t)bh * LL + (size_t)ci * CH + c2) * DH + dd0;
#pragma unroll
    for (int j4 = 0; j4 < 8; ++j4) {
        ushort4 o;
        o.x = f2bf(accu[j4*4+0]); o.y = f2bf(accu[j4*4+1]);
        o.z = f2bf(accu[j4*4+2]); o.w = f2bf(accu[j4*4+3]);
        *(ushort4*)(u_out + obase + j4*4) = o;
    }

#pragma unroll
    for (int j = 0; j < 32; ++j) accu[j] = 0.0f;
    for (int e = 0; e < CH; ++e) {
        float ab = Ab[c2][e];
#pragma unroll
        for (int j4 = 0; j4 < 8; ++j4) {
            float4 v4 = *(const float4*)&kt[e][dd0 + j4*4];
            accu[j4*4+0] += ab * v4.x; accu[j4*4+1] += ab * v4.y;
            accu[j4*4+2] += ab * v4.z; accu[j4*4+3] += ab * v4.w;
        }
    }
#pragma unroll
    for (int j4 = 0; j4 < 8; ++j4) {
        ushort4 o;
        o.x = f2bf(accu[j4*4+0]); o.y = f2bf(accu[j4*4+1]);
        o.z = f2bf(accu[j4*4+2]); o.w = f2bf(accu[j4*4+3]);
        *(ushort4*)(w_out + obase + j4*4) = o;
    }
}

// ------------------------------------------------- chunk scan v5: MFMA + 128 blocks +
// XCD-local swizzle + register prefetch + LDS-only barriers + double-buffered LDS.
__global__ __launch_bounds__(256) void scan5_k(
    const unsigned short* __restrict__ q, const unsigned short* __restrict__ kT,
    const unsigned short* __restrict__ uT, const unsigned short* __restrict__ w,
    const unsigned short* __restrict__ attn, float* __restrict__ dout)
{
    // bh in LOW bits: the 16 dv-slice blocks of one bh land on one XCD (round-robin
    // dispatch heuristic) -> shared L2 for w/q/kT/uT.
    const int bh = blockIdx.x & 7;
    const int jb = blockIdx.x >> 3;
    const int h = bh & (HH - 1), b = bh >> 2;
    const int jcol = jb * 16;
    const int wave = threadIdx.x >> 6, lane = threadIdx.x & 63;
    const int lr = lane & 15, lg = lane >> 4;

    __shared__ unsigned short SbT[2][16][264];   // [par][col][e] bf16
    __shared__ unsigned short uadjT[2][16][40];  // [par][col][cc] bf16
    __shared__ float Pred[2][4][64][18];         // [par][src wave][m][col], pitch 18: 2-way clean

    floatx4 Sacc[4];
#pragma unroll
    for (int mt = 0; mt < 4; ++mt) Sacc[mt] = (floatx4){0.f,0.f,0.f,0.f};

    const unsigned short* qb  = q + (size_t)b * LL * DD + h * DH;
    const unsigned short* wb  = w + (size_t)bh * LL * DH;
    const unsigned short* uTb = uT + (size_t)bh * DH * LL
                                + (size_t)(jcol + lr) * LL + (wave & 1) * 16 + lg * 4;
    const unsigned short* kTb = kT + (size_t)bh * DH * LL;
    const unsigned short* atb = attn + (size_t)bh * NC * (CH * CH)
                                + (size_t)((wave & 1) * 16 + lr) * CH + lg * 8;
    float* db = dout + (size_t)bh * LL * DH;

    // double-buffered prefetch registers
    short8 pw0[2][2], pw1[2][2], pq0[2][2], pq1[2][2], pk[2][4], pa[2];
    ushort4 pu[2];

    // preload chunk 0 into slot 0
    {
#pragma unroll
        for (int kt = 0; kt < 2; ++kt) {
            const int e0 = 64 * wave + 32 * kt + lg * 8;
            pw0[0][kt] = *(const short8*)(wb + (size_t)lr * DH + e0);
            pw1[0][kt] = *(const short8*)(wb + (size_t)(16 + lr) * DH + e0);
            pq0[0][kt] = *(const short8*)(qb + (size_t)lr * DD + e0);
            pq1[0][kt] = *(const short8*)(qb + (size_t)(16 + lr) * DD + e0);
        }
#pragma unroll
        for (int mt = 0; mt < 4; ++mt)
            pk[0][mt] = *(const short8*)(kTb + (size_t)(64 * wave + 16 * mt + lr) * LL + lg * 8);
        pu[0] = *(const ushort4*)(uTb);
        pa[0] = *(const short8*)(atb);
    }

#pragma unroll 2
    for (int ci = 0; ci < NC; ++ci) {
        const int p = ci & 1;
        const int l0 = ci * CH;

        // 1) pack wave's S slice -> SbT[p][col][e]
#pragma unroll
        for (int mt = 0; mt < 4; ++mt) {
            int e0 = 64 * wave + 16 * mt + lg * 4;
            *(unsigned int*)&SbT[p][lr][e0]     = pkbf(Sacc[mt][0], Sacc[mt][1]);
            *(unsigned int*)&SbT[p][lr][e0 + 2] = pkbf(Sacc[mt][2], Sacc[mt][3]);
        }

        // prefetch chunk ci+1 (clamped) into slot p^1 — stays in flight across barriers
        {
            const int cn = (ci + 1 < NC) ? (ci + 1) : ci;
            const int ln = cn * CH;
#pragma unroll
            for (int kt = 0; kt < 2; ++kt) {
                const int e0 = 64 * wave + 32 * kt + lg * 8;
                pw0[p^1][kt] = *(const short8*)(wb + (size_t)(ln + lr) * DH + e0);
                pw1[p^1][kt] = *(const short8*)(wb + (size_t)(ln + 16 + lr) * DH + e0);
                pq0[p^1][kt] = *(const short8*)(qb + (size_t)(ln + lr) * DD + e0);
                pq1[p^1][kt] = *(const short8*)(qb + (size_t)(ln + 16 + lr) * DD + e0);
            }
#pragma unroll
            for (int mt = 0; mt < 4; ++mt)
                pk[p^1][mt] = *(const short8*)(kTb + (size_t)(64 * wave + 16 * mt + lr) * LL + ln + lg * 8);
            pu[p^1] = *(const ushort4*)(uTb + ln);
            pa[p^1] = *(const short8*)(atb + (size_t)cn * (CH * CH));
        }
        lds_barrier();   // (a) SbT[p] visible

        // 2) partial [w0,w1,q0,q1] @ S over wave's e-slice (K = 64)
        floatx4 P0 = (floatx4){0.f,0.f,0.f,0.f}, P1 = P0, P2 = P0, P3 = P0;
#pragma unroll
        for (int kt = 0; kt < 2; ++kt) {
            const int e0 = 64 * wave + 32 * kt + lg * 8;
            short8 sb = *(const short8*)&SbT[p][lr][e0];
            P0 = __builtin_amdgcn_mfma_f32_16x16x32_bf16(pw0[p][kt], sb, P0, 0,0,0);
            P1 = __builtin_amdgcn_mfma_f32_16x16x32_bf16(pw1[p][kt], sb, P1, 0,0,0);
            P2 = __builtin_amdgcn_mfma_f32_16x16x32_bf16(pq0[p][kt], sb, P2, 0,0,0);
            P3 = __builtin_amdgcn_mfma_f32_16x16x32_bf16(pq1[p][kt], sb, P3, 0,0,0);
        }
#pragma unroll
        for (int r = 0; r < 4; ++r) {
            Pred[p][wave][ 0 + lg * 4 + r][lr] = P0[r];
            Pred[p][wave][16 + lg * 4 + r][lr] = P1[r];
            Pred[p][wave][32 + lg * 4 + r][lr] = P2[r];
            Pred[p][wave][48 + lg * 4 + r][lr] = P3[r];
        }
        lds_barrier();   // (b) Pred[p] visible

        // 3) reduce: wave owns m-tile = wave (0:w0, 1:w1, 2:q0, 3:q1)
        float red[4];
#pragma unroll
        for (int r = 0; r < 4; ++r) {
            int m = wave * 16 + lg * 4 + r;
            red[r] = Pred[p][0][m][lr] + Pred[p][1][m][lr] + Pred[p][2][m][lr] + Pred[p][3][m][lr];
        }

        // 4) waves 0,1: uadj = u - w@S -> uadjT[p][col][cc]
        if (wave < 2) {
            ushort4 u4 = pu[p];
            float ua0 = bf2f(u4.x) - red[0];
            float ua1 = bf2f(u4.y) - red[1];
            float ua2 = bf2f(u4.z) - red[2];
            float ua3 = bf2f(u4.w) - red[3];
            int cc0 = wave * 16 + lg * 4;
            *(unsigned int*)&uadjT[p][lr][cc0]     = pkbf(ua0, ua1);
            *(unsigned int*)&uadjT[p][lr][cc0 + 2] = pkbf(ua2, ua3);
        }
        lds_barrier();   // (c) uadjT[p] visible

        short8 ub = *(const short8*)&uadjT[p][lr][lg * 8];

        // 5) waves 2,3: O = q@S + attn@uadj -> dout
        if (wave >= 2) {
            floatx4 Ot = (floatx4){red[0], red[1], red[2], red[3]};
            Ot = __builtin_amdgcn_mfma_f32_16x16x32_bf16(pa[p], ub, Ot, 0,0,0);
#pragma unroll
            for (int r = 0; r < 4; ++r)
                db[(size_t)(l0 + (wave - 2) * 16 + lg * 4 + r) * DH + jcol + lr] = Ot[r];
        }

        // 6) S slice += kT @ uadj  (K = 32)
#pragma unroll
        for (int mt = 0; mt < 4; ++mt)
            Sacc[mt] = __builtin_amdgcn_mfma_f32_16x16x32_bf16(pk[p][mt], ub, Sacc[mt], 0,0,0);
        // no trailing barrier: parity p is untouched until ci+2, guarded by (a),(b),(c) of ci+1
    }
}

// ------------------------------------------------- per-head stats
__global__ __launch_bounds__(256) void stats_k(
    const float* __restrict__ ls, const float* __restrict__ llb,
    const float* __restrict__ dox, const float* __restrict__ v,
    float* __restrict__ stats)
{
    int bl = blockIdx.x;
    int b = bl >> 12, l = bl & (LL - 1);
    int wv = threadIdx.x >> 6, ln = threadIdx.x & 63;
    size_t ibase = (size_t)bl * DD + wv * DH;
    size_t dbase = (((size_t)(b * HH + wv)) * LL + l) * DH;
#pragma unroll
    for (int tn = 0; tn < 4; ++tn) {
        const float* p; size_t base;
        if (tn == 0)      { p = ls;  base = ibase; }
        else if (tn == 1) { p = llb; base = ibase; }
        else if (tn == 2) { p = dox; base = dbase; }
        else              { p = v;   base = ibase; }
        float4 x = *(const float4*)(p + base + ln * 4);
        float sm = x.x + x.y + x.z + x.w;
        float sq = x.x*x.x + x.y*x.y + x.z*x.z + x.w*x.w;
        float sa = fabsf(x.x) + fabsf(x.y) + fabsf(x.z) + fabsf(x.w);
#pragma unroll
        for (int off = 32; off > 0; off >>= 1) {
            sm += __shfl_down(sm, off);
            sq += __shfl_down(sq, off);
            sa += __shfl_down(sa, off);
        }
        if (ln == 0) {
            float mean = sm * (1.0f / DH);
            float var = sq * (1.0f / DH) - mean * mean;
            float am = sa * (1.0f / DH);
            float l2 = sqrtf(sq);
            *(float4*)(stats + (size_t)bl * 64 + wv * 16 + tn * 4) =
                make_float4(mean, var, am, l2);
        }
    }
}

// ------------------------------------------------- gate finish v2: coalesced, single reduction
__global__ __launch_bounds__(256) void gate_fin2_k(
    const float* __restrict__ hpart, const float* __restrict__ stats,
    const unsigned short* __restrict__ w1s,   // [1024][16] bf16
    const float* __restrict__ w2, const float* __restrict__ b2,
    const float* __restrict__ ltemp, float* __restrict__ fw)
{
    const int bl = blockIdx.x;
    const int t = threadIdx.x;
    const float temp = log1pf(expf(ltemp[0])) + 1e-4f;
    __shared__ float st[HH][16];
    __shared__ float red[4][16];
    __shared__ float fin[16];
    if (t < 64) st[t >> 4][t & 15] = stats[(size_t)bl * 64 + t];

    const int e0 = t * 4;
    float4 hp4 = *(const float4*)(hpart + (size_t)bl * DD + e0);
    float hp[4] = {hp4.x, hp4.y, hp4.z, hp4.w};
    float w2a[4][4];
#pragma unroll
    for (int j = 0; j < 4; ++j) {
        float4 wv = *(const float4*)(w2 + (size_t)j * 1024 + e0);
        w2a[j][0] = wv.x; w2a[j][1] = wv.y; w2a[j][2] = wv.z; w2a[j][3] = wv.w;
    }
    uint4 wpk[8];
    const uint4* wp = (const uint4*)(w1s + (size_t)e0 * 16);
#pragma unroll
    for (int i = 0; i < 8; ++i) wpk[i] = wp[i];
    __syncthreads();

    float lg[4][4];
#pragma unroll
    for (int h = 0; h < 4; ++h)
#pragma unroll
        for (int j = 0; j < 4; ++j) lg[h][j] = 0.0f;

#pragma unroll
    for (int ii = 0; ii < 4; ++ii) {
        float xh[4] = {hp[ii], hp[ii], hp[ii], hp[ii]};
        unsigned arr[8] = {wpk[ii*2].x, wpk[ii*2].y, wpk[ii*2].z, wpk[ii*2].w,
                           wpk[ii*2+1].x, wpk[ii*2+1].y, wpk[ii*2+1].z, wpk[ii*2+1].w};
#pragma unroll
        for (int p = 0; p < 8; ++p) {
            float wlo = bflo(arr[p]), whi = bfhi(arr[p]);
            int s = p * 2;
#pragma unroll
            for (int h = 0; h < 4; ++h)
                xh[h] += st[h][s] * wlo + st[h][s + 1] * whi;
        }
#pragma unroll
        for (int h = 0; h < 4; ++h) {
            float x = xh[h];
            float g = 0.5f * x * (1.0f + erff(x * 0.70710678118654752f));
            lg[h][0] += g * w2a[0][ii];
            lg[h][1] += g * w2a[1][ii];
            lg[h][2] += g * w2a[2][ii];
            lg[h][3] += g * w2a[3][ii];
        }
    }

#pragma unroll
    for (int h = 0; h < 4; ++h)
#pragma unroll
        for (int j = 0; j < 4; ++j)
#pragma unroll
            for (int off = 32; off > 0; off >>= 1)
                lg[h][j] += __shfl_down(lg[h][j], off);

    const int wv = t >> 6, ln = t & 63;
    if (ln == 0) {
#pragma unroll
        for (int h = 0; h < 4; ++h)
#pragma unroll
            for (int j = 0; j < 4; ++j) red[wv][h * 4 + j] = lg[h][j];
    }
    __syncthreads();
    if (t < 16) {
        float s = red[0][t] + red[1][t] + red[2][t] + red[3][t] + b2[t & 3];
        fin[t] = s / temp;
    }
    __syncthreads();
    if (t < 4) {
        float l0 = fin[t*4], l1 = fin[t*4+1], l2 = fin[t*4+2], l3 = fin[t*4+3];
        float m = fmaxf(fmaxf(l0, l1), fmaxf(l2, l3));
        float e0x = expf(l0-m), e1 = expf(l1-m), e2 = expf(l2-m), e3 = expf(l3-m);
        float inv = 1.0f / (e0x + e1 + e2 + e3);
        *(float4*)(fw + (size_t)bl * 16 + t * 4) = make_float4(e0x*inv, e1*inv, e2*inv, e3*inv);
    }
}

// ------------------------------------------------- combine + rms norm
__global__ __launch_bounds__(256) void combine_k(
    const float* __restrict__ ls, const float* __restrict__ llb,
    const float* __restrict__ dox, const float* __restrict__ v,
    const float* __restrict__ fw, const float* __restrict__ rss,
    const float* __restrict__ rsl, const float* __restrict__ onw,
    float* __restrict__ opre)
{
    int h = blockIdx.x & (HH - 1);
    int bl = blockIdx.x >> 2;
    int b = bl >> 12, l = bl & (LL - 1);
    int d = threadIdx.x;
    size_t i1 = (size_t)blockIdx.x * DH + d;
    size_t i2 = (((size_t)(b * HH + h)) * LL + l) * DH + d;
    const float* fwp = fw + (size_t)blockIdx.x * 4;
    float f0 = fwp[0], f1 = fwp[1], f2 = fwp[2], f3 = fwp[3];
    float aS = rss[0], aL = rsl[0];
    float vls = ls[i1], vll = llb[i1], vd = dox[i2], vv = v[i1];
    float o = f0*vls + f1*vll + f2*vd + f3*vv + aS*vls + aL*vll;
    float s = o * o;
#pragma unroll
    for (int off = 32; off > 0; off >>= 1) s += __shfl_down(s, off);
    __shared__ float red[4];
    int wv = threadIdx.x >> 6, ln = threadIdx.x & 63;
    if (ln == 0) red[wv] = s;
    __syncthreads();
    float ms = (red[0] + red[1] + red[2] + red[3]) * (1.0f / DH);
    opre[(size_t)bl * DD + h * DH + d] = o * rsqrtf(ms + 1e-5f) * onw[d];
}

// ================================================================ launch
extern "C" void kernel_launch(void* const* d_in, const int* in_sizes, int n_in,
                              void* d_out, int out_size, void* d_ws, size_t ws_size,
                              hipStream_t stream)
{
    const float* hs  = (const float*)d_in[0];
    const float* qw  = (const float*)d_in[1];
    const float* kw  = (const float*)d_in[2];
    const float* vw  = (const float*)d_in[3];
    const float* bw  = (const float*)d_in[4];
    const float* qcw = (const float*)d_in[5];
    const float* kcw = (const float*)d_in[6];
    const float* vcw = (const float*)d_in[7];
    const float* fsw = (const float*)d_in[8];
    const float* flw = (const float*)d_in[9];
    const float* w1  = (const float*)d_in[10];
    const float* b1  = (const float*)d_in[11];
    const float* w2  = (const float*)d_in[12];
    const float* b2  = (const float*)d_in[13];
    const float* lt  = (const float*)d_in[14];
    const float* rss = (const float*)d_in[15];
    const float* rsl = (const float*)d_in[16];
    const float* onw = (const float*)d_in[17];
    const float* opw = (const float*)d_in[18];
    float* out = (float*)d_out;

    float* wsf = (float*)d_ws;
    float* tmp   = wsf;
    unsigned short* ktbuf = (unsigned short*)tmp;
    unsigned short* uTbuf = (unsigned short*)(wsf + BLD/2);
    float* vbuf  = wsf + BLD;
    float* dbuf  = wsf + 2*BLD;
    unsigned short* hsb = (unsigned short*)(wsf + 2*BLD);
    unsigned short* qbuf = (unsigned short*)(wsf + 3*BLD);
    unsigned short* kbuf = qbuf + BLD;
    float* hpart = wsf + 3*BLD;
    float* opre  = wsf + 3*BLD;
    unsigned short* ubuf = (unsigned short*)(wsf + 4*BLD);
    unsigned short* wbuf = ubuf + BLD;
    float* llbuf = wsf + 4*BLD;
    float* lsbuf = tmp;
    unsigned short* attnb = (unsigned short*)(wsf + 5*BLD);
    float* statsb = wsf + 5*BLD + 524288;
    float* fwbuf  = statsb + (size_t)BL*HH*16;
    float* betab  = fwbuf + (size_t)BL*HH*4;
    unsigned short* w1sp = (unsigned short*)(betab + (size_t)BL*HH);

    dim3 gg(8, 64);   // N/128, M/128

    cvt_bf_k<<<(int)(BLD/1024), 256, 0, stream>>>(hs, hsb);
    w1s_prep_k<<<64, 256, 0, stream>>>(w1, w1sp);

    gemm_mfma_bfA<<<gg, 256, 0, stream>>>(hsb, DD, qw, DD, tmp, DD, DD);
    convnorm_qk_k<<<BL*HH, 256, 0, stream>>>(tmp, qcw, qbuf);
    gemm_mfma_bfA<<<gg, 256, 0, stream>>>(hsb, DD, kw, DD, tmp, DD, DD);
    convnorm_qk_k<<<BL*HH, 256, 0, stream>>>(tmp, kcw, kbuf);
    gemm_mfma_bfA<<<gg, 256, 0, stream>>>(hsb, DD, vw, DD, tmp, DD, DD);
    conv_silu_k<<<(int)(BLD/256), 256, 0, stream>>>(tmp, vcw, vbuf);

    beta_k<<<BL, 256, 0, stream>>>(hs, bw, betab);

    tr_k<<<8*64*4, 256, 0, stream>>>(kbuf, ktbuf);
    chunk_prep_k<<<BB*HH*NC, 256, 0, stream>>>(qbuf, kbuf, vbuf, betab, ubuf, wbuf, attnb);
    tru_k<<<8*64*4, 256, 0, stream>>>(ubuf, uTbuf);

    scan5_k<<<BB*HH*16, 256, 0, stream>>>(qbuf, ktbuf, uTbuf, wbuf, attnb, dbuf);

    fir2_k<5><<<BB*64*16, 256, 0, stream>>>(vbuf, fsw, lsbuf);
    fir2_k<64><<<BB*64*16, 256, 0, stream>>>(vbuf, flw, llbuf);

    stats_k<<<BL, 256, 0, stream>>>(lsbuf, llbuf, dbuf, vbuf, statsb);

    gemm_mfma<<<gg, 256, 0, stream>>>(hs, DD, w1, 1040, b1, hpart, DD, DD);
    gate_fin2_k<<<BL, 256, 0, stream>>>(hpart, statsb, w1sp, w2, b2, lt, fwbuf);

    combine_k<<<BL*HH, 256, 0, stream>>>(lsbuf, llbuf, dbuf, vbuf, fwbuf, rss, rsl, onw, opre);

    gemm_mfma<<<gg, 256, 0, stream>>>(opre, DD, opw, DD, nullptr, out, DD, DD);
}

// Round 10
// 1002.927 us; speedup vs baseline: 3.1624x; 1.0379x over previous
//
#include <hip/hip_runtime.h>
#include <hip/hip_bf16.h>

#define BB 2
#define LL 4096
#define DD 1024
#define HH 4
#define DH 256
#define CH 32
#define NC (LL/CH)     // 128
#define BL (BB*LL)     // 8192
#define BLD ((size_t)BB*LL*DD) // 8388608

typedef __attribute__((ext_vector_type(8))) short short8;
typedef __attribute__((ext_vector_type(4))) float floatx4;

__device__ __forceinline__ float bf2f(unsigned short u) {
    union { float f; unsigned int i; } x; x.i = ((unsigned int)u) << 16; return x.f;
}
__device__ __forceinline__ float bflo(unsigned int u) {
    union { float f; unsigned int i; } x; x.i = u << 16; return x.f;
}
__device__ __forceinline__ float bfhi(unsigned int u) {
    union { float f; unsigned int i; } x; x.i = u & 0xFFFF0000u; return x.f;
}
__device__ __forceinline__ unsigned short f2bf(float f) {
    union { float f; unsigned int i; } x; x.f = f;
    unsigned int r = x.i + 0x7FFFu + ((x.i >> 16) & 1u);
    return (unsigned short)(r >> 16);
}
// pack two f32 -> (bf16(b)<<16)|bf16(a), round-half-up
__device__ __forceinline__ unsigned int pkbf(float a, float b) {
    unsigned int ua = __float_as_uint(a) + 0x8000u;
    unsigned int ub = __float_as_uint(b) + 0x8000u;
    return __builtin_amdgcn_perm(ub, ua, 0x07060302);
}
// barrier with LDS-only drain (no vmcnt drain -> prefetch loads stay in flight)
__device__ __forceinline__ void lds_barrier() {
    __builtin_amdgcn_s_waitcnt(0xC07F);
    __builtin_amdgcn_s_barrier();
}

// ---------------------------------------------------------------- f32 -> bf16 bulk convert
__global__ __launch_bounds__(256) void cvt_bf_k(
    const float* __restrict__ x, unsigned short* __restrict__ y)
{
    size_t i = ((size_t)blockIdx.x * 256 + threadIdx.x) * 4;
    float4 v = *(const float4*)(x + i);
    ushort4 o;
    o.x = f2bf(v.x); o.y = f2bf(v.y); o.z = f2bf(v.z); o.w = f2bf(v.w);
    *(ushort4*)(y + i) = o;
}

// ---------------------------------------------------------------- pack w1[:,1024:1040] -> bf16 [1024][16]
__global__ __launch_bounds__(256) void w1s_prep_k(
    const float* __restrict__ w1, unsigned short* __restrict__ w1s)
{
    int idx = blockIdx.x * 256 + threadIdx.x;   // 16384
    int e = idx >> 4, s = idx & 15;
    w1s[idx] = f2bf(w1[(size_t)e * 1040 + 1024 + s]);
}

// ---------------------------------------------------------------- bf16 MFMA GEMM (NT), f32 A, f32 W
__global__ __launch_bounds__(256) void gemm_mfma(
    const float* __restrict__ A, int lda,
    const float* __restrict__ W, int ldw,
    const float* __restrict__ bias,
    float* __restrict__ C, int ldc, int K)
{
    __shared__ unsigned short Abuf[128][56];
    __shared__ unsigned short Bbuf[128][56];
    const int t = threadIdx.x;
    const int wave = t >> 6, lane = t & 63;
    const int wm = wave >> 1, wn = wave & 1;
    const int row0 = blockIdx.y * 128, col0 = blockIdx.x * 128;

    floatx4 acc[4][4];
#pragma unroll
    for (int i = 0; i < 4; ++i)
#pragma unroll
        for (int j = 0; j < 4; ++j) acc[i][j] = (floatx4){0.f, 0.f, 0.f, 0.f};

    const int fr = lane & 15, fk = (lane >> 4) * 8;

    for (int kt = 0; kt < K; kt += 32) {
        __syncthreads();
#pragma unroll
        for (int it = 0; it < 2; ++it) {
            int idx = t + it * 256;
            int r = idx >> 2, s = (idx & 3) * 8;
            const float* ap = A + (size_t)(row0 + r) * lda + kt + s;
            float4 a0 = *(const float4*)(ap);
            float4 a1 = *(const float4*)(ap + 4);
            ushort4 p0, p1;
            p0.x = f2bf(a0.x); p0.y = f2bf(a0.y); p0.z = f2bf(a0.z); p0.w = f2bf(a0.w);
            p1.x = f2bf(a1.x); p1.y = f2bf(a1.y); p1.z = f2bf(a1.z); p1.w = f2bf(a1.w);
            *(ushort4*)&Abuf[r][s]     = p0;
            *(ushort4*)&Abuf[r][s + 4] = p1;
            const float* wp = W + (size_t)(col0 + r) * ldw + kt + s;
            float4 b0 = *(const float4*)(wp);
            float4 b1 = *(const float4*)(wp + 4);
            ushort4 q0, q1;
            q0.x = f2bf(b0.x); q0.y = f2bf(b0.y); q0.z = f2bf(b0.z); q0.w = f2bf(b0.w);
            q1.x = f2bf(b1.x); q1.y = f2bf(b1.y); q1.z = f2bf(b1.z); q1.w = f2bf(b1.w);
            *(ushort4*)&Bbuf[r][s]     = q0;
            *(ushort4*)&Bbuf[r][s + 4] = q1;
        }
        __syncthreads();

        short8 afrag[4], bfrag[4];
#pragma unroll
        for (int i = 0; i < 4; ++i) {
            afrag[i] = *(const short8*)&Abuf[wm * 64 + i * 16 + fr][fk];
            bfrag[i] = *(const short8*)&Bbuf[wn * 64 + i * 16 + fr][fk];
        }
#pragma unroll
        for (int i = 0; i < 4; ++i)
#pragma unroll
            for (int j = 0; j < 4; ++j)
                acc[i][j] = __builtin_amdgcn_mfma_f32_16x16x32_bf16(
                    afrag[i], bfrag[j], acc[i][j], 0, 0, 0);
    }

    const int fc = lane & 15, frow = (lane >> 4) * 4;
#pragma unroll
    for (int j = 0; j < 4; ++j) {
        int col = col0 + wn * 64 + j * 16 + fc;
        float bv = bias ? bias[col] : 0.0f;
#pragma unroll
        for (int i = 0; i < 4; ++i) {
#pragma unroll
            for (int r = 0; r < 4; ++r) {
                int row = row0 + wm * 64 + i * 16 + frow + r;
                C[(size_t)row * ldc + col] = acc[i][j][r] + bv;
            }
        }
    }
}

// ---------------------------------------------------------------- bf16 MFMA GEMM (NT), bf16 A, bf16 B
__global__ __launch_bounds__(256) void gemm_bb(
    const unsigned short* __restrict__ A, int lda,
    const unsigned short* __restrict__ B, int ldb,
    float* __restrict__ C, int ldc, int K)
{
    __shared__ unsigned short Abuf[128][56];
    __shared__ unsigned short Bbuf[128][56];
    const int t = threadIdx.x;
    const int wave = t >> 6, lane = t & 63;
    const int wm = wave >> 1, wn = wave & 1;
    const int row0 = blockIdx.y * 128, col0 = blockIdx.x * 128;

    floatx4 acc[4][4];
#pragma unroll
    for (int i = 0; i < 4; ++i)
#pragma unroll
        for (int j = 0; j < 4; ++j) acc[i][j] = (floatx4){0.f, 0.f, 0.f, 0.f};

    const int fr = lane & 15, fk = (lane >> 4) * 8;

    for (int kt = 0; kt < K; kt += 32) {
        __syncthreads();
#pragma unroll
        for (int it = 0; it < 2; ++it) {
            int idx = t + it * 256;
            int r = idx >> 2, s = (idx & 3) * 8;
            uint4 av = *(const uint4*)(A + (size_t)(row0 + r) * lda + kt + s);
            *(uint4*)&Abuf[r][s] = av;
            uint4 bv = *(const uint4*)(B + (size_t)(col0 + r) * ldb + kt + s);
            *(uint4*)&Bbuf[r][s] = bv;
        }
        __syncthreads();

        short8 afrag[4], bfrag[4];
#pragma unroll
        for (int i = 0; i < 4; ++i) {
            afrag[i] = *(const short8*)&Abuf[wm * 64 + i * 16 + fr][fk];
            bfrag[i] = *(const short8*)&Bbuf[wn * 64 + i * 16 + fr][fk];
        }
#pragma unroll
        for (int i = 0; i < 4; ++i)
#pragma unroll
            for (int j = 0; j < 4; ++j)
                acc[i][j] = __builtin_amdgcn_mfma_f32_16x16x32_bf16(
                    afrag[i], bfrag[j], acc[i][j], 0, 0, 0);
    }

    const int fc = lane & 15, frow = (lane >> 4) * 4;
#pragma unroll
    for (int j = 0; j < 4; ++j) {
        int col = col0 + wn * 64 + j * 16 + fc;
#pragma unroll
        for (int i = 0; i < 4; ++i) {
#pragma unroll
            for (int r = 0; r < 4; ++r) {
                int row = row0 + wm * 64 + i * 16 + frow + r;
                C[(size_t)row * ldc + col] = acc[i][j][r];
            }
        }
    }
}

// --------------------------------------- causal dwconv K=4 + silu + head-l2norm -> bf16
__global__ __launch_bounds__(256) void convnorm_qk_k(
    const float* __restrict__ x, const float* __restrict__ w,
    unsigned short* __restrict__ y)
{
    int bl = blockIdx.x >> 2;
    int h  = blockIdx.x & 3;
    int l  = bl & (LL - 1);
    int d  = threadIdx.x;
    int c  = h * DH + d;
    const float* wp = w + (size_t)c * 4;
    const float* xp = x + (size_t)bl * DD + c;
    float acc = wp[3] * xp[0];
    if (l >= 1) acc += wp[2] * xp[-(int)DD];
    if (l >= 2) acc += wp[1] * xp[-2*(int)DD];
    if (l >= 3) acc += wp[0] * xp[-3*(int)DD];
    acc = acc / (1.0f + expf(-acc));
    float s = acc * acc;
#pragma unroll
    for (int off = 32; off > 0; off >>= 1) s += __shfl_down(s, off);
    __shared__ float red[4];
    int wv = threadIdx.x >> 6, ln = threadIdx.x & 63;
    if (ln == 0) red[wv] = s;
    __syncthreads();
    float tot = red[0] + red[1] + red[2] + red[3];
    y[(size_t)bl * DD + c] = f2bf(acc * rsqrtf(tot));
}

// ------------------------------------------------- causal depthwise conv K=4 + silu (f32)
__global__ __launch_bounds__(256) void conv_silu_k(
    const float* __restrict__ x, const float* __restrict__ w, float* __restrict__ y)
{
    size_t idx = (size_t)blockIdx.x * 256 + threadIdx.x;
    int c = (int)(idx & (DD - 1));
    int bl = (int)(idx >> 10);
    int l = bl & (LL - 1);
    const float* wp = w + (size_t)c * 4;
    const float* xp = x + (size_t)bl * DD + c;
    float acc = wp[3] * xp[0];
    if (l >= 1) acc += wp[2] * xp[-(int)DD];
    if (l >= 2) acc += wp[1] * xp[-2*(int)DD];
    if (l >= 3) acc += wp[0] * xp[-3*(int)DD];
    y[idx] = acc / (1.0f + expf(-acc));
}

// ------------------------------------------------- FIR causal depthwise conv, LDS-tiled
template<int K>
__global__ __launch_bounds__(256) void fir2_k(
    const float* __restrict__ x, const float* __restrict__ filt, float* __restrict__ y)
{
    const int ctile = blockIdx.x & 15;
    const int ltile = (blockIdx.x >> 4) & 63;
    const int b = blockIdx.x >> 10;
    const int RT = 64 + K - 1;
    __shared__ float xs[RT][64];
    __shared__ float fs[64][K + 1];
    const int t = threadIdx.x;
    const int l0 = ltile * 64;

    for (int i = t; i < RT * 16; i += 256) {
        int li = i >> 4, c4 = (i & 15) * 4;
        int l = l0 - (K - 1) + li;
        float4 v = make_float4(0.f, 0.f, 0.f, 0.f);
        if (l >= 0)
            v = *(const float4*)(x + ((size_t)b * LL + l) * DD + ctile * 64 + c4);
        *(float4*)&xs[li][c4] = v;
    }
    for (int i = t; i < 64 * K; i += 256) {
        fs[i / K][i % K] = filt[(size_t)ctile * 64 * K + i];
    }
    __syncthreads();

    const int c = t & 63, lg = t >> 6;
    float acc[16];
#pragma unroll
    for (int o = 0; o < 16; ++o) acc[o] = 0.f;
#pragma unroll
    for (int j = 0; j < 16 + K - 1; ++j) {
        float xv = xs[lg * 16 + j][c];
#pragma unroll
        for (int o = 0; o < 16; ++o) {
            int tap = j - o;
            if (tap >= 0 && tap < K) acc[o] += fs[c][tap] * xv;
        }
    }
    size_t base = ((size_t)b * LL + l0 + lg * 16) * DD + ctile * 64 + c;
#pragma unroll
    for (int o = 0; o < 16; ++o)
        y[base + (size_t)o * DD] = acc[o];
}

// ------------------------------------------------- beta = sigmoid(hs @ b_proj^T)
__global__ __launch_bounds__(256) void beta_k(
    const float* __restrict__ hs, const float* __restrict__ bw, float* __restrict__ beta)
{
    int bl = blockIdx.x;
    const float* xr = hs + (size_t)bl * DD;
    float a0=0.f,a1=0.f,a2=0.f,a3=0.f;
    for (int k = threadIdx.x; k < DD; k += 256) {
        float xv = xr[k];
        a0 += xv * bw[k];
        a1 += xv * bw[DD + k];
        a2 += xv * bw[2*DD + k];
        a3 += xv * bw[3*DD + k];
    }
#pragma unroll
    for (int off = 32; off > 0; off >>= 1) {
        a0 += __shfl_down(a0, off); a1 += __shfl_down(a1, off);
        a2 += __shfl_down(a2, off); a3 += __shfl_down(a3, off);
    }
    __shared__ float red[4][4];
    int wv = threadIdx.x >> 6, ln = threadIdx.x & 63;
    if (ln == 0) { red[wv][0]=a0; red[wv][1]=a1; red[wv][2]=a2; red[wv][3]=a3; }
    __syncthreads();
    if (threadIdx.x < 4) {
        int h = threadIdx.x;
        float s = red[0][h] + red[1][h] + red[2][h] + red[3][h];
        beta[(size_t)bl * HH + h] = 1.0f / (1.0f + expf(-s));
    }
}

// ------------------------------------------------- k transpose: k[b,l,h*DH+e] -> kT[bh,e,l]
__global__ __launch_bounds__(256) void tr_k(
    const unsigned short* __restrict__ k, unsigned short* __restrict__ kT)
{
    int et = blockIdx.x & 3;
    int lt = (blockIdx.x >> 2) & 63;
    int bh = blockIdx.x >> 8;
    int h = bh & 3, b = bh >> 2;
    __shared__ unsigned short tile[64][72];
    int t = threadIdx.x;
    int tr = t >> 4;
    int tc = (t & 15) * 4;
#pragma unroll
    for (int i = 0; i < 4; ++i) {
        int l = tr + i * 16;
        ushort4 v = *(const ushort4*)(k + ((size_t)b * LL + lt*64 + l) * DD + h * DH + et*64 + tc);
        *(ushort4*)&tile[l][tc] = v;
    }
    __syncthreads();
#pragma unroll
    for (int i = 0; i < 4; ++i) {
        int e = tr + i * 16;
        ushort4 v;
        v.x = tile[tc+0][e]; v.y = tile[tc+1][e];
        v.z = tile[tc+2][e]; v.w = tile[tc+3][e];
        *(ushort4*)(kT + ((size_t)bh * DH + et*64 + e) * LL + (size_t)lt*64 + tc) = v;
    }
}

// ------------------------------------------------- u transpose: u[bh,l,d] -> uT[bh,d,l]
__global__ __launch_bounds__(256) void tru_k(
    const unsigned short* __restrict__ u, unsigned short* __restrict__ uT)
{
    int et = blockIdx.x & 3;
    int lt = (blockIdx.x >> 2) & 63;
    int bh = blockIdx.x >> 8;
    __shared__ unsigned short tile[64][72];
    int t = threadIdx.x;
    int tr = t >> 4;
    int tc = (t & 15) * 4;
#pragma unroll
    for (int i = 0; i < 4; ++i) {
        int l = tr + i * 16;
        ushort4 v = *(const ushort4*)(u + ((size_t)bh * LL + lt*64 + l) * DH + et*64 + tc);
        *(ushort4*)&tile[l][tc] = v;
    }
    __syncthreads();
#pragma unroll
    for (int i = 0; i < 4; ++i) {
        int e = tr + i * 16;
        ushort4 v;
        v.x = tile[tc+0][e]; v.y = tile[tc+1][e];
        v.z = tile[tc+2][e]; v.w = tile[tc+3][e];
        *(ushort4*)(uT + ((size_t)bh * DH + et*64 + e) * LL + (size_t)lt*64 + tc) = v;
    }
}

// ------------------------------------------------- per-chunk prep (attn out bf16)
__global__ __launch_bounds__(256) void chunk_prep_k(
    const unsigned short* __restrict__ q, const unsigned short* __restrict__ k,
    const float* __restrict__ v, const float* __restrict__ beta,
    unsigned short* __restrict__ u_out, unsigned short* __restrict__ w_out,
    unsigned short* __restrict__ attn_out)
{
    int ci = blockIdx.x & (NC - 1);
    int bh = blockIdx.x >> 7;
    int h = bh & (HH - 1), b = bh >> 2;
    __shared__ float kt[CH][DH + 4];
    __shared__ float Am[CH][CH + 1];
    __shared__ float Ab[CH][CH + 1];
    __shared__ float bet[CH];
    int t = threadIdx.x;
    size_t qgbase = (size_t)b * LL + (size_t)ci * CH;

    for (int i = t; i < CH * (DH / 4); i += 256) {
        int r = i >> 6;
        int c4 = (i & 63) * 4;
        ushort4 kv = *(const ushort4*)(k + (qgbase + r) * DD + h * DH + c4);
        kt[r][c4+0] = bf2f(kv.x); kt[r][c4+1] = bf2f(kv.y);
        kt[r][c4+2] = bf2f(kv.z); kt[r][c4+3] = bf2f(kv.w);
    }
    if (t < CH) bet[t] = beta[(qgbase + t) * HH + h];
    __syncthreads();

    int c = t >> 3, e0 = (t & 7) * 4;
    {
        float accA[4] = {0,0,0,0}, accT[4] = {0,0,0,0};
        const unsigned short* qrow = q + (qgbase + c) * DD + h * DH;
        for (int d0 = 0; d0 < DH; d0 += 4) {
            float4 kc = *(const float4*)&kt[c][d0];
            ushort4 qv = *(const ushort4*)(qrow + d0);
            float qx = bf2f(qv.x), qy = bf2f(qv.y), qz = bf2f(qv.z), qw = bf2f(qv.w);
#pragma unroll
            for (int e = 0; e < 4; ++e) {
                float4 ke = *(const float4*)&kt[e0 + e][d0];
                accA[e] += kc.x*ke.x + kc.y*ke.y + kc.z*ke.z + kc.w*ke.w;
                accT[e] += qx*ke.x + qy*ke.y + qz*ke.z + qw*ke.w;
            }
        }
        float bc = bet[c];
        size_t abase = (size_t)blockIdx.x * (CH * CH) + (size_t)c * CH;
#pragma unroll
        for (int e = 0; e < 4; ++e) {
            int ee = e0 + e;
            Am[c][ee] = (ee < c) ? (-bc * accA[e]) : 0.0f;
            attn_out[abase + ee] = (ee <= c) ? f2bf(accT[e]) : (unsigned short)0;
        }
    }
    __syncthreads();

    for (int i = 1; i < CH; ++i) {
        float upd = 0.0f;
        if (t < i) {
#pragma unroll
            for (int kk = 0; kk < CH; ++kk) upd += Am[i][kk] * Am[kk][t];
        }
        __syncthreads();
        if (t < i) Am[i][t] += upd;
        __syncthreads();
    }

    for (int i = t; i < CH * CH; i += 256) {
        int cc = i >> 5, ee = i & 31;
        float val = Am[cc][ee] + (cc == ee ? 1.0f : 0.0f);
        Ab[cc][ee] = val * bet[ee];
    }
    __syncthreads();

    int c2 = t >> 3, dd0 = (t & 7) * 32;
    float accu[32];
#pragma unroll
    for (int j = 0; j < 32; ++j) accu[j] = 0.0f;
    for (int e = 0; e < CH; ++e) {
        float ab = Ab[c2][e];
        const float* vrow = v + (qgbase + e) * DD + h * DH + dd0;
#pragma unroll
        for (int j4 = 0; j4 < 8; ++j4) {
            float4 v4 = *(const float4*)(vrow + j4 * 4);
            accu[j4*4+0] += ab * v4.x; accu[j4*4+1] += ab * v4.y;
            accu[j4*4+2] += ab * v4.z; accu[j4*4+3] += ab * v4.w;
        }
    }
    size_t obase = ((size_t)bh * LL + (size_t)ci * CH + c2) * DH + dd0;
#pragma unroll
    for (int j4 = 0; j4 < 8; ++j4) {
        ushort4 o;
        o.x = f2bf(accu[j4*4+0]); o.y = f2bf(accu[j4*4+1]);
        o.z = f2bf(accu[j4*4+2]); o.w = f2bf(accu[j4*4+3]);
        *(ushort4*)(u_out + obase + j4*4) = o;
    }

#pragma unroll
    for (int j = 0; j < 32; ++j) accu[j] = 0.0f;
    for (int e = 0; e < CH; ++e) {
        float ab = Ab[c2][e];
#pragma unroll
        for (int j4 = 0; j4 < 8; ++j4) {
            float4 v4 = *(const float4*)&kt[e][dd0 + j4*4];
            accu[j4*4+0] += ab * v4.x; accu[j4*4+1] += ab * v4.y;
            accu[j4*4+2] += ab * v4.z; accu[j4*4+3] += ab * v4.w;
        }
    }
#pragma unroll
    for (int j4 = 0; j4 < 8; ++j4) {
        ushort4 o;
        o.x = f2bf(accu[j4*4+0]); o.y = f2bf(accu[j4*4+1]);
        o.z = f2bf(accu[j4*4+2]); o.w = f2bf(accu[j4*4+3]);
        *(ushort4*)(w_out + obase + j4*4) = o;
    }
}

// ------------------------------------------------- chunk scan v6: full-K wave roles,
// no Pred reduction, 2 LDS-only barriers/chunk, XCD swizzle + register prefetch.
// wave0: w rows[0:16) ; wave1: w rows[16:32) ; wave2: q rows[0:16) ; wave3: q rows[16:32).
// Each wave also owns S e-slice [64w,64w+64) in accumulators.
__global__ __launch_bounds__(256) void scan6_k(
    const unsigned short* __restrict__ q, const unsigned short* __restrict__ kT,
    const unsigned short* __restrict__ uT, const unsigned short* __restrict__ w,
    const unsigned short* __restrict__ attn, float* __restrict__ dout)
{
    const int bh = blockIdx.x & 7;     // low bits -> 16 same-bh blocks share one XCD
    const int jb = blockIdx.x >> 3;
    const int h = bh & (HH - 1), b = bh >> 2;
    const int jcol = jb * 16;
    const int wave = threadIdx.x >> 6, lane = threadIdx.x & 63;
    const int lr = lane & 15, lg = lane >> 4;
    const int half = wave & 1;
    const bool isQ = wave >= 2;

    __shared__ unsigned short SbT[2][16][264];   // [par][col][e] bf16
    __shared__ unsigned short uadjT[2][16][40];  // [par][col][cc] bf16

    floatx4 Sacc[4];
#pragma unroll
    for (int mt = 0; mt < 4; ++mt) Sacc[mt] = (floatx4){0.f,0.f,0.f,0.f};

    const unsigned short* qb  = q + (size_t)b * LL * DD + h * DH;
    const unsigned short* wb  = w + (size_t)bh * LL * DH;
    const unsigned short* ob  = isQ ? qb : wb;
    const size_t ost          = isQ ? (size_t)DD : (size_t)DH;
    const unsigned short* uTb = uT + (size_t)bh * DH * LL
                                + (size_t)(jcol + lr) * LL + half * 16 + lg * 4;
    const unsigned short* kTb = kT + (size_t)bh * DH * LL;
    const unsigned short* atb = attn + (size_t)bh * NC * (CH * CH)
                                + (size_t)(half * 16 + lr) * CH + lg * 8;
    float* db = dout + (size_t)bh * LL * DH;

    short8 po[2][8];     // this wave's A rows, K=256
    short8 pk[2][4];     // kT A-frags for S-update
    short8 pa[2];        // attn frag (waves 2,3)
    ushort4 pu[2];       // u elems (waves 0,1)

    {   // preload chunk 0 -> slot 0
        const unsigned short* orow = ob + (size_t)(half * 16 + lr) * ost;
#pragma unroll
        for (int kt = 0; kt < 8; ++kt)
            po[0][kt] = *(const short8*)(orow + kt * 32 + lg * 8);
#pragma unroll
        for (int mt = 0; mt < 4; ++mt)
            pk[0][mt] = *(const short8*)(kTb + (size_t)(64 * wave + 16 * mt + lr) * LL + lg * 8);
        if (!isQ) pu[0] = *(const ushort4*)(uTb);
        else      pa[0] = *(const short8*)(atb);
    }

#pragma unroll 2
    for (int ci = 0; ci < NC; ++ci) {
        const int p = ci & 1;
        const int l0 = ci * CH;

        // 1) pack wave's S e-slice -> SbT[p][col][e]
#pragma unroll
        for (int mt = 0; mt < 4; ++mt) {
            int e0 = 64 * wave + 16 * mt + lg * 4;
            *(unsigned int*)&SbT[p][lr][e0]     = pkbf(Sacc[mt][0], Sacc[mt][1]);
            *(unsigned int*)&SbT[p][lr][e0 + 2] = pkbf(Sacc[mt][2], Sacc[mt][3]);
        }

        // prefetch chunk ci+1 (clamped) into slot p^1
        {
            const int cn = (ci + 1 < NC) ? (ci + 1) : ci;
            const int ln = cn * CH;
            const unsigned short* orow = ob + (size_t)(ln + half * 16 + lr) * ost;
#pragma unroll
            for (int kt = 0; kt < 8; ++kt)
                po[p^1][kt] = *(const short8*)(orow + kt * 32 + lg * 8);
#pragma unroll
            for (int mt = 0; mt < 4; ++mt)
                pk[p^1][mt] = *(const short8*)(kTb + (size_t)(64 * wave + 16 * mt + lr) * LL + ln + lg * 8);
            if (!isQ) pu[p^1] = *(const ushort4*)(uTb + ln);
            else      pa[p^1] = *(const short8*)(atb + (size_t)cn * (CH * CH));
        }
        lds_barrier();   // (a) SbT[p] visible

        // 2) P = A @ S over full K=256 (two independent chains for ILP)
        floatx4 Pa = (floatx4){0.f,0.f,0.f,0.f}, Pb = Pa;
#pragma unroll
        for (int kt = 0; kt < 4; ++kt) {
            short8 s0 = *(const short8*)&SbT[p][lr][(2*kt)   * 32 + lg * 8];
            short8 s1 = *(const short8*)&SbT[p][lr][(2*kt+1) * 32 + lg * 8];
            Pa = __builtin_amdgcn_mfma_f32_16x16x32_bf16(po[p][2*kt],   s0, Pa, 0,0,0);
            Pb = __builtin_amdgcn_mfma_f32_16x16x32_bf16(po[p][2*kt+1], s1, Pb, 0,0,0);
        }
        floatx4 P = Pa + Pb;

        // 3) waves 0,1: uadj = u - w@S -> uadjT[p]
        if (!isQ) {
            ushort4 u4 = pu[p];
            float ua0 = bf2f(u4.x) - P[0];
            float ua1 = bf2f(u4.y) - P[1];
            float ua2 = bf2f(u4.z) - P[2];
            float ua3 = bf2f(u4.w) - P[3];
            int cc0 = half * 16 + lg * 4;
            *(unsigned int*)&uadjT[p][lr][cc0]     = pkbf(ua0, ua1);
            *(unsigned int*)&uadjT[p][lr][cc0 + 2] = pkbf(ua2, ua3);
        }
        lds_barrier();   // (b) uadjT[p] visible

        short8 ub = *(const short8*)&uadjT[p][lr][lg * 8];

        // 4) waves 2,3: O = q@S + attn@uadj -> dout
        if (isQ) {
            floatx4 Ot = __builtin_amdgcn_mfma_f32_16x16x32_bf16(pa[p], ub, P, 0,0,0);
#pragma unroll
            for (int r = 0; r < 4; ++r)
                db[(size_t)(l0 + half * 16 + lg * 4 + r) * DH + jcol + lr] = Ot[r];
        }

        // 5) S e-slice += kT @ uadj
#pragma unroll
        for (int mt = 0; mt < 4; ++mt)
            Sacc[mt] = __builtin_amdgcn_mfma_f32_16x16x32_bf16(pk[p][mt], ub, Sacc[mt], 0,0,0);
        // no trailing barrier: parity p untouched until ci+2, guarded by (a),(b) of ci+1
    }
}

// ------------------------------------------------- per-head stats
__global__ __launch_bounds__(256) void stats_k(
    const float* __restrict__ ls, const float* __restrict__ llb,
    const float* __restrict__ dox, const float* __restrict__ v,
    float* __restrict__ stats)
{
    int bl = blockIdx.x;
    int b = bl >> 12, l = bl & (LL - 1);
    int wv = threadIdx.x >> 6, ln = threadIdx.x & 63;
    size_t ibase = (size_t)bl * DD + wv * DH;
    size_t dbase = (((size_t)(b * HH + wv)) * LL + l) * DH;
#pragma unroll
    for (int tn = 0; tn < 4; ++tn) {
        const float* p; size_t base;
        if (tn == 0)      { p = ls;  base = ibase; }
        else if (tn == 1) { p = llb; base = ibase; }
        else if (tn == 2) { p = dox; base = dbase; }
        else              { p = v;   base = ibase; }
        float4 x = *(const float4*)(p + base + ln * 4);
        float sm = x.x + x.y + x.z + x.w;
        float sq = x.x*x.x + x.y*x.y + x.z*x.z + x.w*x.w;
        float sa = fabsf(x.x) + fabsf(x.y) + fabsf(x.z) + fabsf(x.w);
#pragma unroll
        for (int off = 32; off > 0; off >>= 1) {
            sm += __shfl_down(sm, off);
            sq += __shfl_down(sq, off);
            sa += __shfl_down(sa, off);
        }
        if (ln == 0) {
            float mean = sm * (1.0f / DH);
            float var = sq * (1.0f / DH) - mean * mean;
            float am = sa * (1.0f / DH);
            float l2 = sqrtf(sq);
            *(float4*)(stats + (size_t)bl * 64 + wv * 16 + tn * 4) =
                make_float4(mean, var, am, l2);
        }
    }
}

// ------------------------------------------------- gate finish v2
__global__ __launch_bounds__(256) void gate_fin2_k(
    const float* __restrict__ hpart, const float* __restrict__ stats,
    const unsigned short* __restrict__ w1s,
    const float* __restrict__ w2, const float* __restrict__ b2,
    const float* __restrict__ ltemp, float* __restrict__ fw)
{
    const int bl = blockIdx.x;
    const int t = threadIdx.x;
    const float temp = log1pf(expf(ltemp[0])) + 1e-4f;
    __shared__ float st[HH][16];
    __shared__ float red[4][16];
    __shared__ float fin[16];
    if (t < 64) st[t >> 4][t & 15] = stats[(size_t)bl * 64 + t];

    const int e0 = t * 4;
    float4 hp4 = *(const float4*)(hpart + (size_t)bl * DD + e0);
    float hp[4] = {hp4.x, hp4.y, hp4.z, hp4.w};
    float w2a[4][4];
#pragma unroll
    for (int j = 0; j < 4; ++j) {
        float4 wv = *(const float4*)(w2 + (size_t)j * 1024 + e0);
        w2a[j][0] = wv.x; w2a[j][1] = wv.y; w2a[j][2] = wv.z; w2a[j][3] = wv.w;
    }
    uint4 wpk[8];
    const uint4* wp = (const uint4*)(w1s + (size_t)e0 * 16);
#pragma unroll
    for (int i = 0; i < 8; ++i) wpk[i] = wp[i];
    __syncthreads();

    float lg[4][4];
#pragma unroll
    for (int h = 0; h < 4; ++h)
#pragma unroll
        for (int j = 0; j < 4; ++j) lg[h][j] = 0.0f;

#pragma unroll
    for (int ii = 0; ii < 4; ++ii) {
        float xh[4] = {hp[ii], hp[ii], hp[ii], hp[ii]};
        unsigned arr[8] = {wpk[ii*2].x, wpk[ii*2].y, wpk[ii*2].z, wpk[ii*2].w,
                           wpk[ii*2+1].x, wpk[ii*2+1].y, wpk[ii*2+1].z, wpk[ii*2+1].w};
#pragma unroll
        for (int p = 0; p < 8; ++p) {
            float wlo = bflo(arr[p]), whi = bfhi(arr[p]);
            int s = p * 2;
#pragma unroll
            for (int h = 0; h < 4; ++h)
                xh[h] += st[h][s] * wlo + st[h][s + 1] * whi;
        }
#pragma unroll
        for (int h = 0; h < 4; ++h) {
            float x = xh[h];
            float g = 0.5f * x * (1.0f + erff(x * 0.70710678118654752f));
            lg[h][0] += g * w2a[0][ii];
            lg[h][1] += g * w2a[1][ii];
            lg[h][2] += g * w2a[2][ii];
            lg[h][3] += g * w2a[3][ii];
        }
    }

#pragma unroll
    for (int h = 0; h < 4; ++h)
#pragma unroll
        for (int j = 0; j < 4; ++j)
#pragma unroll
            for (int off = 32; off > 0; off >>= 1)
                lg[h][j] += __shfl_down(lg[h][j], off);

    const int wv = t >> 6, ln = t & 63;
    if (ln == 0) {
#pragma unroll
        for (int h = 0; h < 4; ++h)
#pragma unroll
            for (int j = 0; j < 4; ++j) red[wv][h * 4 + j] = lg[h][j];
    }
    __syncthreads();
    if (t < 16) {
        float s = red[0][t] + red[1][t] + red[2][t] + red[3][t] + b2[t & 3];
        fin[t] = s / temp;
    }
    __syncthreads();
    if (t < 4) {
        float l0 = fin[t*4], l1 = fin[t*4+1], l2 = fin[t*4+2], l3 = fin[t*4+3];
        float m = fmaxf(fmaxf(l0, l1), fmaxf(l2, l3));
        float e0x = expf(l0-m), e1 = expf(l1-m), e2 = expf(l2-m), e3 = expf(l3-m);
        float inv = 1.0f / (e0x + e1 + e2 + e3);
        *(float4*)(fw + (size_t)bl * 16 + t * 4) = make_float4(e0x*inv, e1*inv, e2*inv, e3*inv);
    }
}

// ------------------------------------------------- combine + rms norm
__global__ __launch_bounds__(256) void combine_k(
    const float* __restrict__ ls, const float* __restrict__ llb,
    const float* __restrict__ dox, const float* __restrict__ v,
    const float* __restrict__ fw, const float* __restrict__ rss,
    const float* __restrict__ rsl, const float* __restrict__ onw,
    float* __restrict__ opre)
{
    int h = blockIdx.x & (HH - 1);
    int bl = blockIdx.x >> 2;
    int b = bl >> 12, l = bl & (LL - 1);
    int d = threadIdx.x;
    size_t i1 = (size_t)blockIdx.x * DH + d;
    size_t i2 = (((size_t)(b * HH + h)) * LL + l) * DH + d;
    const float* fwp = fw + (size_t)blockIdx.x * 4;
    float f0 = fwp[0], f1 = fwp[1], f2 = fwp[2], f3 = fwp[3];
    float aS = rss[0], aL = rsl[0];
    float vls = ls[i1], vll = llb[i1], vd = dox[i2], vv = v[i1];
    float o = f0*vls + f1*vll + f2*vd + f3*vv + aS*vls + aL*vll;
    float s = o * o;
#pragma unroll
    for (int off = 32; off > 0; off >>= 1) s += __shfl_down(s, off);
    __shared__ float red[4];
    int wv = threadIdx.x >> 6, ln = threadIdx.x & 63;
    if (ln == 0) red[wv] = s;
    __syncthreads();
    float ms = (red[0] + red[1] + red[2] + red[3]) * (1.0f / DH);
    opre[(size_t)bl * DD + h * DH + d] = o * rsqrtf(ms + 1e-5f) * onw[d];
}

// ================================================================ launch
extern "C" void kernel_launch(void* const* d_in, const int* in_sizes, int n_in,
                              void* d_out, int out_size, void* d_ws, size_t ws_size,
                              hipStream_t stream)
{
    const float* hs  = (const float*)d_in[0];
    const float* qw  = (const float*)d_in[1];
    const float* kw  = (const float*)d_in[2];
    const float* vw  = (const float*)d_in[3];
    const float* bw  = (const float*)d_in[4];
    const float* qcw = (const float*)d_in[5];
    const float* kcw = (const float*)d_in[6];
    const float* vcw = (const float*)d_in[7];
    const float* fsw = (const float*)d_in[8];
    const float* flw = (const float*)d_in[9];
    const float* w1  = (const float*)d_in[10];
    const float* b1  = (const float*)d_in[11];
    const float* w2  = (const float*)d_in[12];
    const float* b2  = (const float*)d_in[13];
    const float* lt  = (const float*)d_in[14];
    const float* rss = (const float*)d_in[15];
    const float* rsl = (const float*)d_in[16];
    const float* onw = (const float*)d_in[17];
    const float* opw = (const float*)d_in[18];
    float* out = (float*)d_out;

    float* wsf = (float*)d_ws;
    float* tmp   = wsf;
    unsigned short* ktbuf = (unsigned short*)tmp;
    unsigned short* uTbuf = (unsigned short*)(wsf + BLD/2);
    float* vbuf  = wsf + BLD;
    float* dbuf  = wsf + 2*BLD;
    // hsb shares the dbuf region -> DEAD once scan6 writes dbuf. Only used in phase 1.
    unsigned short* hsb = (unsigned short*)(wsf + 2*BLD);
    // bf16 QKV weights live in the dead second half of the dbuf region during phase 1
    unsigned short* qwb = (unsigned short*)(wsf + 2*BLD + BLD/2);
    unsigned short* kwb = qwb + (size_t)DD*DD;
    unsigned short* vwb = kwb + (size_t)DD*DD;
    unsigned short* qbuf = (unsigned short*)(wsf + 3*BLD);
    unsigned short* kbuf = qbuf + BLD;
    float* hpart = wsf + 3*BLD;
    float* opre  = wsf + 3*BLD;
    unsigned short* ubuf = (unsigned short*)(wsf + 4*BLD);
    unsigned short* wbuf = ubuf + BLD;
    float* llbuf = wsf + 4*BLD;
    float* lsbuf = tmp;
    unsigned short* attnb = (unsigned short*)(wsf + 5*BLD);
    float* statsb = wsf + 5*BLD + 524288;
    float* fwbuf  = statsb + (size_t)BL*HH*16;
    float* betab  = fwbuf + (size_t)BL*HH*4;
    unsigned short* w1sp = (unsigned short*)(betab + (size_t)BL*HH);

    dim3 gg(8, 64);   // N/128, M/128

    cvt_bf_k<<<(int)(BLD/1024), 256, 0, stream>>>(hs, hsb);
    cvt_bf_k<<<1024, 256, 0, stream>>>(qw, qwb);
    cvt_bf_k<<<1024, 256, 0, stream>>>(kw, kwb);
    cvt_bf_k<<<1024, 256, 0, stream>>>(vw, vwb);
    w1s_prep_k<<<64, 256, 0, stream>>>(w1, w1sp);

    gemm_bb<<<gg, 256, 0, stream>>>(hsb, DD, qwb, DD, tmp, DD, DD);
    convnorm_qk_k<<<BL*HH, 256, 0, stream>>>(tmp, qcw, qbuf);
    gemm_bb<<<gg, 256, 0, stream>>>(hsb, DD, kwb, DD, tmp, DD, DD);
    convnorm_qk_k<<<BL*HH, 256, 0, stream>>>(tmp, kcw, kbuf);
    gemm_bb<<<gg, 256, 0, stream>>>(hsb, DD, vwb, DD, tmp, DD, DD);
    conv_silu_k<<<(int)(BLD/256), 256, 0, stream>>>(tmp, vcw, vbuf);

    beta_k<<<BL, 256, 0, stream>>>(hs, bw, betab);

    tr_k<<<8*64*4, 256, 0, stream>>>(kbuf, ktbuf);
    chunk_prep_k<<<BB*HH*NC, 256, 0, stream>>>(qbuf, kbuf, vbuf, betab, ubuf, wbuf, attnb);
    tru_k<<<8*64*4, 256, 0, stream>>>(ubuf, uTbuf);

    scan6_k<<<BB*HH*16, 256, 0, stream>>>(qbuf, ktbuf, uTbuf, wbuf, attnb, dbuf);

    fir2_k<5><<<BB*64*16, 256, 0, stream>>>(vbuf, fsw, lsbuf);
    fir2_k<64><<<BB*64*16, 256, 0, stream>>>(vbuf, flw, llbuf);

    stats_k<<<BL, 256, 0, stream>>>(lsbuf, llbuf, dbuf, vbuf, statsb);

    // hpart GEMM reads the pristine f32 input hs (hsb is dead: overwritten by dbuf)
    gemm_mfma<<<gg, 256, 0, stream>>>(hs, DD, w1, 1040, b1, hpart, DD, DD);
    gate_fin2_k<<<BL, 256, 0, stream>>>(hpart, statsb, w1sp, w2, b2, lt, fwbuf);

    combine_k<<<BL*HH, 256, 0, stream>>>(lsbuf, llbuf, dbuf, vbuf, fwbuf, rss, rsl, onw, opre);

    gemm_mfma<<<gg, 256, 0, stream>>>(opre, DD, opw, DD, nullptr, out, DD, DD);
}